// Round 16
// baseline (612.908 us; speedup 1.0000x reference)
//
#include <hip/hip_runtime.h>
#include <hip/hip_bf16.h>

#define HID 64
#define RPW 16   // rows per wave in gemm2_lds
#define KCH 8    // k-chunk width (W regs live at a time = 2*KCH)

typedef __hip_bfloat16  bf16;
typedef __hip_bfloat162 bf162;
__device__ __forceinline__ float bl(bf16 h) { return __bfloat162float(h); }
__device__ __forceinline__ void storeb(float* p, float v) { *p = v; }
__device__ __forceinline__ void storeb(bf16* p, float v) { *p = __float2bfloat16(v); }

// -------- fused dual GEMM, LDS-broadcast rows + register W.
// outa[R][64] = in[R][K] @ Wa[:,coloff..]^T ; outb same with Wb (TB=bf16 for
// message operands). R9-R15 lesson: scalar s_load row-broadcast leaves the
// kernel latency-bound (VALU 28%, 59us on n3). Here each wave stages its 16
// rows into a private LDS slice with COALESCED global loads, then the K-loop
// reads wave-uniform ds_read_b128 (broadcast, conflict-free, independent
// across the unrolled row loop -> compiler hoists) + pure v_fma.
// W streams in 8-wide chunks, #pragma unroll 1 (R6: full unroll spills).
// waves_per_eu(6,6): live ~70 regs < 85 cap. LDS 16KB/block -> 6 blocks/CU.
// In-place safe: all global loads precede all stores per wave; rows 1:1 waves.
template <int KC, typename TB>
__global__ __attribute__((amdgpu_flat_work_group_size(256, 256),
                          amdgpu_waves_per_eu(6, 6)))
void gemm2_lds(const float* in,
               const float* __restrict__ Wa, const float* __restrict__ Wb,
               float* outa, TB* outb,
               int R, int ldw, int coloff) {
    __shared__ float rowbuf[4][RPW][64];
    int lane = threadIdx.x & 63;
    int wv = threadIdx.x >> 6;
    int wid = blockIdx.x * 4 + wv;
    int j0 = wid * RPW;
    if (j0 >= R) return;
    float (*rb)[64] = rowbuf[wv];
#pragma unroll
    for (int r = 0; r < RPW; ++r) {
        int j = j0 + r;
        if (j < R && lane < KC) rb[r][lane] = in[(size_t)j * KC + lane];
    }
    float accx[RPW], accy[RPW];
#pragma unroll
    for (int r = 0; r < RPW; ++r) { accx[r] = 0.f; accy[r] = 0.f; }
    const float* pa = Wa + (size_t)lane * ldw + coloff;
    const float* pb = Wb + (size_t)lane * ldw + coloff;
#pragma unroll 1
    for (int kc = 0; kc < KC; kc += KCH) {
        float wx[KCH], wy[KCH];
#pragma unroll
        for (int kk = 0; kk < KCH; ++kk) { wx[kk] = pa[kc + kk]; wy[kk] = pb[kc + kk]; }
#pragma unroll
        for (int r = 0; r < RPW; ++r) {
            const float4* rp = (const float4*)&rb[r][kc];
            float4 a0 = rp[0], a1 = rp[1];
            accx[r] = fmaf(a0.x, wx[0], accx[r]); accy[r] = fmaf(a0.x, wy[0], accy[r]);
            accx[r] = fmaf(a0.y, wx[1], accx[r]); accy[r] = fmaf(a0.y, wy[1], accy[r]);
            accx[r] = fmaf(a0.z, wx[2], accx[r]); accy[r] = fmaf(a0.z, wy[2], accy[r]);
            accx[r] = fmaf(a0.w, wx[3], accx[r]); accy[r] = fmaf(a0.w, wy[3], accy[r]);
            accx[r] = fmaf(a1.x, wx[4], accx[r]); accy[r] = fmaf(a1.x, wy[4], accy[r]);
            accx[r] = fmaf(a1.y, wx[5], accx[r]); accy[r] = fmaf(a1.y, wy[5], accy[r]);
            accx[r] = fmaf(a1.z, wx[6], accx[r]); accy[r] = fmaf(a1.z, wy[6], accy[r]);
            accx[r] = fmaf(a1.w, wx[7], accx[r]); accy[r] = fmaf(a1.w, wy[7], accy[r]);
        }
    }
#pragma unroll
    for (int r = 0; r < RPW; ++r) {
        int j = j0 + r;
        if (j < R) {
            outa[(size_t)j * HID + lane] = accx[r];
            storeb(&outb[(size_t)j * HID + lane], accy[r]);
        }
    }
}

// ======== batched CSR build (unchanged) ========
__global__ void zero4_k(int* p1, int s1, int* p2, int s2, int* p3, int s3,
                        int* p4, int s4, int nb1, int nb2, int nb3) {
    int b = blockIdx.x; int* p; int n; int lb;
    if (b < nb1)                 { p = p1; n = s1; lb = b; }
    else if (b < nb1 + nb2)      { p = p2; n = s2; lb = b - nb1; }
    else if (b < nb1 + nb2 + nb3){ p = p3; n = s3; lb = b - nb1 - nb2; }
    else                         { p = p4; n = s4; lb = b - nb1 - nb2 - nb3; }
    int i = lb * 256 + threadIdx.x;
    if (i < n) p[i] = 0;
}

__global__ void hist3_k(const int* e1, int E1, int* c1,
                        const int* e2, int E2, int* c2,
                        const int* e3, int E3, int* c3, int nb1, int nb2) {
    int b = blockIdx.x; const int* dst; int* c; int E; int lb;
    if (b < nb1)            { dst = e1 + E1; c = c1; E = E1; lb = b; }
    else if (b < nb1 + nb2) { dst = e2 + E2; c = c2; E = E2; lb = b - nb1; }
    else                    { dst = e3 + E3; c = c3; E = E3; lb = b - nb1 - nb2; }
    int e = lb * 256 + threadIdx.x;
    if (e < E) atomicAdd(&c[dst[e]], 1);
}

__device__ __forceinline__ void scan1_body(const int* __restrict__ cnt, int* __restrict__ rs,
                                           int* __restrict__ bsum, int n1, int n, int lb) {
    __shared__ int wsum[4];
    int t = threadIdx.x;
    int base = lb * 1024 + t * 4;
    int v[4]; int s = 0;
#pragma unroll
    for (int i = 0; i < 4; ++i) { int idx = base + i; v[i] = s; s += (idx < n) ? cnt[idx] : 0; }
    int lane = t & 63, wv = t >> 6;
    int x = s;
#pragma unroll
    for (int off = 1; off < 64; off <<= 1) { int y = __shfl_up(x, off, 64); if (lane >= off) x += y; }
    if (lane == 63) wsum[wv] = x;
    __syncthreads();
    int woff = 0;
    for (int w = 0; w < wv; ++w) woff += wsum[w];
    int excl = woff + (x - s);
#pragma unroll
    for (int i = 0; i < 4; ++i) { int idx = base + i; if (idx < n1) rs[idx] = excl + v[i]; }
    if (t == 255) bsum[lb] = wsum[0] + wsum[1] + wsum[2] + wsum[3];
}

__global__ void scan1_3k(const int* c1, int* r1, int* b1, int n1a, int na,
                         const int* c2, int* r2, int* b2, int n1b, int nb,
                         const int* c3, int* r3, int* b3, int n1c, int nc,
                         int nbl1, int nbl2) {
    int b = blockIdx.x;
    if (b < nbl1)             scan1_body(c1, r1, b1, n1a, na, b);
    else if (b < nbl1 + nbl2) scan1_body(c2, r2, b2, n1b, nb, b - nbl1);
    else                      scan1_body(c3, r3, b3, n1c, nc, b - nbl1 - nbl2);
}

__device__ __forceinline__ void scan2_body(int* bsum, int nb, int* wsum) {
    int t = threadIdx.x;
    int s = (t < nb) ? bsum[t] : 0;
    int lane = t & 63, wv = t >> 6;
    int x = s;
#pragma unroll
    for (int off = 1; off < 64; off <<= 1) { int y = __shfl_up(x, off, 64); if (lane >= off) x += y; }
    if (lane == 63) wsum[wv] = x;
    __syncthreads();
    int woff = 0;
    for (int w = 0; w < wv; ++w) woff += wsum[w];
    if (t < nb) bsum[t] = woff + x - s;
    __syncthreads();
}

__global__ void scan2_3k(int* b1, int nb1, int* b2, int nb2, int* b3, int nb3) {
    __shared__ int wsum[4];
    scan2_body(b1, nb1, wsum);
    scan2_body(b2, nb2, wsum);
    scan2_body(b3, nb3, wsum);
}

__global__ void scan3_3k(int* r1, const int* b1, int n1a,
                         int* r2, const int* b2, int n1b,
                         int* r3, const int* b3, int n1c, int nc1, int nc2) {
    int b = blockIdx.x; int* rs; const int* bsum; int n1; int lb;
    if (b < nc1)            { rs = r1; bsum = b1; n1 = n1a; lb = b; }
    else if (b < nc1 + nc2) { rs = r2; bsum = b2; n1 = n1b; lb = b - nc1; }
    else                    { rs = r3; bsum = b3; n1 = n1c; lb = b - nc1 - nc2; }
    int i = lb * 256 + threadIdx.x;
    if (i < n1) rs[i] += bsum[lb >> 2];
}

__global__ void fill3_k(const int* e1, int E1, const int* r1, int* c1, int* s1,
                        const int* e2, int E2, const int* r2, int* c2, int* s2,
                        const int* e3, int E3, const int* r3, int* c3, int* s3,
                        int nb1, int nb2) {
    int b = blockIdx.x;
    const int* edges; int E; const int* rs; int* cur; int* csrc; int lb;
    if (b < nb1)            { edges = e1; E = E1; rs = r1; cur = c1; csrc = s1; lb = b; }
    else if (b < nb1 + nb2) { edges = e2; E = E2; rs = r2; cur = c2; csrc = s2; lb = b - nb1; }
    else                    { edges = e3; E = E3; rs = r3; cur = c3; csrc = s3; lb = b - nb1 - nb2; }
    int e = lb * 256 + threadIdx.x;
    if (e >= E) return;
    int d = edges[E + e];
    int p = rs[d] + atomicAdd(&cur[d], 1);
    csrc[p] = edges[e];
}

// -------- gather + relu with bf16 messages
__global__ void neighsum_relu_k(const int* __restrict__ rs, const int* __restrict__ csrc,
                                const bf162* __restrict__ m, float* __restrict__ z,
                                int R, int nb8) {
    int b = (int)(blockIdx.x & 7) * nb8 + (int)(blockIdx.x >> 3);
    int t = threadIdx.x;
    int wv = t >> 6, lane = t & 63;
    int j = b * 8 + wv * 2 + (lane >> 5);
    int f2 = lane & 31;
    if (j >= R) return;
    float2* z2p = (float2*)z;
    int s = rs[j], e = rs[j + 1];
    float2 a = z2p[(size_t)j * 32 + f2];
    float ax = a.x, ay = a.y;
    int k = s;
    for (; k + 8 <= e; k += 8) {
        int i0 = csrc[k],     i1 = csrc[k + 1], i2 = csrc[k + 2], i3 = csrc[k + 3];
        int i4 = csrc[k + 4], i5 = csrc[k + 5], i6 = csrc[k + 6], i7 = csrc[k + 7];
        bf162 v0 = m[(size_t)i0 * 32 + f2], v1 = m[(size_t)i1 * 32 + f2];
        bf162 v2 = m[(size_t)i2 * 32 + f2], v3 = m[(size_t)i3 * 32 + f2];
        bf162 v4 = m[(size_t)i4 * 32 + f2], v5 = m[(size_t)i5 * 32 + f2];
        bf162 v6 = m[(size_t)i6 * 32 + f2], v7 = m[(size_t)i7 * 32 + f2];
        ax += ((bl(v0.x) + bl(v1.x)) + (bl(v2.x) + bl(v3.x)))
            + ((bl(v4.x) + bl(v5.x)) + (bl(v6.x) + bl(v7.x)));
        ay += ((bl(v0.y) + bl(v1.y)) + (bl(v2.y) + bl(v3.y)))
            + ((bl(v4.y) + bl(v5.y)) + (bl(v6.y) + bl(v7.y)));
    }
    for (; k + 4 <= e; k += 4) {
        int i0 = csrc[k], i1 = csrc[k + 1], i2 = csrc[k + 2], i3 = csrc[k + 3];
        bf162 v0 = m[(size_t)i0 * 32 + f2], v1 = m[(size_t)i1 * 32 + f2];
        bf162 v2 = m[(size_t)i2 * 32 + f2], v3 = m[(size_t)i3 * 32 + f2];
        ax += (bl(v0.x) + bl(v1.x)) + (bl(v2.x) + bl(v3.x));
        ay += (bl(v0.y) + bl(v1.y)) + (bl(v2.y) + bl(v3.y));
    }
    for (; k < e; ++k) {
        bf162 v = m[(size_t)csrc[k] * 32 + f2];
        ax += bl(v.x); ay += bl(v.y);
    }
    z2p[(size_t)j * 32 + f2] = make_float2(fmaxf(ax, 0.f), fmaxf(ay, 0.f));
}

// -------- level-2 layer-0 combined gather: z-init (fp32) + m (bf16)
__global__ void gatherZM2_k(const float* __restrict__ hU1, const float* __restrict__ hV1,
                            const float* __restrict__ hU2, const float* __restrict__ hV2,
                            const int* __restrict__ gu, const int* __restrict__ gv,
                            const float* __restrict__ iso2,
                            const float* __restrict__ W1, const float* __restrict__ W2,
                            float* __restrict__ z, bf16* __restrict__ m,
                            int n2, int jstep) {
    int idx = blockIdx.x * 256 + threadIdx.x;
    int j = idx >> 6, f = idx & 63;
    float w1c = W1[f * 129 + 128], w2c = W2[f * 129 + 128];
#pragma unroll
    for (int r = 0; r < 4; ++r, j += jstep) {
        if (j >= n2) return;
        int u = gu[j], v = gv[j];
        float is = iso2[j];
        z[(size_t)j * HID + f] = hU1[u * HID + f] + hV1[v * HID + f] + is * w1c;
        m[(size_t)j * HID + f] =
            __float2bfloat16(hU2[u * HID + f] + hV2[v * HID + f] + is * w2c);
    }
}

// -------- level-3 layer-0 combined gather (iso3 one-hot x4)
__global__ void gatherZM3_k(const float* __restrict__ hA1, const float* __restrict__ hB1,
                            const float* __restrict__ hC1,
                            const float* __restrict__ hA2, const float* __restrict__ hB2,
                            const float* __restrict__ hC2,
                            const int* __restrict__ ga, const int* __restrict__ gb,
                            const int* __restrict__ gc, const float* __restrict__ iso3,
                            const float* __restrict__ W1, const float* __restrict__ W2,
                            float* __restrict__ z, bf16* __restrict__ m,
                            int n3, int jstep) {
    int idx = blockIdx.x * 256 + threadIdx.x;
    int j = idx >> 6, f = idx & 63;
    float w1c[4], w2c[4];
#pragma unroll
    for (int c = 0; c < 4; ++c) {
        w1c[c] = W1[f * 196 + 192 + c];
        w2c[c] = W2[f * 196 + 192 + c];
    }
    const float4* I4 = (const float4*)iso3;
#pragma unroll
    for (int r = 0; r < 4; ++r, j += jstep) {
        if (j >= n3) return;
        int a = ga[j], b = gb[j], c = gc[j];
        float4 iv = I4[j];
        float zz = hA1[a * HID + f] + hB1[b * HID + f] + hC1[c * HID + f]
                 + iv.x * w1c[0] + iv.y * w1c[1] + iv.z * w1c[2] + iv.w * w1c[3];
        float mm = hA2[a * HID + f] + hB2[b * HID + f] + hC2[c * HID + f]
                 + iv.x * w2c[0] + iv.y * w2c[1] + iv.z * w2c[2] + iv.w * w2c[3];
        z[(size_t)j * HID + f] = zz;
        m[(size_t)j * HID + f] = __float2bfloat16(mm);
    }
}

// -------- split segment sum
__global__ void segsum_split_k(const float* __restrict__ h, float* __restrict__ comb,
                               int per, int coloff, int S, int chunk) {
    int b = blockIdx.x;
    int g = b / S, s = b % S;
    int f = threadIdx.x;
    int r0 = s * chunk;
    int r1 = min(per, r0 + chunk);
    float acc = 0.f;
    const float* p = h + ((size_t)g * per + r0) * HID + f;
    for (int r = r0; r < r1; ++r) { acc += *p; p += HID; }
    atomicAdd(&comb[g * 192 + coloff + f], acc);
}

// -------- classifier
__global__ void classifier_k(const float* __restrict__ comb,
                             const float* __restrict__ cW1, const float* __restrict__ cb1,
                             const float* __restrict__ cW2, const float* __restrict__ cb2,
                             float* __restrict__ out) {
    __shared__ float row[192];
    __shared__ float hid[64];
    int g = blockIdx.x, t = threadIdx.x;
    for (int i = t; i < 192; i += 64) row[i] = comb[g * 192 + i];
    __syncthreads();
    float acc = cb1[t];
#pragma unroll 8
    for (int k = 0; k < 192; ++k) acc += row[k] * cW1[t * 192 + k];
    hid[t] = fmaxf(acc, 0.f);
    __syncthreads();
    if (t < 10) {
        float o = cb2[t];
#pragma unroll
        for (int k = 0; k < 64; ++k) o += hid[k] * cW2[t * 64 + k];
        out[g * 10 + t] = o;
    }
}

static inline int cdiv(long long a, long long b) { return (int)((a + b - 1) / b); }

extern "C" void kernel_launch(void* const* d_in, const int* in_sizes, int n_in,
                              void* d_out, int out_size, void* d_ws, size_t ws_size,
                              hipStream_t stream) {
    const float* x        = (const float*)d_in[0];
    const int*   eidx     = (const int*)d_in[1];
    const int*   gu2      = (const int*)d_in[3];
    const int*   gv2      = (const int*)d_in[4];
    const float* iso2     = (const float*)d_in[5];
    const int*   tedges   = (const int*)d_in[6];
    const int*   ga3      = (const int*)d_in[8];
    const int*   gb3      = (const int*)d_in[9];
    const int*   gc3      = (const int*)d_in[10];
    const float* iso3     = (const float*)d_in[11];
    const int*   hedges   = (const int*)d_in[12];
    const float* g1W1[3]  = {(const float*)d_in[14], (const float*)d_in[16], (const float*)d_in[18]};
    const float* g1W2[3]  = {(const float*)d_in[15], (const float*)d_in[17], (const float*)d_in[19]};
    const float* g2W1_0   = (const float*)d_in[20];
    const float* g2W2_0   = (const float*)d_in[21];
    const float* g2W1_1   = (const float*)d_in[22];
    const float* g2W2_1   = (const float*)d_in[23];
    const float* g3W1_0   = (const float*)d_in[24];
    const float* g3W2_0   = (const float*)d_in[25];
    const float* g3W1_1   = (const float*)d_in[26];
    const float* g3W2_1   = (const float*)d_in[27];
    const float* cW1      = (const float*)d_in[28];
    const float* cb1      = (const float*)d_in[29];
    const float* cW2      = (const float*)d_in[30];
    const float* cb2      = (const float*)d_in[31];
    float* out = (float*)d_out;

    const int N  = in_sizes[0] / 32;       // 2560
    const int E1 = in_sizes[1] / 2;
    const int n2 = in_sizes[3];            // 24320
    const int E2 = in_sizes[6] / 2;
    const int n3 = in_sizes[8];            // 145920
    const int E3 = in_sizes[12] / 2;
    const int G  = out_size / 10;          // 128
    const int per1 = N / G, per2 = n2 / G, per3 = n3 / G;

    // ---- workspace carve-up (float units)
    float* ws = (float*)d_ws;
    size_t off = 0;
    auto alloc = [&](size_t n) { float* p = ws + off; off += n; return p; };
    const size_t NH = (size_t)N * HID;
    float* nb0 = alloc(NH); float* nb1 = alloc(NH);
    bf16* mb1 = (bf16*)alloc(NH / 2 + 64);
    float* hU1 = alloc(NH); float* hV1 = alloc(NH); float* hU2 = alloc(NH); float* hV2 = alloc(NH);
    float* hA1 = alloc(NH); float* hB1 = alloc(NH); float* hC1 = alloc(NH);
    float* hA2 = alloc(NH); float* hB2 = alloc(NH); float* hC2 = alloc(NH);
    float* z2 = alloc((size_t)n2 * HID);
    bf16* m2b = (bf16*)alloc((size_t)n2 * HID / 2 + 64);
    float* z3 = alloc((size_t)n3 * HID);
    bf16* m3b = (bf16*)alloc((size_t)n3 * HID / 2 + 64);
    float* comb = alloc((size_t)G * 192);
    int* iws = (int*)(ws + off);
    size_t ioff = 0;
    auto ialloc = [&](size_t n) { int* p = iws + ioff; ioff += n; return p; };
    int* rs1 = ialloc(N + 1);  int* cur1 = ialloc(N);  int* csrc1 = ialloc(E1);
    int* rs2 = ialloc(n2 + 1); int* cur2 = ialloc(n2); int* csrc2 = ialloc(E2);
    int* rs3 = ialloc(n3 + 1); int* cur3 = ialloc(n3); int* csrc3 = ialloc(E3);
    int* bsum1 = ialloc(256); int* bsum2 = ialloc(256); int* bsum3 = ialloc(256);
    (void)ws_size;

    dim3 B256(256);
    auto gemm2 = [&](const float* in, const float* Wa, const float* Wb,
                     float* oa, float* ob, int R, int K, int ldw, int coloff) {
        int blocks = cdiv(cdiv(R, RPW), 4);
        if (K == 64)
            gemm2_lds<64, float><<<blocks, B256, 0, stream>>>(in, Wa, Wb, oa, ob, R, ldw, coloff);
        else
            gemm2_lds<32, float><<<blocks, B256, 0, stream>>>(in, Wa, Wb, oa, ob, R, ldw, coloff);
    };
    auto gemm2b = [&](const float* in, const float* Wa, const float* Wb,
                      float* oa, bf16* ob, int R, int K, int ldw, int coloff) {
        int blocks = cdiv(cdiv(R, RPW), 4);
        if (K == 64)
            gemm2_lds<64, bf16><<<blocks, B256, 0, stream>>>(in, Wa, Wb, oa, ob, R, ldw, coloff);
        else
            gemm2_lds<32, bf16><<<blocks, B256, 0, stream>>>(in, Wa, Wb, oa, ob, R, ldw, coloff);
    };
    auto neigh = [&](const int* rs, const int* csrc, const bf16* m, float* z, int R) {
        int nb = cdiv(R, 8);
        int nb8 = cdiv(nb, 8);
        neighsum_relu_k<<<nb8 * 8, B256, 0, stream>>>(rs, csrc, (const bf162*)m, z, R, nb8);
    };
    auto segsum = [&](const float* h, int per, int coloff) {
        int chunk = 64;
        int S = cdiv(per, chunk);
        segsum_split_k<<<G * S, 64, 0, stream>>>(h, comb, per, coloff, S, chunk);
    };

    // ---- batched CSR build (7 dispatches; comb zero folded into first)
    int nz1 = cdiv(N, 256), nz2 = cdiv(n2, 256), nz3 = cdiv(n3, 256), nz4 = cdiv(G * 192, 256);
    zero4_k<<<nz1 + nz2 + nz3 + nz4, B256, 0, stream>>>(
        cur1, N, cur2, n2, cur3, n3, (int*)comb, G * 192, nz1, nz2, nz3);
    int ne1 = cdiv(E1, 256), ne2 = cdiv(E2, 256), ne3 = cdiv(E3, 256);
    hist3_k<<<ne1 + ne2 + ne3, B256, 0, stream>>>(
        eidx, E1, cur1, tedges, E2, cur2, hedges, E3, cur3, ne1, ne2);
    int ns1 = cdiv(N + 1, 1024), ns2 = cdiv(n2 + 1, 1024), ns3 = cdiv(n3 + 1, 1024);
    scan1_3k<<<ns1 + ns2 + ns3, B256, 0, stream>>>(
        cur1, rs1, bsum1, N + 1, N, cur2, rs2, bsum2, n2 + 1, n2,
        cur3, rs3, bsum3, n3 + 1, n3, ns1, ns2);
    scan2_3k<<<1, B256, 0, stream>>>(bsum1, ns1, bsum2, ns2, bsum3, ns3);
    int nc1 = cdiv(N + 1, 256), nc2 = cdiv(n2 + 1, 256), nc3 = cdiv(n3 + 1, 256);
    scan3_3k<<<nc1 + nc2 + nc3, B256, 0, stream>>>(
        rs1, bsum1, N + 1, rs2, bsum2, n2 + 1, rs3, bsum3, n3 + 1, nc1, nc2);
    zero4_k<<<nz1 + nz2 + nz3, B256, 0, stream>>>(
        cur1, N, cur2, n2, cur3, n3, nullptr, 0, nz1, nz2, nz3);
    fill3_k<<<ne1 + ne2 + ne3, B256, 0, stream>>>(
        eidx, E1, rs1, cur1, csrc1, tedges, E2, rs2, cur2, csrc2,
        hedges, E3, rs3, cur3, csrc3, ne1, ne2);

    // ================= level 1: node GNN (3 layers; bf16 messages) ==========
    const float* hcur = x;
    float* zb[2] = {nb0, nb1};
    for (int l = 0; l < 3; ++l) {
        int K = (l == 0) ? 32 : 64;
        float* z = zb[l & 1];
        gemm2b(hcur, g1W1[l], g1W2[l], z, mb1, N, K, K, 0);
        neigh(rs1, csrc1, mb1, z, N);
        hcur = z;
    }
    const float* h = hcur;   // = nb0 after 3 layers

    segsum(h, per1, 0);

    // ================= level 2: pair GNN (2 layers) =================
    gemm2(h, g2W1_0, g2W2_0, hU1, hU2, N, 64, 129, 0);
    gemm2(h, g2W1_0, g2W2_0, hV1, hV2, N, 64, 129, 64);
    {
        int jstep = cdiv(n2, 4);
        gatherZM2_k<<<cdiv((long long)jstep * 64, 256), B256, 0, stream>>>(
            hU1, hV1, hU2, hV2, gu2, gv2, iso2, g2W1_0, g2W2_0, z2, m2b, n2, jstep);
    }
    neigh(rs2, csrc2, m2b, z2, n2);
    gemm2b(z2, g2W1_1, g2W2_1, z2, m2b, n2, 64, 64, 0);   // in-place z2
    neigh(rs2, csrc2, m2b, z2, n2);
    segsum(z2, per2, 64);

    // ================= level 3: triple GNN (2 layers) =================
    gemm2(h, g3W1_0, g3W2_0, hA1, hA2, N, 64, 196, 0);
    gemm2(h, g3W1_0, g3W2_0, hB1, hB2, N, 64, 196, 64);
    gemm2(h, g3W1_0, g3W2_0, hC1, hC2, N, 64, 196, 128);
    {
        int jstep = cdiv(n3, 4);
        gatherZM3_k<<<cdiv((long long)jstep * 64, 256), B256, 0, stream>>>(
            hA1, hB1, hC1, hA2, hB2, hC2, ga3, gb3, gc3, iso3,
            g3W1_0, g3W2_0, z3, m3b, n3, jstep);
    }
    neigh(rs3, csrc3, m3b, z3, n3);
    gemm2b(z3, g3W1_1, g3W2_1, z3, m3b, n3, 64, 64, 0);   // in-place z3
    neigh(rs3, csrc3, m3b, z3, n3);
    segsum(z3, per3, 128);

    // ================= classifier =================
    classifier_k<<<G, 64, 0, stream>>>(comb, cW1, cb1, cW2, cb2, out);
}

// Round 17
// 489.843 us; speedup vs baseline: 1.2512x; 1.2512x over previous
//
#include <hip/hip_runtime.h>
#include <hip/hip_bf16.h>

#define HID 64
#define RPW 16   // rows per wave in gemm kernels
#define KCH 8    // k-chunk width (W regs live at a time = 2*KCH)

typedef __hip_bfloat16  bf16;
typedef __hip_bfloat162 bf162;
__device__ __forceinline__ float bl(bf16 h) { return __bfloat162float(h); }

// -------- fused dual GEMM, K-chunked register tiling, SCALAR row broadcast.
// Best measured config (R13): waves_per_eu(6,6), KCH=8 -> 54us on n3.
// R16 lesson: LDS-broadcast variant spilled (WRITE 55->123MB) - reverted.
template <int KC>
__global__ __attribute__((amdgpu_flat_work_group_size(256, 256),
                          amdgpu_waves_per_eu(6, 6)))
void gemm2_reg(const float* in,
               const float* __restrict__ Wa, const float* __restrict__ Wb,
               float* outa, float* outb,
               int R, int ldw, int coloff) {
    int lane = threadIdx.x & 63;
    int wid = blockIdx.x * (blockDim.x >> 6) + (threadIdx.x >> 6);
    int j0 = __builtin_amdgcn_readfirstlane(wid * RPW);
    if (j0 >= R) return;
    float accx[RPW], accy[RPW];
#pragma unroll
    for (int r = 0; r < RPW; ++r) { accx[r] = 0.f; accy[r] = 0.f; }
    const float* pa = Wa + (size_t)lane * ldw + coloff;
    const float* pb = Wb + (size_t)lane * ldw + coloff;
#pragma unroll 1
    for (int kc = 0; kc < KC; kc += KCH) {
        float wx[KCH], wy[KCH];
#pragma unroll
        for (int kk = 0; kk < KCH; ++kk) { wx[kk] = pa[kc + kk]; wy[kk] = pb[kc + kk]; }
#pragma unroll
        for (int r = 0; r < RPW; ++r) {
            const float* rp = in + (size_t)(j0 + r) * KC + kc;
#pragma unroll
            for (int kk = 0; kk < KCH; ++kk) {
                float s = rp[kk];
                accx[r] = fmaf(s, wx[kk], accx[r]);
                accy[r] = fmaf(s, wy[kk], accy[r]);
            }
        }
    }
#pragma unroll
    for (int r = 0; r < RPW; ++r) {
        int j = j0 + r;
        outa[(size_t)j * HID + lane] = accx[r];
        outb[(size_t)j * HID + lane] = accy[r];
    }
}

// -------- same, but outb (the message operand) stored as bf16.
template <int KC>
__global__ __attribute__((amdgpu_flat_work_group_size(256, 256),
                          amdgpu_waves_per_eu(6, 6)))
void gemm2_regb(const float* in,
                const float* __restrict__ Wa, const float* __restrict__ Wb,
                float* outa, bf16* outb,
                int R, int ldw, int coloff) {
    int lane = threadIdx.x & 63;
    int wid = blockIdx.x * (blockDim.x >> 6) + (threadIdx.x >> 6);
    int j0 = __builtin_amdgcn_readfirstlane(wid * RPW);
    if (j0 >= R) return;
    float accx[RPW], accy[RPW];
#pragma unroll
    for (int r = 0; r < RPW; ++r) { accx[r] = 0.f; accy[r] = 0.f; }
    const float* pa = Wa + (size_t)lane * ldw + coloff;
    const float* pb = Wb + (size_t)lane * ldw + coloff;
#pragma unroll 1
    for (int kc = 0; kc < KC; kc += KCH) {
        float wx[KCH], wy[KCH];
#pragma unroll
        for (int kk = 0; kk < KCH; ++kk) { wx[kk] = pa[kc + kk]; wy[kk] = pb[kc + kk]; }
#pragma unroll
        for (int r = 0; r < RPW; ++r) {
            const float* rp = in + (size_t)(j0 + r) * KC + kc;
#pragma unroll
            for (int kk = 0; kk < KCH; ++kk) {
                float s = rp[kk];
                accx[r] = fmaf(s, wx[kk], accx[r]);
                accy[r] = fmaf(s, wy[kk], accy[r]);
            }
        }
    }
#pragma unroll
    for (int r = 0; r < RPW; ++r) {
        int j = j0 + r;
        outa[(size_t)j * HID + lane] = accx[r];
        outb[(size_t)j * HID + lane] = __float2bfloat16(accy[r]);
    }
}

// -------- batched table GEMM: 5 independent (Wa,Wb,coloff) jobs over the
// same input h (R=N=2560 rows each -> 40 blocks/job alone = launch-bound;
// batched = 200 concurrent blocks, one dispatch instead of five).
struct TJob { const float* Wa; const float* Wb; float* oa; float* ob; int ldw; int coloff; };
struct TJobs5 { TJob j[5]; };

__global__ __attribute__((amdgpu_flat_work_group_size(256, 256),
                          amdgpu_waves_per_eu(6, 6)))
void gemm2_table(const float* in, TJobs5 jobs, int R, int bpj) {
    int jobi = blockIdx.x / bpj;
    int lb = blockIdx.x % bpj;
    TJob jb = jobs.j[jobi];
    int lane = threadIdx.x & 63;
    int wid = lb * 4 + (threadIdx.x >> 6);
    int j0 = __builtin_amdgcn_readfirstlane(wid * RPW);
    if (j0 >= R) return;
    float accx[RPW], accy[RPW];
#pragma unroll
    for (int r = 0; r < RPW; ++r) { accx[r] = 0.f; accy[r] = 0.f; }
    const float* pa = jb.Wa + (size_t)lane * jb.ldw + jb.coloff;
    const float* pb = jb.Wb + (size_t)lane * jb.ldw + jb.coloff;
#pragma unroll 1
    for (int kc = 0; kc < 64; kc += KCH) {
        float wx[KCH], wy[KCH];
#pragma unroll
        for (int kk = 0; kk < KCH; ++kk) { wx[kk] = pa[kc + kk]; wy[kk] = pb[kc + kk]; }
#pragma unroll
        for (int r = 0; r < RPW; ++r) {
            const float* rp = in + (size_t)(j0 + r) * 64 + kc;
#pragma unroll
            for (int kk = 0; kk < KCH; ++kk) {
                float s = rp[kk];
                accx[r] = fmaf(s, wx[kk], accx[r]);
                accy[r] = fmaf(s, wy[kk], accy[r]);
            }
        }
    }
#pragma unroll
    for (int r = 0; r < RPW; ++r) {
        int j = j0 + r;
        jb.oa[(size_t)j * HID + lane] = accx[r];
        jb.ob[(size_t)j * HID + lane] = accy[r];
    }
}

// ======== batched CSR build (unchanged) ========
__global__ void zero4_k(int* p1, int s1, int* p2, int s2, int* p3, int s3,
                        int* p4, int s4, int nb1, int nb2, int nb3) {
    int b = blockIdx.x; int* p; int n; int lb;
    if (b < nb1)                 { p = p1; n = s1; lb = b; }
    else if (b < nb1 + nb2)      { p = p2; n = s2; lb = b - nb1; }
    else if (b < nb1 + nb2 + nb3){ p = p3; n = s3; lb = b - nb1 - nb2; }
    else                         { p = p4; n = s4; lb = b - nb1 - nb2 - nb3; }
    int i = lb * 256 + threadIdx.x;
    if (i < n) p[i] = 0;
}

__global__ void hist3_k(const int* e1, int E1, int* c1,
                        const int* e2, int E2, int* c2,
                        const int* e3, int E3, int* c3, int nb1, int nb2) {
    int b = blockIdx.x; const int* dst; int* c; int E; int lb;
    if (b < nb1)            { dst = e1 + E1; c = c1; E = E1; lb = b; }
    else if (b < nb1 + nb2) { dst = e2 + E2; c = c2; E = E2; lb = b - nb1; }
    else                    { dst = e3 + E3; c = c3; E = E3; lb = b - nb1 - nb2; }
    int e = lb * 256 + threadIdx.x;
    if (e < E) atomicAdd(&c[dst[e]], 1);
}

__device__ __forceinline__ void scan1_body(const int* __restrict__ cnt, int* __restrict__ rs,
                                           int* __restrict__ bsum, int n1, int n, int lb) {
    __shared__ int wsum[4];
    int t = threadIdx.x;
    int base = lb * 1024 + t * 4;
    int v[4]; int s = 0;
#pragma unroll
    for (int i = 0; i < 4; ++i) { int idx = base + i; v[i] = s; s += (idx < n) ? cnt[idx] : 0; }
    int lane = t & 63, wv = t >> 6;
    int x = s;
#pragma unroll
    for (int off = 1; off < 64; off <<= 1) { int y = __shfl_up(x, off, 64); if (lane >= off) x += y; }
    if (lane == 63) wsum[wv] = x;
    __syncthreads();
    int woff = 0;
    for (int w = 0; w < wv; ++w) woff += wsum[w];
    int excl = woff + (x - s);
#pragma unroll
    for (int i = 0; i < 4; ++i) { int idx = base + i; if (idx < n1) rs[idx] = excl + v[i]; }
    if (t == 255) bsum[lb] = wsum[0] + wsum[1] + wsum[2] + wsum[3];
}

__global__ void scan1_3k(const int* c1, int* r1, int* b1, int n1a, int na,
                         const int* c2, int* r2, int* b2, int n1b, int nb,
                         const int* c3, int* r3, int* b3, int n1c, int nc,
                         int nbl1, int nbl2) {
    int b = blockIdx.x;
    if (b < nbl1)             scan1_body(c1, r1, b1, n1a, na, b);
    else if (b < nbl1 + nbl2) scan1_body(c2, r2, b2, n1b, nb, b - nbl1);
    else                      scan1_body(c3, r3, b3, n1c, nc, b - nbl1 - nbl2);
}

__device__ __forceinline__ void scan2_body(int* bsum, int nb, int* wsum) {
    int t = threadIdx.x;
    int s = (t < nb) ? bsum[t] : 0;
    int lane = t & 63, wv = t >> 6;
    int x = s;
#pragma unroll
    for (int off = 1; off < 64; off <<= 1) { int y = __shfl_up(x, off, 64); if (lane >= off) x += y; }
    if (lane == 63) wsum[wv] = x;
    __syncthreads();
    int woff = 0;
    for (int w = 0; w < wv; ++w) woff += wsum[w];
    if (t < nb) bsum[t] = woff + x - s;
    __syncthreads();
}

__global__ void scan2_3k(int* b1, int nb1, int* b2, int nb2, int* b3, int nb3) {
    __shared__ int wsum[4];
    scan2_body(b1, nb1, wsum);
    scan2_body(b2, nb2, wsum);
    scan2_body(b3, nb3, wsum);
}

__global__ void scan3_3k(int* r1, const int* b1, int n1a,
                         int* r2, const int* b2, int n1b,
                         int* r3, const int* b3, int n1c, int nc1, int nc2) {
    int b = blockIdx.x; int* rs; const int* bsum; int n1; int lb;
    if (b < nc1)            { rs = r1; bsum = b1; n1 = n1a; lb = b; }
    else if (b < nc1 + nc2) { rs = r2; bsum = b2; n1 = n1b; lb = b - nc1; }
    else                    { rs = r3; bsum = b3; n1 = n1c; lb = b - nc1 - nc2; }
    int i = lb * 256 + threadIdx.x;
    if (i < n1) rs[i] += bsum[lb >> 2];
}

__global__ void fill3_k(const int* e1, int E1, const int* r1, int* c1, int* s1,
                        const int* e2, int E2, const int* r2, int* c2, int* s2,
                        const int* e3, int E3, const int* r3, int* c3, int* s3,
                        int nb1, int nb2) {
    int b = blockIdx.x;
    const int* edges; int E; const int* rs; int* cur; int* csrc; int lb;
    if (b < nb1)            { edges = e1; E = E1; rs = r1; cur = c1; csrc = s1; lb = b; }
    else if (b < nb1 + nb2) { edges = e2; E = E2; rs = r2; cur = c2; csrc = s2; lb = b - nb1; }
    else                    { edges = e3; E = E3; rs = r3; cur = c3; csrc = s3; lb = b - nb1 - nb2; }
    int e = lb * 256 + threadIdx.x;
    if (e >= E) return;
    int d = edges[E + e];
    int p = rs[d] + atomicAdd(&cur[d], 1);
    csrc[p] = edges[e];
}

// -------- gather + relu with bf16 messages
__global__ void neighsum_relu_k(const int* __restrict__ rs, const int* __restrict__ csrc,
                                const bf162* __restrict__ m, float* __restrict__ z,
                                int R, int nb8) {
    int b = (int)(blockIdx.x & 7) * nb8 + (int)(blockIdx.x >> 3);
    int t = threadIdx.x;
    int wv = t >> 6, lane = t & 63;
    int j = b * 8 + wv * 2 + (lane >> 5);
    int f2 = lane & 31;
    if (j >= R) return;
    float2* z2p = (float2*)z;
    int s = rs[j], e = rs[j + 1];
    float2 a = z2p[(size_t)j * 32 + f2];
    float ax = a.x, ay = a.y;
    int k = s;
    for (; k + 8 <= e; k += 8) {
        int i0 = csrc[k],     i1 = csrc[k + 1], i2 = csrc[k + 2], i3 = csrc[k + 3];
        int i4 = csrc[k + 4], i5 = csrc[k + 5], i6 = csrc[k + 6], i7 = csrc[k + 7];
        bf162 v0 = m[(size_t)i0 * 32 + f2], v1 = m[(size_t)i1 * 32 + f2];
        bf162 v2 = m[(size_t)i2 * 32 + f2], v3 = m[(size_t)i3 * 32 + f2];
        bf162 v4 = m[(size_t)i4 * 32 + f2], v5 = m[(size_t)i5 * 32 + f2];
        bf162 v6 = m[(size_t)i6 * 32 + f2], v7 = m[(size_t)i7 * 32 + f2];
        ax += ((bl(v0.x) + bl(v1.x)) + (bl(v2.x) + bl(v3.x)))
            + ((bl(v4.x) + bl(v5.x)) + (bl(v6.x) + bl(v7.x)));
        ay += ((bl(v0.y) + bl(v1.y)) + (bl(v2.y) + bl(v3.y)))
            + ((bl(v4.y) + bl(v5.y)) + (bl(v6.y) + bl(v7.y)));
    }
    for (; k + 4 <= e; k += 4) {
        int i0 = csrc[k], i1 = csrc[k + 1], i2 = csrc[k + 2], i3 = csrc[k + 3];
        bf162 v0 = m[(size_t)i0 * 32 + f2], v1 = m[(size_t)i1 * 32 + f2];
        bf162 v2 = m[(size_t)i2 * 32 + f2], v3 = m[(size_t)i3 * 32 + f2];
        ax += (bl(v0.x) + bl(v1.x)) + (bl(v2.x) + bl(v3.x));
        ay += (bl(v0.y) + bl(v1.y)) + (bl(v2.y) + bl(v3.y));
    }
    for (; k < e; ++k) {
        bf162 v = m[(size_t)csrc[k] * 32 + f2];
        ax += bl(v.x); ay += bl(v.y);
    }
    z2p[(size_t)j * 32 + f2] = make_float2(fmaxf(ax, 0.f), fmaxf(ay, 0.f));
}

// -------- level-2 layer-0 combined gather: z-init (fp32) + m (bf16)
__global__ void gatherZM2_k(const float* __restrict__ hU1, const float* __restrict__ hV1,
                            const float* __restrict__ hU2, const float* __restrict__ hV2,
                            const int* __restrict__ gu, const int* __restrict__ gv,
                            const float* __restrict__ iso2,
                            const float* __restrict__ W1, const float* __restrict__ W2,
                            float* __restrict__ z, bf16* __restrict__ m,
                            int n2, int jstep) {
    int idx = blockIdx.x * 256 + threadIdx.x;
    int j = idx >> 6, f = idx & 63;
    float w1c = W1[f * 129 + 128], w2c = W2[f * 129 + 128];
#pragma unroll
    for (int r = 0; r < 4; ++r, j += jstep) {
        if (j >= n2) return;
        int u = gu[j], v = gv[j];
        float is = iso2[j];
        z[(size_t)j * HID + f] = hU1[u * HID + f] + hV1[v * HID + f] + is * w1c;
        m[(size_t)j * HID + f] =
            __float2bfloat16(hU2[u * HID + f] + hV2[v * HID + f] + is * w2c);
    }
}

// -------- level-3 layer-0 combined gather (iso3 one-hot x4)
__global__ void gatherZM3_k(const float* __restrict__ hA1, const float* __restrict__ hB1,
                            const float* __restrict__ hC1,
                            const float* __restrict__ hA2, const float* __restrict__ hB2,
                            const float* __restrict__ hC2,
                            const int* __restrict__ ga, const int* __restrict__ gb,
                            const int* __restrict__ gc, const float* __restrict__ iso3,
                            const float* __restrict__ W1, const float* __restrict__ W2,
                            float* __restrict__ z, bf16* __restrict__ m,
                            int n3, int jstep) {
    int idx = blockIdx.x * 256 + threadIdx.x;
    int j = idx >> 6, f = idx & 63;
    float w1c[4], w2c[4];
#pragma unroll
    for (int c = 0; c < 4; ++c) {
        w1c[c] = W1[f * 196 + 192 + c];
        w2c[c] = W2[f * 196 + 192 + c];
    }
    const float4* I4 = (const float4*)iso3;
#pragma unroll
    for (int r = 0; r < 4; ++r, j += jstep) {
        if (j >= n3) return;
        int a = ga[j], b = gb[j], c = gc[j];
        float4 iv = I4[j];
        float zz = hA1[a * HID + f] + hB1[b * HID + f] + hC1[c * HID + f]
                 + iv.x * w1c[0] + iv.y * w1c[1] + iv.z * w1c[2] + iv.w * w1c[3];
        float mm = hA2[a * HID + f] + hB2[b * HID + f] + hC2[c * HID + f]
                 + iv.x * w2c[0] + iv.y * w2c[1] + iv.z * w2c[2] + iv.w * w2c[3];
        z[(size_t)j * HID + f] = zz;
        m[(size_t)j * HID + f] = __float2bfloat16(mm);
    }
}

// -------- split segment sum
__global__ void segsum_split_k(const float* __restrict__ h, float* __restrict__ comb,
                               int per, int coloff, int S, int chunk) {
    int b = blockIdx.x;
    int g = b / S, s = b % S;
    int f = threadIdx.x;
    int r0 = s * chunk;
    int r1 = min(per, r0 + chunk);
    float acc = 0.f;
    const float* p = h + ((size_t)g * per + r0) * HID + f;
    for (int r = r0; r < r1; ++r) { acc += *p; p += HID; }
    atomicAdd(&comb[g * 192 + coloff + f], acc);
}

// -------- classifier
__global__ void classifier_k(const float* __restrict__ comb,
                             const float* __restrict__ cW1, const float* __restrict__ cb1,
                             const float* __restrict__ cW2, const float* __restrict__ cb2,
                             float* __restrict__ out) {
    __shared__ float row[192];
    __shared__ float hid[64];
    int g = blockIdx.x, t = threadIdx.x;
    for (int i = t; i < 192; i += 64) row[i] = comb[g * 192 + i];
    __syncthreads();
    float acc = cb1[t];
#pragma unroll 8
    for (int k = 0; k < 192; ++k) acc += row[k] * cW1[t * 192 + k];
    hid[t] = fmaxf(acc, 0.f);
    __syncthreads();
    if (t < 10) {
        float o = cb2[t];
#pragma unroll
        for (int k = 0; k < 64; ++k) o += hid[k] * cW2[t * 64 + k];
        out[g * 10 + t] = o;
    }
}

static inline int cdiv(long long a, long long b) { return (int)((a + b - 1) / b); }

extern "C" void kernel_launch(void* const* d_in, const int* in_sizes, int n_in,
                              void* d_out, int out_size, void* d_ws, size_t ws_size,
                              hipStream_t stream) {
    const float* x        = (const float*)d_in[0];
    const int*   eidx     = (const int*)d_in[1];
    const int*   gu2      = (const int*)d_in[3];
    const int*   gv2      = (const int*)d_in[4];
    const float* iso2     = (const float*)d_in[5];
    const int*   tedges   = (const int*)d_in[6];
    const int*   ga3      = (const int*)d_in[8];
    const int*   gb3      = (const int*)d_in[9];
    const int*   gc3      = (const int*)d_in[10];
    const float* iso3     = (const float*)d_in[11];
    const int*   hedges   = (const int*)d_in[12];
    const float* g1W1[3]  = {(const float*)d_in[14], (const float*)d_in[16], (const float*)d_in[18]};
    const float* g1W2[3]  = {(const float*)d_in[15], (const float*)d_in[17], (const float*)d_in[19]};
    const float* g2W1_0   = (const float*)d_in[20];
    const float* g2W2_0   = (const float*)d_in[21];
    const float* g2W1_1   = (const float*)d_in[22];
    const float* g2W2_1   = (const float*)d_in[23];
    const float* g3W1_0   = (const float*)d_in[24];
    const float* g3W2_0   = (const float*)d_in[25];
    const float* g3W1_1   = (const float*)d_in[26];
    const float* g3W2_1   = (const float*)d_in[27];
    const float* cW1      = (const float*)d_in[28];
    const float* cb1      = (const float*)d_in[29];
    const float* cW2      = (const float*)d_in[30];
    const float* cb2      = (const float*)d_in[31];
    float* out = (float*)d_out;

    const int N  = in_sizes[0] / 32;       // 2560
    const int E1 = in_sizes[1] / 2;
    const int n2 = in_sizes[3];            // 24320
    const int E2 = in_sizes[6] / 2;
    const int n3 = in_sizes[8];            // 145920
    const int E3 = in_sizes[12] / 2;
    const int G  = out_size / 10;          // 128
    const int per1 = N / G, per2 = n2 / G, per3 = n3 / G;

    // ---- workspace carve-up (float units)
    float* ws = (float*)d_ws;
    size_t off = 0;
    auto alloc = [&](size_t n) { float* p = ws + off; off += n; return p; };
    const size_t NH = (size_t)N * HID;
    float* nb0 = alloc(NH); float* nb1 = alloc(NH);
    bf16* mb1 = (bf16*)alloc(NH / 2 + 64);
    float* hU1 = alloc(NH); float* hV1 = alloc(NH); float* hU2 = alloc(NH); float* hV2 = alloc(NH);
    float* hA1 = alloc(NH); float* hB1 = alloc(NH); float* hC1 = alloc(NH);
    float* hA2 = alloc(NH); float* hB2 = alloc(NH); float* hC2 = alloc(NH);
    float* z2 = alloc((size_t)n2 * HID);
    bf16* m2b = (bf16*)alloc((size_t)n2 * HID / 2 + 64);
    float* z3 = alloc((size_t)n3 * HID);
    bf16* m3b = (bf16*)alloc((size_t)n3 * HID / 2 + 64);
    float* comb = alloc((size_t)G * 192);
    int* iws = (int*)(ws + off);
    size_t ioff = 0;
    auto ialloc = [&](size_t n) { int* p = iws + ioff; ioff += n; return p; };
    int* rs1 = ialloc(N + 1);  int* cur1 = ialloc(N);  int* csrc1 = ialloc(E1);
    int* rs2 = ialloc(n2 + 1); int* cur2 = ialloc(n2); int* csrc2 = ialloc(E2);
    int* rs3 = ialloc(n3 + 1); int* cur3 = ialloc(n3); int* csrc3 = ialloc(E3);
    int* bsum1 = ialloc(256); int* bsum2 = ialloc(256); int* bsum3 = ialloc(256);
    (void)ws_size;

    dim3 B256(256);
    auto gemm2b = [&](const float* in, const float* Wa, const float* Wb,
                      float* oa, bf16* ob, int R, int K, int ldw, int coloff) {
        int blocks = cdiv(cdiv(R, RPW), 4);
        if (K == 64)
            gemm2_regb<64><<<blocks, B256, 0, stream>>>(in, Wa, Wb, oa, ob, R, ldw, coloff);
        else
            gemm2_regb<32><<<blocks, B256, 0, stream>>>(in, Wa, Wb, oa, ob, R, ldw, coloff);
    };
    auto neigh = [&](const int* rs, const int* csrc, const bf16* m, float* z, int R) {
        int nb = cdiv(R, 8);
        int nb8 = cdiv(nb, 8);
        neighsum_relu_k<<<nb8 * 8, B256, 0, stream>>>(rs, csrc, (const bf162*)m, z, R, nb8);
    };
    auto segsum = [&](const float* h, int per, int coloff) {
        int chunk = 64;
        int S = cdiv(per, chunk);
        segsum_split_k<<<G * S, 64, 0, stream>>>(h, comb, per, coloff, S, chunk);
    };

    // ---- batched CSR build (7 dispatches; comb zero folded into first)
    int nz1 = cdiv(N, 256), nz2 = cdiv(n2, 256), nz3 = cdiv(n3, 256), nz4 = cdiv(G * 192, 256);
    zero4_k<<<nz1 + nz2 + nz3 + nz4, B256, 0, stream>>>(
        cur1, N, cur2, n2, cur3, n3, (int*)comb, G * 192, nz1, nz2, nz3);
    int ne1 = cdiv(E1, 256), ne2 = cdiv(E2, 256), ne3 = cdiv(E3, 256);
    hist3_k<<<ne1 + ne2 + ne3, B256, 0, stream>>>(
        eidx, E1, cur1, tedges, E2, cur2, hedges, E3, cur3, ne1, ne2);
    int ns1 = cdiv(N + 1, 1024), ns2 = cdiv(n2 + 1, 1024), ns3 = cdiv(n3 + 1, 1024);
    scan1_3k<<<ns1 + ns2 + ns3, B256, 0, stream>>>(
        cur1, rs1, bsum1, N + 1, N, cur2, rs2, bsum2, n2 + 1, n2,
        cur3, rs3, bsum3, n3 + 1, n3, ns1, ns2);
    scan2_3k<<<1, B256, 0, stream>>>(bsum1, ns1, bsum2, ns2, bsum3, ns3);
    int nc1 = cdiv(N + 1, 256), nc2 = cdiv(n2 + 1, 256), nc3 = cdiv(n3 + 1, 256);
    scan3_3k<<<nc1 + nc2 + nc3, B256, 0, stream>>>(
        rs1, bsum1, N + 1, rs2, bsum2, n2 + 1, rs3, bsum3, n3 + 1, nc1, nc2);
    zero4_k<<<nz1 + nz2 + nz3, B256, 0, stream>>>(
        cur1, N, cur2, n2, cur3, n3, nullptr, 0, nz1, nz2, nz3);
    fill3_k<<<ne1 + ne2 + ne3, B256, 0, stream>>>(
        eidx, E1, rs1, cur1, csrc1, tedges, E2, rs2, cur2, csrc2,
        hedges, E3, rs3, cur3, csrc3, ne1, ne2);

    // ================= level 1: node GNN (3 layers; bf16 messages) ==========
    const float* hcur = x;
    float* zb[2] = {nb0, nb1};
    for (int l = 0; l < 3; ++l) {
        int K = (l == 0) ? 32 : 64;
        float* z = zb[l & 1];
        gemm2b(hcur, g1W1[l], g1W2[l], z, mb1, N, K, K, 0);
        neigh(rs1, csrc1, mb1, z, N);
        hcur = z;
    }
    const float* h = hcur;   // = nb0 after 3 layers

    segsum(h, per1, 0);

    // ---- all 5 table GEMMs (hU,hV | hA,hB,hC) in ONE dispatch
    {
        TJobs5 jobs;
        jobs.j[0] = {g2W1_0, g2W2_0, hU1, hU2, 129, 0};
        jobs.j[1] = {g2W1_0, g2W2_0, hV1, hV2, 129, 64};
        jobs.j[2] = {g3W1_0, g3W2_0, hA1, hA2, 196, 0};
        jobs.j[3] = {g3W1_0, g3W2_0, hB1, hB2, 196, 64};
        jobs.j[4] = {g3W1_0, g3W2_0, hC1, hC2, 196, 128};
        int bpj = cdiv(cdiv(N, RPW), 4);
        gemm2_table<<<bpj * 5, B256, 0, stream>>>(h, jobs, N, bpj);
    }

    // ================= level 2: pair GNN (2 layers) =================
    {
        int jstep = cdiv(n2, 4);
        gatherZM2_k<<<cdiv((long long)jstep * 64, 256), B256, 0, stream>>>(
            hU1, hV1, hU2, hV2, gu2, gv2, iso2, g2W1_0, g2W2_0, z2, m2b, n2, jstep);
    }
    neigh(rs2, csrc2, m2b, z2, n2);
    gemm2b(z2, g2W1_1, g2W2_1, z2, m2b, n2, 64, 64, 0);   // in-place z2
    neigh(rs2, csrc2, m2b, z2, n2);
    segsum(z2, per2, 64);

    // ================= level 3: triple GNN (2 layers) =================
    {
        int jstep = cdiv(n3, 4);
        gatherZM3_k<<<cdiv((long long)jstep * 64, 256), B256, 0, stream>>>(
            hA1, hB1, hC1, hA2, hB2, hC2, ga3, gb3, gc3, iso3,
            g3W1_0, g3W2_0, z3, m3b, n3, jstep);
    }
    neigh(rs3, csrc3, m3b, z3, n3);
    gemm2b(z3, g3W1_1, g3W2_1, z3, m3b, n3, 64, 64, 0);   // in-place z3
    neigh(rs3, csrc3, m3b, z3, n3);
    segsum(z3, per3, 128);

    // ================= classifier =================
    classifier_k<<<G, 64, 0, stream>>>(comb, cW1, cb1, cW2, cb2, out);
}

// Round 18
// 436.578 us; speedup vs baseline: 1.4039x; 1.1220x over previous
//
#include <hip/hip_runtime.h>
#include <hip/hip_bf16.h>

#define HID 64
#define RPW 16   // rows per wave in scalar gemm kernels
#define KCH 8    // k-chunk width (W regs live at a time = 2*KCH)

typedef __hip_bfloat16  bf16;
typedef __hip_bfloat162 bf162;
typedef __attribute__((ext_vector_type(8))) short bf8v;   // 8 bf16 (4 VGPRs)
typedef __attribute__((ext_vector_type(4))) float f4v;    // MFMA acc
__device__ __forceinline__ float bl(bf16 h) { return __bfloat162float(h); }

// -------- scalar dual GEMM (level-1 + K=32 sites). R13-best config.
template <int KC>
__global__ __attribute__((amdgpu_flat_work_group_size(256, 256),
                          amdgpu_waves_per_eu(6, 6)))
void gemm2_regb(const float* in,
                const float* __restrict__ Wa, const float* __restrict__ Wb,
                float* outa, bf16* outb,
                int R, int ldw, int coloff) {
    int lane = threadIdx.x & 63;
    int wid = blockIdx.x * (blockDim.x >> 6) + (threadIdx.x >> 6);
    int j0 = __builtin_amdgcn_readfirstlane(wid * RPW);
    if (j0 >= R) return;
    float accx[RPW], accy[RPW];
#pragma unroll
    for (int r = 0; r < RPW; ++r) { accx[r] = 0.f; accy[r] = 0.f; }
    const float* pa = Wa + (size_t)lane * ldw + coloff;
    const float* pb = Wb + (size_t)lane * ldw + coloff;
#pragma unroll 1
    for (int kc = 0; kc < KC; kc += KCH) {
        float wx[KCH], wy[KCH];
#pragma unroll
        for (int kk = 0; kk < KCH; ++kk) { wx[kk] = pa[kc + kk]; wy[kk] = pb[kc + kk]; }
#pragma unroll
        for (int r = 0; r < RPW; ++r) {
            const float* rp = in + (size_t)(j0 + r) * KC + kc;
#pragma unroll
            for (int kk = 0; kk < KCH; ++kk) {
                float s = rp[kk];
                accx[r] = fmaf(s, wx[kk], accx[r]);
                accy[r] = fmaf(s, wy[kk], accy[r]);
            }
        }
    }
#pragma unroll
    for (int r = 0; r < RPW; ++r) {
        int j = j0 + r;
        outa[(size_t)j * HID + lane] = accx[r];
        outb[(size_t)j * HID + lane] = __float2bfloat16(accy[r]);
    }
}

// -------- MFMA dual GEMM (layer-1 of levels 2/3): bf16 input, K=64, 64 cols.
// outa[R][64](fp32) = in[R][64](bf16) @ Wa^T ; outb(bf16) same with Wb.
// Wa/Wb fp32 row-major 64x64, staged once to LDS as bf16 (+8 bf16 row pad
// -> 2-way bank alias only, free per m136). Layouts (HW-verified, m89/m120):
// A[m=lane&15][k=(lane>>4)*8+j]; C/D col=lane&15, row=(lane>>4)*4+reg.
// 32 rows/wave, 128 rows/block; all call-site R are multiples of 128.
__global__ __launch_bounds__(256)
void gemm2_mfma(const bf16* __restrict__ in,
                const float* __restrict__ Wa, const float* __restrict__ Wb,
                float* __restrict__ outa, bf16* __restrict__ outb, int R) {
    __shared__ bf16 wl1[64][72];
    __shared__ bf16 wl2[64][72];
    int t = threadIdx.x;
    {
        int n = t >> 2, k0 = (t & 3) * 16;
#pragma unroll
        for (int k = 0; k < 16; ++k) {
            wl1[n][k0 + k] = __float2bfloat16(Wa[n * 64 + k0 + k]);
            wl2[n][k0 + k] = __float2bfloat16(Wb[n * 64 + k0 + k]);
        }
    }
    __syncthreads();
    int lane = t & 63, wv = t >> 6;
    int quad = lane >> 4, m16 = lane & 15;
    int j0 = (blockIdx.x * 4 + wv) * 32;
    if (j0 >= R) return;
    bf8v a[2][2];
#pragma unroll
    for (int rt = 0; rt < 2; ++rt)
#pragma unroll
        for (int kt = 0; kt < 2; ++kt)
            a[rt][kt] = *(const bf8v*)(in + (size_t)(j0 + rt * 16 + m16) * 64
                                          + kt * 32 + quad * 8);
#pragma unroll
    for (int n = 0; n < 4; ++n) {
        bf8v b1k0 = *(const bf8v*)&wl1[n * 16 + m16][quad * 8];
        bf8v b1k1 = *(const bf8v*)&wl1[n * 16 + m16][32 + quad * 8];
        bf8v b2k0 = *(const bf8v*)&wl2[n * 16 + m16][quad * 8];
        bf8v b2k1 = *(const bf8v*)&wl2[n * 16 + m16][32 + quad * 8];
#pragma unroll
        for (int rt = 0; rt < 2; ++rt) {
            f4v acca = {0.f, 0.f, 0.f, 0.f};
            f4v accb = {0.f, 0.f, 0.f, 0.f};
            acca = __builtin_amdgcn_mfma_f32_16x16x32_bf16(a[rt][0], b1k0, acca, 0, 0, 0);
            acca = __builtin_amdgcn_mfma_f32_16x16x32_bf16(a[rt][1], b1k1, acca, 0, 0, 0);
            accb = __builtin_amdgcn_mfma_f32_16x16x32_bf16(a[rt][0], b2k0, accb, 0, 0, 0);
            accb = __builtin_amdgcn_mfma_f32_16x16x32_bf16(a[rt][1], b2k1, accb, 0, 0, 0);
            int col = n * 16 + m16;
#pragma unroll
            for (int r = 0; r < 4; ++r) {
                int row = j0 + rt * 16 + quad * 4 + r;
                outa[(size_t)row * 64 + col] = acca[r];
                outb[(size_t)row * 64 + col] = __float2bfloat16(accb[r]);
            }
        }
    }
}

// -------- batched table GEMM (5 jobs over h), R17 version.
struct TJob { const float* Wa; const float* Wb; float* oa; float* ob; int ldw; int coloff; };
struct TJobs5 { TJob j[5]; };

__global__ __attribute__((amdgpu_flat_work_group_size(256, 256),
                          amdgpu_waves_per_eu(6, 6)))
void gemm2_table(const float* in, TJobs5 jobs, int R, int bpj) {
    int jobi = blockIdx.x / bpj;
    int lb = blockIdx.x % bpj;
    TJob jb = jobs.j[jobi];
    int lane = threadIdx.x & 63;
    int wid = lb * 4 + (threadIdx.x >> 6);
    int j0 = __builtin_amdgcn_readfirstlane(wid * RPW);
    if (j0 >= R) return;
    float accx[RPW], accy[RPW];
#pragma unroll
    for (int r = 0; r < RPW; ++r) { accx[r] = 0.f; accy[r] = 0.f; }
    const float* pa = jb.Wa + (size_t)lane * jb.ldw + jb.coloff;
    const float* pb = jb.Wb + (size_t)lane * jb.ldw + jb.coloff;
#pragma unroll 1
    for (int kc = 0; kc < 64; kc += KCH) {
        float wx[KCH], wy[KCH];
#pragma unroll
        for (int kk = 0; kk < KCH; ++kk) { wx[kk] = pa[kc + kk]; wy[kk] = pb[kc + kk]; }
#pragma unroll
        for (int r = 0; r < RPW; ++r) {
            const float* rp = in + (size_t)(j0 + r) * 64 + kc;
#pragma unroll
            for (int kk = 0; kk < KCH; ++kk) {
                float s = rp[kk];
                accx[r] = fmaf(s, wx[kk], accx[r]);
                accy[r] = fmaf(s, wy[kk], accy[r]);
            }
        }
    }
#pragma unroll
    for (int r = 0; r < RPW; ++r) {
        int j = j0 + r;
        jb.oa[(size_t)j * HID + lane] = accx[r];
        jb.ob[(size_t)j * HID + lane] = accy[r];
    }
}

// ======== batched CSR build (unchanged) ========
__global__ void zero4_k(int* p1, int s1, int* p2, int s2, int* p3, int s3,
                        int* p4, int s4, int nb1, int nb2, int nb3) {
    int b = blockIdx.x; int* p; int n; int lb;
    if (b < nb1)                 { p = p1; n = s1; lb = b; }
    else if (b < nb1 + nb2)      { p = p2; n = s2; lb = b - nb1; }
    else if (b < nb1 + nb2 + nb3){ p = p3; n = s3; lb = b - nb1 - nb2; }
    else                         { p = p4; n = s4; lb = b - nb1 - nb2 - nb3; }
    int i = lb * 256 + threadIdx.x;
    if (i < n) p[i] = 0;
}

__global__ void hist3_k(const int* e1, int E1, int* c1,
                        const int* e2, int E2, int* c2,
                        const int* e3, int E3, int* c3, int nb1, int nb2) {
    int b = blockIdx.x; const int* dst; int* c; int E; int lb;
    if (b < nb1)            { dst = e1 + E1; c = c1; E = E1; lb = b; }
    else if (b < nb1 + nb2) { dst = e2 + E2; c = c2; E = E2; lb = b - nb1; }
    else                    { dst = e3 + E3; c = c3; E = E3; lb = b - nb1 - nb2; }
    int e = lb * 256 + threadIdx.x;
    if (e < E) atomicAdd(&c[dst[e]], 1);
}

__device__ __forceinline__ void scan1_body(const int* __restrict__ cnt, int* __restrict__ rs,
                                           int* __restrict__ bsum, int n1, int n, int lb) {
    __shared__ int wsum[4];
    int t = threadIdx.x;
    int base = lb * 1024 + t * 4;
    int v[4]; int s = 0;
#pragma unroll
    for (int i = 0; i < 4; ++i) { int idx = base + i; v[i] = s; s += (idx < n) ? cnt[idx] : 0; }
    int lane = t & 63, wv = t >> 6;
    int x = s;
#pragma unroll
    for (int off = 1; off < 64; off <<= 1) { int y = __shfl_up(x, off, 64); if (lane >= off) x += y; }
    if (lane == 63) wsum[wv] = x;
    __syncthreads();
    int woff = 0;
    for (int w = 0; w < wv; ++w) woff += wsum[w];
    int excl = woff + (x - s);
#pragma unroll
    for (int i = 0; i < 4; ++i) { int idx = base + i; if (idx < n1) rs[idx] = excl + v[i]; }
    if (t == 255) bsum[lb] = wsum[0] + wsum[1] + wsum[2] + wsum[3];
}

__global__ void scan1_3k(const int* c1, int* r1, int* b1, int n1a, int na,
                         const int* c2, int* r2, int* b2, int n1b, int nb,
                         const int* c3, int* r3, int* b3, int n1c, int nc,
                         int nbl1, int nbl2) {
    int b = blockIdx.x;
    if (b < nbl1)             scan1_body(c1, r1, b1, n1a, na, b);
    else if (b < nbl1 + nbl2) scan1_body(c2, r2, b2, n1b, nb, b - nbl1);
    else                      scan1_body(c3, r3, b3, n1c, nc, b - nbl1 - nbl2);
}

__device__ __forceinline__ void scan2_body(int* bsum, int nb, int* wsum) {
    int t = threadIdx.x;
    int s = (t < nb) ? bsum[t] : 0;
    int lane = t & 63, wv = t >> 6;
    int x = s;
#pragma unroll
    for (int off = 1; off < 64; off <<= 1) { int y = __shfl_up(x, off, 64); if (lane >= off) x += y; }
    if (lane == 63) wsum[wv] = x;
    __syncthreads();
    int woff = 0;
    for (int w = 0; w < wv; ++w) woff += wsum[w];
    if (t < nb) bsum[t] = woff + x - s;
    __syncthreads();
}

__global__ void scan2_3k(int* b1, int nb1, int* b2, int nb2, int* b3, int nb3) {
    __shared__ int wsum[4];
    scan2_body(b1, nb1, wsum);
    scan2_body(b2, nb2, wsum);
    scan2_body(b3, nb3, wsum);
}

__global__ void scan3_3k(int* r1, const int* b1, int n1a,
                         int* r2, const int* b2, int n1b,
                         int* r3, const int* b3, int n1c, int nc1, int nc2) {
    int b = blockIdx.x; int* rs; const int* bsum; int n1; int lb;
    if (b < nc1)            { rs = r1; bsum = b1; n1 = n1a; lb = b; }
    else if (b < nc1 + nc2) { rs = r2; bsum = b2; n1 = n1b; lb = b - nc1; }
    else                    { rs = r3; bsum = b3; n1 = n1c; lb = b - nc1 - nc2; }
    int i = lb * 256 + threadIdx.x;
    if (i < n1) rs[i] += bsum[lb >> 2];
}

__global__ void fill3_k(const int* e1, int E1, const int* r1, int* c1, int* s1,
                        const int* e2, int E2, const int* r2, int* c2, int* s2,
                        const int* e3, int E3, const int* r3, int* c3, int* s3,
                        int nb1, int nb2) {
    int b = blockIdx.x;
    const int* edges; int E; const int* rs; int* cur; int* csrc; int lb;
    if (b < nb1)            { edges = e1; E = E1; rs = r1; cur = c1; csrc = s1; lb = b; }
    else if (b < nb1 + nb2) { edges = e2; E = E2; rs = r2; cur = c2; csrc = s2; lb = b - nb1; }
    else                    { edges = e3; E = E3; rs = r3; cur = c3; csrc = s3; lb = b - nb1 - nb2; }
    int e = lb * 256 + threadIdx.x;
    if (e >= E) return;
    int d = edges[E + e];
    int p = rs[d] + atomicAdd(&cur[d], 1);
    csrc[p] = edges[e];
}

// -------- gather + relu with bf16 messages; output fp32 (TZ=float2) or
// bf16 (TZ=bf162, for layer-0 outputs that feed the MFMA gemm).
__device__ __forceinline__ void storez(float2* p, float ax, float ay) {
    *p = make_float2(ax, ay);
}
__device__ __forceinline__ void storez(bf162* p, float ax, float ay) {
    bf162 v; v.x = __float2bfloat16(ax); v.y = __float2bfloat16(ay); *p = v;
}

template <typename TZ>
__global__ void neighsum_relu_k(const int* __restrict__ rs, const int* __restrict__ csrc,
                                const bf162* __restrict__ m,
                                const float* __restrict__ zin, TZ* __restrict__ zout,
                                int R, int nb8) {
    int b = (int)(blockIdx.x & 7) * nb8 + (int)(blockIdx.x >> 3);
    int t = threadIdx.x;
    int wv = t >> 6, lane = t & 63;
    int j = b * 8 + wv * 2 + (lane >> 5);
    int f2 = lane & 31;
    if (j >= R) return;
    const float2* zi = (const float2*)zin;
    int s = rs[j], e = rs[j + 1];
    float2 a = zi[(size_t)j * 32 + f2];
    float ax = a.x, ay = a.y;
    int k = s;
    for (; k + 8 <= e; k += 8) {
        int i0 = csrc[k],     i1 = csrc[k + 1], i2 = csrc[k + 2], i3 = csrc[k + 3];
        int i4 = csrc[k + 4], i5 = csrc[k + 5], i6 = csrc[k + 6], i7 = csrc[k + 7];
        bf162 v0 = m[(size_t)i0 * 32 + f2], v1 = m[(size_t)i1 * 32 + f2];
        bf162 v2 = m[(size_t)i2 * 32 + f2], v3 = m[(size_t)i3 * 32 + f2];
        bf162 v4 = m[(size_t)i4 * 32 + f2], v5 = m[(size_t)i5 * 32 + f2];
        bf162 v6 = m[(size_t)i6 * 32 + f2], v7 = m[(size_t)i7 * 32 + f2];
        ax += ((bl(v0.x) + bl(v1.x)) + (bl(v2.x) + bl(v3.x)))
            + ((bl(v4.x) + bl(v5.x)) + (bl(v6.x) + bl(v7.x)));
        ay += ((bl(v0.y) + bl(v1.y)) + (bl(v2.y) + bl(v3.y)))
            + ((bl(v4.y) + bl(v5.y)) + (bl(v6.y) + bl(v7.y)));
    }
    for (; k + 4 <= e; k += 4) {
        int i0 = csrc[k], i1 = csrc[k + 1], i2 = csrc[k + 2], i3 = csrc[k + 3];
        bf162 v0 = m[(size_t)i0 * 32 + f2], v1 = m[(size_t)i1 * 32 + f2];
        bf162 v2 = m[(size_t)i2 * 32 + f2], v3 = m[(size_t)i3 * 32 + f2];
        ax += (bl(v0.x) + bl(v1.x)) + (bl(v2.x) + bl(v3.x));
        ay += (bl(v0.y) + bl(v1.y)) + (bl(v2.y) + bl(v3.y));
    }
    for (; k < e; ++k) {
        bf162 v = m[(size_t)csrc[k] * 32 + f2];
        ax += bl(v.x); ay += bl(v.y);
    }
    storez(&zout[(size_t)j * 32 + f2], fmaxf(ax, 0.f), fmaxf(ay, 0.f));
}

// -------- level-2 layer-0 combined gather: z-init (fp32) + m (bf16)
__global__ void gatherZM2_k(const float* __restrict__ hU1, const float* __restrict__ hV1,
                            const float* __restrict__ hU2, const float* __restrict__ hV2,
                            const int* __restrict__ gu, const int* __restrict__ gv,
                            const float* __restrict__ iso2,
                            const float* __restrict__ W1, const float* __restrict__ W2,
                            float* __restrict__ z, bf16* __restrict__ m,
                            int n2, int jstep) {
    int idx = blockIdx.x * 256 + threadIdx.x;
    int j = idx >> 6, f = idx & 63;
    float w1c = W1[f * 129 + 128], w2c = W2[f * 129 + 128];
#pragma unroll
    for (int r = 0; r < 4; ++r, j += jstep) {
        if (j >= n2) return;
        int u = gu[j], v = gv[j];
        float is = iso2[j];
        z[(size_t)j * HID + f] = hU1[u * HID + f] + hV1[v * HID + f] + is * w1c;
        m[(size_t)j * HID + f] =
            __float2bfloat16(hU2[u * HID + f] + hV2[v * HID + f] + is * w2c);
    }
}

// -------- level-3 layer-0 combined gather (iso3 one-hot x4)
__global__ void gatherZM3_k(const float* __restrict__ hA1, const float* __restrict__ hB1,
                            const float* __restrict__ hC1,
                            const float* __restrict__ hA2, const float* __restrict__ hB2,
                            const float* __restrict__ hC2,
                            const int* __restrict__ ga, const int* __restrict__ gb,
                            const int* __restrict__ gc, const float* __restrict__ iso3,
                            const float* __restrict__ W1, const float* __restrict__ W2,
                            float* __restrict__ z, bf16* __restrict__ m,
                            int n3, int jstep) {
    int idx = blockIdx.x * 256 + threadIdx.x;
    int j = idx >> 6, f = idx & 63;
    float w1c[4], w2c[4];
#pragma unroll
    for (int c = 0; c < 4; ++c) {
        w1c[c] = W1[f * 196 + 192 + c];
        w2c[c] = W2[f * 196 + 192 + c];
    }
    const float4* I4 = (const float4*)iso3;
#pragma unroll
    for (int r = 0; r < 4; ++r, j += jstep) {
        if (j >= n3) return;
        int a = ga[j], b = gb[j], c = gc[j];
        float4 iv = I4[j];
        float zz = hA1[a * HID + f] + hB1[b * HID + f] + hC1[c * HID + f]
                 + iv.x * w1c[0] + iv.y * w1c[1] + iv.z * w1c[2] + iv.w * w1c[3];
        float mm = hA2[a * HID + f] + hB2[b * HID + f] + hC2[c * HID + f]
                 + iv.x * w2c[0] + iv.y * w2c[1] + iv.z * w2c[2] + iv.w * w2c[3];
        z[(size_t)j * HID + f] = zz;
        m[(size_t)j * HID + f] = __float2bfloat16(mm);
    }
}

// -------- split segment sum
__global__ void segsum_split_k(const float* __restrict__ h, float* __restrict__ comb,
                               int per, int coloff, int S, int chunk) {
    int b = blockIdx.x;
    int g = b / S, s = b % S;
    int f = threadIdx.x;
    int r0 = s * chunk;
    int r1 = min(per, r0 + chunk);
    float acc = 0.f;
    const float* p = h + ((size_t)g * per + r0) * HID + f;
    for (int r = r0; r < r1; ++r) { acc += *p; p += HID; }
    atomicAdd(&comb[g * 192 + coloff + f], acc);
}

// -------- classifier
__global__ void classifier_k(const float* __restrict__ comb,
                             const float* __restrict__ cW1, const float* __restrict__ cb1,
                             const float* __restrict__ cW2, const float* __restrict__ cb2,
                             float* __restrict__ out) {
    __shared__ float row[192];
    __shared__ float hid[64];
    int g = blockIdx.x, t = threadIdx.x;
    for (int i = t; i < 192; i += 64) row[i] = comb[g * 192 + i];
    __syncthreads();
    float acc = cb1[t];
#pragma unroll 8
    for (int k = 0; k < 192; ++k) acc += row[k] * cW1[t * 192 + k];
    hid[t] = fmaxf(acc, 0.f);
    __syncthreads();
    if (t < 10) {
        float o = cb2[t];
#pragma unroll
        for (int k = 0; k < 64; ++k) o += hid[k] * cW2[t * 64 + k];
        out[g * 10 + t] = o;
    }
}

static inline int cdiv(long long a, long long b) { return (int)((a + b - 1) / b); }

extern "C" void kernel_launch(void* const* d_in, const int* in_sizes, int n_in,
                              void* d_out, int out_size, void* d_ws, size_t ws_size,
                              hipStream_t stream) {
    const float* x        = (const float*)d_in[0];
    const int*   eidx     = (const int*)d_in[1];
    const int*   gu2      = (const int*)d_in[3];
    const int*   gv2      = (const int*)d_in[4];
    const float* iso2     = (const float*)d_in[5];
    const int*   tedges   = (const int*)d_in[6];
    const int*   ga3      = (const int*)d_in[8];
    const int*   gb3      = (const int*)d_in[9];
    const int*   gc3      = (const int*)d_in[10];
    const float* iso3     = (const float*)d_in[11];
    const int*   hedges   = (const int*)d_in[12];
    const float* g1W1[3]  = {(const float*)d_in[14], (const float*)d_in[16], (const float*)d_in[18]};
    const float* g1W2[3]  = {(const float*)d_in[15], (const float*)d_in[17], (const float*)d_in[19]};
    const float* g2W1_0   = (const float*)d_in[20];
    const float* g2W2_0   = (const float*)d_in[21];
    const float* g2W1_1   = (const float*)d_in[22];
    const float* g2W2_1   = (const float*)d_in[23];
    const float* g3W1_0   = (const float*)d_in[24];
    const float* g3W2_0   = (const float*)d_in[25];
    const float* g3W1_1   = (const float*)d_in[26];
    const float* g3W2_1   = (const float*)d_in[27];
    const float* cW1      = (const float*)d_in[28];
    const float* cb1      = (const float*)d_in[29];
    const float* cW2      = (const float*)d_in[30];
    const float* cb2      = (const float*)d_in[31];
    float* out = (float*)d_out;

    const int N  = in_sizes[0] / 32;       // 2560
    const int E1 = in_sizes[1] / 2;
    const int n2 = in_sizes[3];            // 24320
    const int E2 = in_sizes[6] / 2;
    const int n3 = in_sizes[8];            // 145920
    const int E3 = in_sizes[12] / 2;
    const int G  = out_size / 10;          // 128
    const int per1 = N / G, per2 = n2 / G, per3 = n3 / G;

    // ---- workspace carve-up (float units, 16B-aligned blocks)
    float* ws = (float*)d_ws;
    size_t off = 0;
    auto alloc = [&](size_t n) { off = (off + 3) & ~(size_t)3; float* p = ws + off; off += n; return p; };
    const size_t NH = (size_t)N * HID;
    float* nb0 = alloc(NH); float* nb1 = alloc(NH);
    bf16* mb1 = (bf16*)alloc(NH / 2 + 64);
    float* hU1 = alloc(NH); float* hV1 = alloc(NH); float* hU2 = alloc(NH); float* hV2 = alloc(NH);
    float* hA1 = alloc(NH); float* hB1 = alloc(NH); float* hC1 = alloc(NH);
    float* hA2 = alloc(NH); float* hB2 = alloc(NH); float* hC2 = alloc(NH);
    float* z2 = alloc((size_t)n2 * HID);
    bf16* m2b = (bf16*)alloc((size_t)n2 * HID / 2 + 64);
    bf16* z2b = (bf16*)alloc((size_t)n2 * HID / 2 + 64);
    float* z3 = alloc((size_t)n3 * HID);
    bf16* m3b = (bf16*)alloc((size_t)n3 * HID / 2 + 64);
    bf16* z3b = (bf16*)alloc((size_t)n3 * HID / 2 + 64);
    float* comb = alloc((size_t)G * 192);
    int* iws = (int*)(ws + off);
    size_t ioff = 0;
    auto ialloc = [&](size_t n) { int* p = iws + ioff; ioff += n; return p; };
    int* rs1 = ialloc(N + 1);  int* cur1 = ialloc(N);  int* csrc1 = ialloc(E1);
    int* rs2 = ialloc(n2 + 1); int* cur2 = ialloc(n2); int* csrc2 = ialloc(E2);
    int* rs3 = ialloc(n3 + 1); int* cur3 = ialloc(n3); int* csrc3 = ialloc(E3);
    int* bsum1 = ialloc(256); int* bsum2 = ialloc(256); int* bsum3 = ialloc(256);
    (void)ws_size;

    dim3 B256(256);
    auto gemm2b = [&](const float* in, const float* Wa, const float* Wb,
                      float* oa, bf16* ob, int R, int K, int ldw, int coloff) {
        int blocks = cdiv(cdiv(R, RPW), 4);
        if (K == 64)
            gemm2_regb<64><<<blocks, B256, 0, stream>>>(in, Wa, Wb, oa, ob, R, ldw, coloff);
        else
            gemm2_regb<32><<<blocks, B256, 0, stream>>>(in, Wa, Wb, oa, ob, R, ldw, coloff);
    };
    auto gemm_mfma = [&](const bf16* in, const float* Wa, const float* Wb,
                         float* oa, bf16* ob, int R) {
        gemm2_mfma<<<cdiv(R, 128), B256, 0, stream>>>(in, Wa, Wb, oa, ob, R);
    };
    auto neighf = [&](const int* rs, const int* csrc, const bf16* m,
                      const float* zi, float* zo, int R) {
        int nb = cdiv(R, 8); int nb8 = cdiv(nb, 8);
        neighsum_relu_k<float2><<<nb8 * 8, B256, 0, stream>>>(
            rs, csrc, (const bf162*)m, zi, (float2*)zo, R, nb8);
    };
    auto neighb = [&](const int* rs, const int* csrc, const bf16* m,
                      const float* zi, bf16* zo, int R) {
        int nb = cdiv(R, 8); int nb8 = cdiv(nb, 8);
        neighsum_relu_k<bf162><<<nb8 * 8, B256, 0, stream>>>(
            rs, csrc, (const bf162*)m, zi, (bf162*)zo, R, nb8);
    };
    auto segsum = [&](const float* h, int per, int coloff) {
        int chunk = 64;
        int S = cdiv(per, chunk);
        segsum_split_k<<<G * S, 64, 0, stream>>>(h, comb, per, coloff, S, chunk);
    };

    // ---- batched CSR build (7 dispatches; comb zero folded into first)
    int nz1 = cdiv(N, 256), nz2 = cdiv(n2, 256), nz3 = cdiv(n3, 256), nz4 = cdiv(G * 192, 256);
    zero4_k<<<nz1 + nz2 + nz3 + nz4, B256, 0, stream>>>(
        cur1, N, cur2, n2, cur3, n3, (int*)comb, G * 192, nz1, nz2, nz3);
    int ne1 = cdiv(E1, 256), ne2 = cdiv(E2, 256), ne3 = cdiv(E3, 256);
    hist3_k<<<ne1 + ne2 + ne3, B256, 0, stream>>>(
        eidx, E1, cur1, tedges, E2, cur2, hedges, E3, cur3, ne1, ne2);
    int ns1 = cdiv(N + 1, 1024), ns2 = cdiv(n2 + 1, 1024), ns3 = cdiv(n3 + 1, 1024);
    scan1_3k<<<ns1 + ns2 + ns3, B256, 0, stream>>>(
        cur1, rs1, bsum1, N + 1, N, cur2, rs2, bsum2, n2 + 1, n2,
        cur3, rs3, bsum3, n3 + 1, n3, ns1, ns2);
    scan2_3k<<<1, B256, 0, stream>>>(bsum1, ns1, bsum2, ns2, bsum3, ns3);
    int nc1 = cdiv(N + 1, 256), nc2 = cdiv(n2 + 1, 256), nc3 = cdiv(n3 + 1, 256);
    scan3_3k<<<nc1 + nc2 + nc3, B256, 0, stream>>>(
        rs1, bsum1, N + 1, rs2, bsum2, n2 + 1, rs3, bsum3, n3 + 1, nc1, nc2);
    zero4_k<<<nz1 + nz2 + nz3, B256, 0, stream>>>(
        cur1, N, cur2, n2, cur3, n3, nullptr, 0, nz1, nz2, nz3);
    fill3_k<<<ne1 + ne2 + ne3, B256, 0, stream>>>(
        eidx, E1, rs1, cur1, csrc1, tedges, E2, rs2, cur2, csrc2,
        hedges, E3, rs3, cur3, csrc3, ne1, ne2);

    // ================= level 1: node GNN (3 layers; scalar gemm) ==========
    const float* hcur = x;
    float* zb[2] = {nb0, nb1};
    for (int l = 0; l < 3; ++l) {
        int K = (l == 0) ? 32 : 64;
        float* z = zb[l & 1];
        gemm2b(hcur, g1W1[l], g1W2[l], z, mb1, N, K, K, 0);
        neighf(rs1, csrc1, mb1, z, z, N);
        hcur = z;
    }
    const float* h = hcur;   // = nb0 after 3 layers

    segsum(h, per1, 0);

    // ---- all 5 table GEMMs in ONE dispatch
    {
        TJobs5 jobs;
        jobs.j[0] = {g2W1_0, g2W2_0, hU1, hU2, 129, 0};
        jobs.j[1] = {g2W1_0, g2W2_0, hV1, hV2, 129, 64};
        jobs.j[2] = {g3W1_0, g3W2_0, hA1, hA2, 196, 0};
        jobs.j[3] = {g3W1_0, g3W2_0, hB1, hB2, 196, 64};
        jobs.j[4] = {g3W1_0, g3W2_0, hC1, hC2, 196, 128};
        int bpj = cdiv(cdiv(N, RPW), 4);
        gemm2_table<<<bpj * 5, B256, 0, stream>>>(h, jobs, N, bpj);
    }

    // ================= level 2: pair GNN (2 layers) =================
    {
        int jstep = cdiv(n2, 4);
        gatherZM2_k<<<cdiv((long long)jstep * 64, 256), B256, 0, stream>>>(
            hU1, hV1, hU2, hV2, gu2, gv2, iso2, g2W1_0, g2W2_0, z2, m2b, n2, jstep);
    }
    neighb(rs2, csrc2, m2b, z2, z2b, n2);                 // layer-0 out -> bf16
    gemm_mfma(z2b, g2W1_1, g2W2_1, z2, m2b, n2);          // MFMA dual gemm
    neighf(rs2, csrc2, m2b, z2, z2, n2);
    segsum(z2, per2, 64);

    // ================= level 3: triple GNN (2 layers) =================
    {
        int jstep = cdiv(n3, 4);
        gatherZM3_k<<<cdiv((long long)jstep * 64, 256), B256, 0, stream>>>(
            hA1, hB1, hC1, hA2, hB2, hC2, ga3, gb3, gc3, iso3,
            g3W1_0, g3W2_0, z3, m3b, n3, jstep);
    }
    neighb(rs3, csrc3, m3b, z3, z3b, n3);                 // layer-0 out -> bf16
    gemm_mfma(z3b, g3W1_1, g3W2_1, z3, m3b, n3);          // MFMA dual gemm
    neighf(rs3, csrc3, m3b, z3, z3, n3);
    segsum(z3, per3, 128);

    // ================= classifier =================
    classifier_k<<<G, 64, 0, stream>>>(comb, cW1, cb1, cW2, cb2, out);
}

// Round 19
// 409.001 us; speedup vs baseline: 1.4985x; 1.0674x over previous
//
#include <hip/hip_runtime.h>
#include <hip/hip_bf16.h>

#define HID 64
#define RPW 16   // rows per wave in scalar gemm kernels
#define KCH 8    // k-chunk width (W regs live at a time = 2*KCH)

typedef __hip_bfloat16  bf16;
typedef __hip_bfloat162 bf162;
typedef __attribute__((ext_vector_type(8))) short bf8v;   // 8 bf16 (4 VGPRs)
typedef __attribute__((ext_vector_type(4))) float f4v;    // MFMA acc
__device__ __forceinline__ float bl(bf16 h) { return __bfloat162float(h); }

// -------- scalar dual GEMM (level-1 + K=32 sites). R13-best config.
template <int KC>
__global__ __attribute__((amdgpu_flat_work_group_size(256, 256),
                          amdgpu_waves_per_eu(6, 6)))
void gemm2_regb(const float* in,
                const float* __restrict__ Wa, const float* __restrict__ Wb,
                float* outa, bf16* outb,
                int R, int ldw, int coloff) {
    int lane = threadIdx.x & 63;
    int wid = blockIdx.x * (blockDim.x >> 6) + (threadIdx.x >> 6);
    int j0 = __builtin_amdgcn_readfirstlane(wid * RPW);
    if (j0 >= R) return;
    float accx[RPW], accy[RPW];
#pragma unroll
    for (int r = 0; r < RPW; ++r) { accx[r] = 0.f; accy[r] = 0.f; }
    const float* pa = Wa + (size_t)lane * ldw + coloff;
    const float* pb = Wb + (size_t)lane * ldw + coloff;
#pragma unroll 1
    for (int kc = 0; kc < KC; kc += KCH) {
        float wx[KCH], wy[KCH];
#pragma unroll
        for (int kk = 0; kk < KCH; ++kk) { wx[kk] = pa[kc + kk]; wy[kk] = pb[kc + kk]; }
#pragma unroll
        for (int r = 0; r < RPW; ++r) {
            const float* rp = in + (size_t)(j0 + r) * KC + kc;
#pragma unroll
            for (int kk = 0; kk < KCH; ++kk) {
                float s = rp[kk];
                accx[r] = fmaf(s, wx[kk], accx[r]);
                accy[r] = fmaf(s, wy[kk], accy[r]);
            }
        }
    }
#pragma unroll
    for (int r = 0; r < RPW; ++r) {
        int j = j0 + r;
        outa[(size_t)j * HID + lane] = accx[r];
        outb[(size_t)j * HID + lane] = __float2bfloat16(accy[r]);
    }
}

// -------- MFMA dual GEMM body (R18-verified layouts m89/m120).
struct MJob { const bf16* in; const float* Wa; const float* Wb; float* oa; bf16* ob; int R; int nblocks; };

__device__ __forceinline__ void mfma_body(const MJob& jb, int blk, int t) {
    __shared__ bf16 wl1[64][72];
    __shared__ bf16 wl2[64][72];
    {
        int n = t >> 2, k0 = (t & 3) * 16;
#pragma unroll
        for (int k = 0; k < 16; ++k) {
            wl1[n][k0 + k] = __float2bfloat16(jb.Wa[n * 64 + k0 + k]);
            wl2[n][k0 + k] = __float2bfloat16(jb.Wb[n * 64 + k0 + k]);
        }
    }
    __syncthreads();
    int lane = t & 63, wv = t >> 6;
    int quad = lane >> 4, m16 = lane & 15;
    int j0 = (blk * 4 + wv) * 32;
    if (j0 >= jb.R) return;
    bf8v a[2][2];
#pragma unroll
    for (int rt = 0; rt < 2; ++rt)
#pragma unroll
        for (int kt = 0; kt < 2; ++kt)
            a[rt][kt] = *(const bf8v*)(jb.in + (size_t)(j0 + rt * 16 + m16) * 64
                                             + kt * 32 + quad * 8);
#pragma unroll
    for (int n = 0; n < 4; ++n) {
        bf8v b1k0 = *(const bf8v*)&wl1[n * 16 + m16][quad * 8];
        bf8v b1k1 = *(const bf8v*)&wl1[n * 16 + m16][32 + quad * 8];
        bf8v b2k0 = *(const bf8v*)&wl2[n * 16 + m16][quad * 8];
        bf8v b2k1 = *(const bf8v*)&wl2[n * 16 + m16][32 + quad * 8];
#pragma unroll
        for (int rt = 0; rt < 2; ++rt) {
            f4v acca = {0.f, 0.f, 0.f, 0.f};
            f4v accb = {0.f, 0.f, 0.f, 0.f};
            acca = __builtin_amdgcn_mfma_f32_16x16x32_bf16(a[rt][0], b1k0, acca, 0, 0, 0);
            acca = __builtin_amdgcn_mfma_f32_16x16x32_bf16(a[rt][1], b1k1, acca, 0, 0, 0);
            accb = __builtin_amdgcn_mfma_f32_16x16x32_bf16(a[rt][0], b2k0, accb, 0, 0, 0);
            accb = __builtin_amdgcn_mfma_f32_16x16x32_bf16(a[rt][1], b2k1, accb, 0, 0, 0);
            int col = n * 16 + m16;
#pragma unroll
            for (int r = 0; r < 4; ++r) {
                int row = j0 + rt * 16 + quad * 4 + r;
                jb.oa[(size_t)row * 64 + col] = acca[r];
                jb.ob[(size_t)row * 64 + col] = __float2bfloat16(accb[r]);
            }
        }
    }
}

// merged L3+L2 MFMA dispatch (independent jobs, block-range partitioned)
__global__ __launch_bounds__(256)
void gemm2_mfma2(MJob j3, MJob j2) {
    if ((int)blockIdx.x < j3.nblocks) mfma_body(j3, blockIdx.x, threadIdx.x);
    else                              mfma_body(j2, blockIdx.x - j3.nblocks, threadIdx.x);
}

// -------- batched table GEMM (5 jobs over h), R17 version.
struct TJob { const float* Wa; const float* Wb; float* oa; float* ob; int ldw; int coloff; };
struct TJobs5 { TJob j[5]; };

__global__ __attribute__((amdgpu_flat_work_group_size(256, 256),
                          amdgpu_waves_per_eu(6, 6)))
void gemm2_table(const float* in, TJobs5 jobs, int R, int bpj) {
    int jobi = blockIdx.x / bpj;
    int lb = blockIdx.x % bpj;
    TJob jb = jobs.j[jobi];
    int lane = threadIdx.x & 63;
    int wid = lb * 4 + (threadIdx.x >> 6);
    int j0 = __builtin_amdgcn_readfirstlane(wid * RPW);
    if (j0 >= R) return;
    float accx[RPW], accy[RPW];
#pragma unroll
    for (int r = 0; r < RPW; ++r) { accx[r] = 0.f; accy[r] = 0.f; }
    const float* pa = jb.Wa + (size_t)lane * jb.ldw + jb.coloff;
    const float* pb = jb.Wb + (size_t)lane * jb.ldw + jb.coloff;
#pragma unroll 1
    for (int kc = 0; kc < 64; kc += KCH) {
        float wx[KCH], wy[KCH];
#pragma unroll
        for (int kk = 0; kk < KCH; ++kk) { wx[kk] = pa[kc + kk]; wy[kk] = pb[kc + kk]; }
#pragma unroll
        for (int r = 0; r < RPW; ++r) {
            const float* rp = in + (size_t)(j0 + r) * 64 + kc;
#pragma unroll
            for (int kk = 0; kk < KCH; ++kk) {
                float s = rp[kk];
                accx[r] = fmaf(s, wx[kk], accx[r]);
                accy[r] = fmaf(s, wy[kk], accy[r]);
            }
        }
    }
#pragma unroll
    for (int r = 0; r < RPW; ++r) {
        int j = j0 + r;
        jb.oa[(size_t)j * HID + lane] = accx[r];
        jb.ob[(size_t)j * HID + lane] = accy[r];
    }
}

// ======== batched CSR build (unchanged) ========
__global__ void zero4_k(int* p1, int s1, int* p2, int s2, int* p3, int s3,
                        int* p4, int s4, int nb1, int nb2, int nb3) {
    int b = blockIdx.x; int* p; int n; int lb;
    if (b < nb1)                 { p = p1; n = s1; lb = b; }
    else if (b < nb1 + nb2)      { p = p2; n = s2; lb = b - nb1; }
    else if (b < nb1 + nb2 + nb3){ p = p3; n = s3; lb = b - nb1 - nb2; }
    else                         { p = p4; n = s4; lb = b - nb1 - nb2 - nb3; }
    int i = lb * 256 + threadIdx.x;
    if (i < n) p[i] = 0;
}

__global__ void hist3_k(const int* e1, int E1, int* c1,
                        const int* e2, int E2, int* c2,
                        const int* e3, int E3, int* c3, int nb1, int nb2) {
    int b = blockIdx.x; const int* dst; int* c; int E; int lb;
    if (b < nb1)            { dst = e1 + E1; c = c1; E = E1; lb = b; }
    else if (b < nb1 + nb2) { dst = e2 + E2; c = c2; E = E2; lb = b - nb1; }
    else                    { dst = e3 + E3; c = c3; E = E3; lb = b - nb1 - nb2; }
    int e = lb * 256 + threadIdx.x;
    if (e < E) atomicAdd(&c[dst[e]], 1);
}

__device__ __forceinline__ void scan1_body(const int* __restrict__ cnt, int* __restrict__ rs,
                                           int* __restrict__ bsum, int n1, int n, int lb) {
    __shared__ int wsum[4];
    int t = threadIdx.x;
    int base = lb * 1024 + t * 4;
    int v[4]; int s = 0;
#pragma unroll
    for (int i = 0; i < 4; ++i) { int idx = base + i; v[i] = s; s += (idx < n) ? cnt[idx] : 0; }
    int lane = t & 63, wv = t >> 6;
    int x = s;
#pragma unroll
    for (int off = 1; off < 64; off <<= 1) { int y = __shfl_up(x, off, 64); if (lane >= off) x += y; }
    if (lane == 63) wsum[wv] = x;
    __syncthreads();
    int woff = 0;
    for (int w = 0; w < wv; ++w) woff += wsum[w];
    int excl = woff + (x - s);
#pragma unroll
    for (int i = 0; i < 4; ++i) { int idx = base + i; if (idx < n1) rs[idx] = excl + v[i]; }
    if (t == 255) bsum[lb] = wsum[0] + wsum[1] + wsum[2] + wsum[3];
}

__global__ void scan1_3k(const int* c1, int* r1, int* b1, int n1a, int na,
                         const int* c2, int* r2, int* b2, int n1b, int nb,
                         const int* c3, int* r3, int* b3, int n1c, int nc,
                         int nbl1, int nbl2) {
    int b = blockIdx.x;
    if (b < nbl1)             scan1_body(c1, r1, b1, n1a, na, b);
    else if (b < nbl1 + nbl2) scan1_body(c2, r2, b2, n1b, nb, b - nbl1);
    else                      scan1_body(c3, r3, b3, n1c, nc, b - nbl1 - nbl2);
}

__device__ __forceinline__ void scan2_body(int* bsum, int nb, int* wsum) {
    int t = threadIdx.x;
    int s = (t < nb) ? bsum[t] : 0;
    int lane = t & 63, wv = t >> 6;
    int x = s;
#pragma unroll
    for (int off = 1; off < 64; off <<= 1) { int y = __shfl_up(x, off, 64); if (lane >= off) x += y; }
    if (lane == 63) wsum[wv] = x;
    __syncthreads();
    int woff = 0;
    for (int w = 0; w < wv; ++w) woff += wsum[w];
    if (t < nb) bsum[t] = woff + x - s;
    __syncthreads();
}

__global__ void scan2_3k(int* b1, int nb1, int* b2, int nb2, int* b3, int nb3) {
    __shared__ int wsum[4];
    scan2_body(b1, nb1, wsum);
    scan2_body(b2, nb2, wsum);
    scan2_body(b3, nb3, wsum);
}

__global__ void scan3_3k(int* r1, const int* b1, int n1a,
                         int* r2, const int* b2, int n1b,
                         int* r3, const int* b3, int n1c, int nc1, int nc2) {
    int b = blockIdx.x; int* rs; const int* bsum; int n1; int lb;
    if (b < nc1)            { rs = r1; bsum = b1; n1 = n1a; lb = b; }
    else if (b < nc1 + nc2) { rs = r2; bsum = b2; n1 = n1b; lb = b - nc1; }
    else                    { rs = r3; bsum = b3; n1 = n1c; lb = b - nc1 - nc2; }
    int i = lb * 256 + threadIdx.x;
    if (i < n1) rs[i] += bsum[lb >> 2];
}

__global__ void fill3_k(const int* e1, int E1, const int* r1, int* c1, int* s1,
                        const int* e2, int E2, const int* r2, int* c2, int* s2,
                        const int* e3, int E3, const int* r3, int* c3, int* s3,
                        int nb1, int nb2) {
    int b = blockIdx.x;
    const int* edges; int E; const int* rs; int* cur; int* csrc; int lb;
    if (b < nb1)            { edges = e1; E = E1; rs = r1; cur = c1; csrc = s1; lb = b; }
    else if (b < nb1 + nb2) { edges = e2; E = E2; rs = r2; cur = c2; csrc = s2; lb = b - nb1; }
    else                    { edges = e3; E = E3; rs = r3; cur = c3; csrc = s3; lb = b - nb1 - nb2; }
    int e = lb * 256 + threadIdx.x;
    if (e >= E) return;
    int d = edges[E + e];
    int p = rs[d] + atomicAdd(&cur[d], 1);
    csrc[p] = edges[e];
}

// -------- gather + relu (bf16 messages); TZ selects fp32/bf16 output.
__device__ __forceinline__ void storez(float2* p, float ax, float ay) {
    *p = make_float2(ax, ay);
}
__device__ __forceinline__ void storez(bf162* p, float ax, float ay) {
    bf162 v; v.x = __float2bfloat16(ax); v.y = __float2bfloat16(ay); *p = v;
}

struct NJob { const int* rs; const int* csrc; const bf162* m; const float* zin;
              void* zout; int R; int nb8; int nblocks; };

template <typename TZ>
__device__ __forceinline__ void neigh_body(const NJob& jb, int blk, int t) {
    int b = (blk & 7) * jb.nb8 + (blk >> 3);
    int wv = t >> 6, lane = t & 63;
    int j = b * 8 + wv * 2 + (lane >> 5);
    int f2 = lane & 31;
    if (j >= jb.R) return;
    const float2* zi = (const float2*)jb.zin;
    const bf162* m = jb.m;
    int s = jb.rs[j], e = jb.rs[j + 1];
    float2 a = zi[(size_t)j * 32 + f2];
    float ax = a.x, ay = a.y;
    int k = s;
    for (; k + 8 <= e; k += 8) {
        int i0 = jb.csrc[k],     i1 = jb.csrc[k + 1], i2 = jb.csrc[k + 2], i3 = jb.csrc[k + 3];
        int i4 = jb.csrc[k + 4], i5 = jb.csrc[k + 5], i6 = jb.csrc[k + 6], i7 = jb.csrc[k + 7];
        bf162 v0 = m[(size_t)i0 * 32 + f2], v1 = m[(size_t)i1 * 32 + f2];
        bf162 v2 = m[(size_t)i2 * 32 + f2], v3 = m[(size_t)i3 * 32 + f2];
        bf162 v4 = m[(size_t)i4 * 32 + f2], v5 = m[(size_t)i5 * 32 + f2];
        bf162 v6 = m[(size_t)i6 * 32 + f2], v7 = m[(size_t)i7 * 32 + f2];
        ax += ((bl(v0.x) + bl(v1.x)) + (bl(v2.x) + bl(v3.x)))
            + ((bl(v4.x) + bl(v5.x)) + (bl(v6.x) + bl(v7.x)));
        ay += ((bl(v0.y) + bl(v1.y)) + (bl(v2.y) + bl(v3.y)))
            + ((bl(v4.y) + bl(v5.y)) + (bl(v6.y) + bl(v7.y)));
    }
    for (; k + 4 <= e; k += 4) {
        int i0 = jb.csrc[k], i1 = jb.csrc[k + 1], i2 = jb.csrc[k + 2], i3 = jb.csrc[k + 3];
        bf162 v0 = m[(size_t)i0 * 32 + f2], v1 = m[(size_t)i1 * 32 + f2];
        bf162 v2 = m[(size_t)i2 * 32 + f2], v3 = m[(size_t)i3 * 32 + f2];
        ax += (bl(v0.x) + bl(v1.x)) + (bl(v2.x) + bl(v3.x));
        ay += (bl(v0.y) + bl(v1.y)) + (bl(v2.y) + bl(v3.y));
    }
    for (; k < e; ++k) {
        bf162 v = m[(size_t)jb.csrc[k] * 32 + f2];
        ax += bl(v.x); ay += bl(v.y);
    }
    storez((TZ*)jb.zout + (size_t)j * 32 + f2, fmaxf(ax, 0.f), fmaxf(ay, 0.f));
}

// single-job (level 1) and merged L3+L2 variants
template <typename TZ>
__global__ void neighsum_relu_k(NJob j1) {
    neigh_body<TZ>(j1, blockIdx.x, threadIdx.x);
}
template <typename TZ>
__global__ void neighsum2_relu_k(NJob j3, NJob j2) {
    if ((int)blockIdx.x < j3.nblocks) neigh_body<TZ>(j3, blockIdx.x, threadIdx.x);
    else                              neigh_body<TZ>(j2, blockIdx.x - j3.nblocks, threadIdx.x);
}

// -------- merged layer-0 combined gather (L3 blocks first, then L2)
__global__ void gatherZM23_k(
    // L3:
    const float* __restrict__ hA1, const float* __restrict__ hB1, const float* __restrict__ hC1,
    const float* __restrict__ hA2, const float* __restrict__ hB2, const float* __restrict__ hC2,
    const int* __restrict__ ga, const int* __restrict__ gb, const int* __restrict__ gc,
    const float* __restrict__ iso3, const float* __restrict__ W13, const float* __restrict__ W23,
    float* __restrict__ z3, bf16* __restrict__ m3, int n3, int jstep3, int nblk3,
    // L2:
    const float* __restrict__ hU1, const float* __restrict__ hV1,
    const float* __restrict__ hU2, const float* __restrict__ hV2,
    const int* __restrict__ gu, const int* __restrict__ gv,
    const float* __restrict__ iso2, const float* __restrict__ W12, const float* __restrict__ W22,
    float* __restrict__ z2, bf16* __restrict__ m2, int n2, int jstep2) {
    int t = threadIdx.x;
    if ((int)blockIdx.x < nblk3) {
        int idx = blockIdx.x * 256 + t;
        int j = idx >> 6, f = idx & 63;
        float w1c[4], w2c[4];
#pragma unroll
        for (int c = 0; c < 4; ++c) {
            w1c[c] = W13[f * 196 + 192 + c];
            w2c[c] = W23[f * 196 + 192 + c];
        }
        const float4* I4 = (const float4*)iso3;
#pragma unroll
        for (int r = 0; r < 4; ++r, j += jstep3) {
            if (j >= n3) return;
            int a = ga[j], b = gb[j], c = gc[j];
            float4 iv = I4[j];
            float zz = hA1[a * HID + f] + hB1[b * HID + f] + hC1[c * HID + f]
                     + iv.x * w1c[0] + iv.y * w1c[1] + iv.z * w1c[2] + iv.w * w1c[3];
            float mm = hA2[a * HID + f] + hB2[b * HID + f] + hC2[c * HID + f]
                     + iv.x * w2c[0] + iv.y * w2c[1] + iv.z * w2c[2] + iv.w * w2c[3];
            z3[(size_t)j * HID + f] = zz;
            m3[(size_t)j * HID + f] = __float2bfloat16(mm);
        }
    } else {
        int idx = (blockIdx.x - nblk3) * 256 + t;
        int j = idx >> 6, f = idx & 63;
        float w1c = W12[f * 129 + 128], w2c = W22[f * 129 + 128];
#pragma unroll
        for (int r = 0; r < 4; ++r, j += jstep2) {
            if (j >= n2) return;
            int u = gu[j], v = gv[j];
            float is = iso2[j];
            z2[(size_t)j * HID + f] = hU1[u * HID + f] + hV1[v * HID + f] + is * w1c;
            m2[(size_t)j * HID + f] =
                __float2bfloat16(hU2[u * HID + f] + hV2[v * HID + f] + is * w2c);
        }
    }
}

// -------- merged split segment sum (levels 1+2+3 in one dispatch)
struct SJob { const float* h; int per; int coloff; int S; int nblocks; };

__device__ __forceinline__ void segsum_body(const SJob& jb, float* comb, int blk, int f) {
    int g = blk / jb.S, s = blk % jb.S;
    int r0 = s * 64;
    int r1 = min(jb.per, r0 + 64);
    float acc = 0.f;
    const float* p = jb.h + ((size_t)g * jb.per + r0) * HID + f;
    for (int r = r0; r < r1; ++r) { acc += *p; p += HID; }
    atomicAdd(&comb[g * 192 + jb.coloff + f], acc);
}

__global__ void segsum3_k(SJob s1, SJob s2, SJob s3, float* comb) {
    int b = blockIdx.x, f = threadIdx.x;   // 64 threads
    if (b < s1.nblocks)                    segsum_body(s1, comb, b, f);
    else if (b < s1.nblocks + s2.nblocks)  segsum_body(s2, comb, b - s1.nblocks, f);
    else                                   segsum_body(s3, comb, b - s1.nblocks - s2.nblocks, f);
}

// -------- classifier
__global__ void classifier_k(const float* __restrict__ comb,
                             const float* __restrict__ cW1, const float* __restrict__ cb1,
                             const float* __restrict__ cW2, const float* __restrict__ cb2,
                             float* __restrict__ out) {
    __shared__ float row[192];
    __shared__ float hid[64];
    int g = blockIdx.x, t = threadIdx.x;
    for (int i = t; i < 192; i += 64) row[i] = comb[g * 192 + i];
    __syncthreads();
    float acc = cb1[t];
#pragma unroll 8
    for (int k = 0; k < 192; ++k) acc += row[k] * cW1[t * 192 + k];
    hid[t] = fmaxf(acc, 0.f);
    __syncthreads();
    if (t < 10) {
        float o = cb2[t];
#pragma unroll
        for (int k = 0; k < 64; ++k) o += hid[k] * cW2[t * 64 + k];
        out[g * 10 + t] = o;
    }
}

static inline int cdiv(long long a, long long b) { return (int)((a + b - 1) / b); }

extern "C" void kernel_launch(void* const* d_in, const int* in_sizes, int n_in,
                              void* d_out, int out_size, void* d_ws, size_t ws_size,
                              hipStream_t stream) {
    const float* x        = (const float*)d_in[0];
    const int*   eidx     = (const int*)d_in[1];
    const int*   gu2      = (const int*)d_in[3];
    const int*   gv2      = (const int*)d_in[4];
    const float* iso2     = (const float*)d_in[5];
    const int*   tedges   = (const int*)d_in[6];
    const int*   ga3      = (const int*)d_in[8];
    const int*   gb3      = (const int*)d_in[9];
    const int*   gc3      = (const int*)d_in[10];
    const float* iso3     = (const float*)d_in[11];
    const int*   hedges   = (const int*)d_in[12];
    const float* g1W1[3]  = {(const float*)d_in[14], (const float*)d_in[16], (const float*)d_in[18]};
    const float* g1W2[3]  = {(const float*)d_in[15], (const float*)d_in[17], (const float*)d_in[19]};
    const float* g2W1_0   = (const float*)d_in[20];
    const float* g2W2_0   = (const float*)d_in[21];
    const float* g2W1_1   = (const float*)d_in[22];
    const float* g2W2_1   = (const float*)d_in[23];
    const float* g3W1_0   = (const float*)d_in[24];
    const float* g3W2_0   = (const float*)d_in[25];
    const float* g3W1_1   = (const float*)d_in[26];
    const float* g3W2_1   = (const float*)d_in[27];
    const float* cW1      = (const float*)d_in[28];
    const float* cb1      = (const float*)d_in[29];
    const float* cW2      = (const float*)d_in[30];
    const float* cb2      = (const float*)d_in[31];
    float* out = (float*)d_out;

    const int N  = in_sizes[0] / 32;       // 2560
    const int E1 = in_sizes[1] / 2;
    const int n2 = in_sizes[3];            // 24320
    const int E2 = in_sizes[6] / 2;
    const int n3 = in_sizes[8];            // 145920
    const int E3 = in_sizes[12] / 2;
    const int G  = out_size / 10;          // 128
    const int per1 = N / G, per2 = n2 / G, per3 = n3 / G;

    // ---- workspace carve-up (float units, 16B-aligned blocks)
    float* ws = (float*)d_ws;
    size_t off = 0;
    auto alloc = [&](size_t n) { off = (off + 3) & ~(size_t)3; float* p = ws + off; off += n; return p; };
    const size_t NH = (size_t)N * HID;
    float* nb0 = alloc(NH); float* nb1 = alloc(NH);
    bf16* mb1 = (bf16*)alloc(NH / 2 + 64);
    float* hU1 = alloc(NH); float* hV1 = alloc(NH); float* hU2 = alloc(NH); float* hV2 = alloc(NH);
    float* hA1 = alloc(NH); float* hB1 = alloc(NH); float* hC1 = alloc(NH);
    float* hA2 = alloc(NH); float* hB2 = alloc(NH); float* hC2 = alloc(NH);
    float* z2 = alloc((size_t)n2 * HID);
    bf16* m2b = (bf16*)alloc((size_t)n2 * HID / 2 + 64);
    bf16* z2b = (bf16*)alloc((size_t)n2 * HID / 2 + 64);
    float* z3 = alloc((size_t)n3 * HID);
    bf16* m3b = (bf16*)alloc((size_t)n3 * HID / 2 + 64);
    bf16* z3b = (bf16*)alloc((size_t)n3 * HID / 2 + 64);
    float* comb = alloc((size_t)G * 192);
    int* iws = (int*)(ws + off);
    size_t ioff = 0;
    auto ialloc = [&](size_t n) { int* p = iws + ioff; ioff += n; return p; };
    int* rs1 = ialloc(N + 1);  int* cur1 = ialloc(N);  int* csrc1 = ialloc(E1);
    int* rs2 = ialloc(n2 + 1); int* cur2 = ialloc(n2); int* csrc2 = ialloc(E2);
    int* rs3 = ialloc(n3 + 1); int* cur3 = ialloc(n3); int* csrc3 = ialloc(E3);
    int* bsum1 = ialloc(256); int* bsum2 = ialloc(256); int* bsum3 = ialloc(256);
    (void)ws_size;

    dim3 B256(256);
    auto gemm2b = [&](const float* in, const float* Wa, const float* Wb,
                      float* oa, bf16* ob, int R, int K, int ldw, int coloff) {
        int blocks = cdiv(cdiv(R, RPW), 4);
        if (K == 64)
            gemm2_regb<64><<<blocks, B256, 0, stream>>>(in, Wa, Wb, oa, ob, R, ldw, coloff);
        else
            gemm2_regb<32><<<blocks, B256, 0, stream>>>(in, Wa, Wb, oa, ob, R, ldw, coloff);
    };
    auto mknjob = [&](const int* rs, const int* csrc, const bf16* m,
                      const float* zi, void* zo, int R) {
        NJob j; j.rs = rs; j.csrc = csrc; j.m = (const bf162*)m; j.zin = zi; j.zout = zo;
        j.R = R; int nb = cdiv(R, 8); j.nb8 = cdiv(nb, 8); j.nblocks = j.nb8 * 8; return j;
    };

    // ---- batched CSR build (7 dispatches; comb zero folded into first)
    int nz1 = cdiv(N, 256), nz2 = cdiv(n2, 256), nz3 = cdiv(n3, 256), nz4 = cdiv(G * 192, 256);
    zero4_k<<<nz1 + nz2 + nz3 + nz4, B256, 0, stream>>>(
        cur1, N, cur2, n2, cur3, n3, (int*)comb, G * 192, nz1, nz2, nz3);
    int ne1 = cdiv(E1, 256), ne2 = cdiv(E2, 256), ne3 = cdiv(E3, 256);
    hist3_k<<<ne1 + ne2 + ne3, B256, 0, stream>>>(
        eidx, E1, cur1, tedges, E2, cur2, hedges, E3, cur3, ne1, ne2);
    int ns1 = cdiv(N + 1, 1024), ns2 = cdiv(n2 + 1, 1024), ns3 = cdiv(n3 + 1, 1024);
    scan1_3k<<<ns1 + ns2 + ns3, B256, 0, stream>>>(
        cur1, rs1, bsum1, N + 1, N, cur2, rs2, bsum2, n2 + 1, n2,
        cur3, rs3, bsum3, n3 + 1, n3, ns1, ns2);
    scan2_3k<<<1, B256, 0, stream>>>(bsum1, ns1, bsum2, ns2, bsum3, ns3);
    int nc1 = cdiv(N + 1, 256), nc2 = cdiv(n2 + 1, 256), nc3 = cdiv(n3 + 1, 256);
    scan3_3k<<<nc1 + nc2 + nc3, B256, 0, stream>>>(
        rs1, bsum1, N + 1, rs2, bsum2, n2 + 1, rs3, bsum3, n3 + 1, nc1, nc2);
    zero4_k<<<nz1 + nz2 + nz3, B256, 0, stream>>>(
        cur1, N, cur2, n2, cur3, n3, nullptr, 0, nz1, nz2, nz3);
    fill3_k<<<ne1 + ne2 + ne3, B256, 0, stream>>>(
        eidx, E1, rs1, cur1, csrc1, tedges, E2, rs2, cur2, csrc2,
        hedges, E3, rs3, cur3, csrc3, ne1, ne2);

    // ================= level 1: node GNN (3 layers; scalar gemm) ==========
    const float* hcur = x;
    float* zb[2] = {nb0, nb1};
    for (int l = 0; l < 3; ++l) {
        int K = (l == 0) ? 32 : 64;
        float* z = zb[l & 1];
        gemm2b(hcur, g1W1[l], g1W2[l], z, mb1, N, K, K, 0);
        NJob j1 = mknjob(rs1, csrc1, mb1, z, z, N);
        neighsum_relu_k<float2><<<j1.nblocks, B256, 0, stream>>>(j1);
        hcur = z;
    }
    const float* h = hcur;   // = nb0 after 3 layers

    // ---- all 5 table GEMMs in ONE dispatch
    {
        TJobs5 jobs;
        jobs.j[0] = {g2W1_0, g2W2_0, hU1, hU2, 129, 0};
        jobs.j[1] = {g2W1_0, g2W2_0, hV1, hV2, 129, 64};
        jobs.j[2] = {g3W1_0, g3W2_0, hA1, hA2, 196, 0};
        jobs.j[3] = {g3W1_0, g3W2_0, hB1, hB2, 196, 64};
        jobs.j[4] = {g3W1_0, g3W2_0, hC1, hC2, 196, 128};
        int bpj = cdiv(cdiv(N, RPW), 4);
        gemm2_table<<<bpj * 5, B256, 0, stream>>>(h, jobs, N, bpj);
    }

    // ================= levels 2+3 merged (independent pipelines) ==========
    // layer-0 combined gather (L3 blocks + L2 blocks, one dispatch)
    {
        int jstep3 = cdiv(n3, 4), jstep2 = cdiv(n2, 4);
        int nblk3 = cdiv((long long)jstep3 * 64, 256);
        int nblk2 = cdiv((long long)jstep2 * 64, 256);
        gatherZM23_k<<<nblk3 + nblk2, B256, 0, stream>>>(
            hA1, hB1, hC1, hA2, hB2, hC2, ga3, gb3, gc3, iso3, g3W1_0, g3W2_0,
            z3, m3b, n3, jstep3, nblk3,
            hU1, hV1, hU2, hV2, gu2, gv2, iso2, g2W1_0, g2W2_0, z2, m2b, n2, jstep2);
    }
    // layer-0 neighbor sums (bf16 out), merged
    {
        NJob j3 = mknjob(rs3, csrc3, m3b, z3, z3b, n3);
        NJob j2 = mknjob(rs2, csrc2, m2b, z2, z2b, n2);
        neighsum2_relu_k<bf162><<<j3.nblocks + j2.nblocks, B256, 0, stream>>>(j3, j2);
    }
    // layer-1 MFMA dual GEMMs, merged
    {
        MJob j3 = {z3b, g3W1_1, g3W2_1, z3, m3b, n3, cdiv(n3, 128)};
        MJob j2 = {z2b, g2W1_1, g2W2_1, z2, m2b, n2, cdiv(n2, 128)};
        gemm2_mfma2<<<j3.nblocks + j2.nblocks, B256, 0, stream>>>(j3, j2);
    }
    // layer-1 neighbor sums (fp32 out), merged
    {
        NJob j3 = mknjob(rs3, csrc3, m3b, z3, z3, n3);
        NJob j2 = mknjob(rs2, csrc2, m2b, z2, z2, n2);
        neighsum2_relu_k<float2><<<j3.nblocks + j2.nblocks, B256, 0, stream>>>(j3, j2);
    }
    // all three segment sums, merged
    {
        SJob s1 = {h,  per1, 0,   cdiv(per1, 64), 0};
        SJob s2 = {z2, per2, 64,  cdiv(per2, 64), 0};
        SJob s3 = {z3, per3, 128, cdiv(per3, 64), 0};
        s1.nblocks = G * s1.S; s2.nblocks = G * s2.S; s3.nblocks = G * s3.S;
        segsum3_k<<<s1.nblocks + s2.nblocks + s3.nblocks, 64, 0, stream>>>(s1, s2, s3, comb);
    }

    // ================= classifier =================
    classifier_k<<<G, 64, 0, stream>>>(comb, cW1, cb1, cW2, cb2, out);
}

// Round 20
// 400.779 us; speedup vs baseline: 1.5293x; 1.0205x over previous
//
#include <hip/hip_runtime.h>
#include <hip/hip_bf16.h>

#define HID 64
#define RPW 16   // rows per wave in scalar gemm kernels
#define KCH 8    // k-chunk width (W regs live at a time = 2*KCH)

typedef __hip_bfloat16  bf16;
typedef __hip_bfloat162 bf162;
typedef __attribute__((ext_vector_type(8))) short bf8v;   // 8 bf16 (4 VGPRs)
typedef __attribute__((ext_vector_type(4))) float f4v;    // MFMA acc
__device__ __forceinline__ float bl(bf16 h) { return __bfloat162float(h); }

// -------- scalar dual GEMM (level-1 sites). R13-best config.
template <int KC>
__global__ __attribute__((amdgpu_flat_work_group_size(256, 256),
                          amdgpu_waves_per_eu(6, 6)))
void gemm2_regb(const float* in,
                const float* __restrict__ Wa, const float* __restrict__ Wb,
                float* outa, bf16* outb,
                int R, int ldw, int coloff) {
    int lane = threadIdx.x & 63;
    int wid = blockIdx.x * (blockDim.x >> 6) + (threadIdx.x >> 6);
    int j0 = __builtin_amdgcn_readfirstlane(wid * RPW);
    if (j0 >= R) return;
    float accx[RPW], accy[RPW];
#pragma unroll
    for (int r = 0; r < RPW; ++r) { accx[r] = 0.f; accy[r] = 0.f; }
    const float* pa = Wa + (size_t)lane * ldw + coloff;
    const float* pb = Wb + (size_t)lane * ldw + coloff;
#pragma unroll 1
    for (int kc = 0; kc < KC; kc += KCH) {
        float wx[KCH], wy[KCH];
#pragma unroll
        for (int kk = 0; kk < KCH; ++kk) { wx[kk] = pa[kc + kk]; wy[kk] = pb[kc + kk]; }
#pragma unroll
        for (int r = 0; r < RPW; ++r) {
            const float* rp = in + (size_t)(j0 + r) * KC + kc;
#pragma unroll
            for (int kk = 0; kk < KCH; ++kk) {
                float s = rp[kk];
                accx[r] = fmaf(s, wx[kk], accx[r]);
                accy[r] = fmaf(s, wy[kk], accy[r]);
            }
        }
    }
#pragma unroll
    for (int r = 0; r < RPW; ++r) {
        int j = j0 + r;
        outa[(size_t)j * HID + lane] = accx[r];
        outb[(size_t)j * HID + lane] = __float2bfloat16(accy[r]);
    }
}

// -------- MFMA dual GEMM body (R18-verified layouts m89/m120).
struct MJob { const bf16* in; const float* Wa; const float* Wb; float* oa; bf16* ob; int R; int nblocks; };

__device__ __forceinline__ void mfma_body(const MJob& jb, int blk, int t) {
    __shared__ bf16 wl1[64][72];
    __shared__ bf16 wl2[64][72];
    {
        int n = t >> 2, k0 = (t & 3) * 16;
#pragma unroll
        for (int k = 0; k < 16; ++k) {
            wl1[n][k0 + k] = __float2bfloat16(jb.Wa[n * 64 + k0 + k]);
            wl2[n][k0 + k] = __float2bfloat16(jb.Wb[n * 64 + k0 + k]);
        }
    }
    __syncthreads();
    int lane = t & 63, wv = t >> 6;
    int quad = lane >> 4, m16 = lane & 15;
    int j0 = (blk * 4 + wv) * 32;
    if (j0 >= jb.R) return;
    bf8v a[2][2];
#pragma unroll
    for (int rt = 0; rt < 2; ++rt)
#pragma unroll
        for (int kt = 0; kt < 2; ++kt)
            a[rt][kt] = *(const bf8v*)(jb.in + (size_t)(j0 + rt * 16 + m16) * 64
                                             + kt * 32 + quad * 8);
#pragma unroll
    for (int n = 0; n < 4; ++n) {
        bf8v b1k0 = *(const bf8v*)&wl1[n * 16 + m16][quad * 8];
        bf8v b1k1 = *(const bf8v*)&wl1[n * 16 + m16][32 + quad * 8];
        bf8v b2k0 = *(const bf8v*)&wl2[n * 16 + m16][quad * 8];
        bf8v b2k1 = *(const bf8v*)&wl2[n * 16 + m16][32 + quad * 8];
#pragma unroll
        for (int rt = 0; rt < 2; ++rt) {
            f4v acca = {0.f, 0.f, 0.f, 0.f};
            f4v accb = {0.f, 0.f, 0.f, 0.f};
            acca = __builtin_amdgcn_mfma_f32_16x16x32_bf16(a[rt][0], b1k0, acca, 0, 0, 0);
            acca = __builtin_amdgcn_mfma_f32_16x16x32_bf16(a[rt][1], b1k1, acca, 0, 0, 0);
            accb = __builtin_amdgcn_mfma_f32_16x16x32_bf16(a[rt][0], b2k0, accb, 0, 0, 0);
            accb = __builtin_amdgcn_mfma_f32_16x16x32_bf16(a[rt][1], b2k1, accb, 0, 0, 0);
            int col = n * 16 + m16;
#pragma unroll
            for (int r = 0; r < 4; ++r) {
                int row = j0 + rt * 16 + quad * 4 + r;
                jb.oa[(size_t)row * 64 + col] = acca[r];
                jb.ob[(size_t)row * 64 + col] = __float2bfloat16(accb[r]);
            }
        }
    }
}

__global__ __launch_bounds__(256)
void gemm2_mfma2(MJob j3, MJob j2) {
    if ((int)blockIdx.x < j3.nblocks) mfma_body(j3, blockIdx.x, threadIdx.x);
    else                              mfma_body(j2, blockIdx.x - j3.nblocks, threadIdx.x);
}

// -------- batched table GEMM: 5 jobs over h; INTERLEAVED output
// o[node][128]: o[j*128+2f] = (h@Wa^T)[j][f], o[j*128+2f+1] = (h@Wb^T)[j][f].
// Downstream gathers read one float2 per table instead of two scattered floats.
struct TJob { const float* Wa; const float* Wb; float* o; int ldw; int coloff; };
struct TJobs5 { TJob j[5]; };

__global__ __attribute__((amdgpu_flat_work_group_size(256, 256),
                          amdgpu_waves_per_eu(6, 6)))
void gemm2_table(const float* in, TJobs5 jobs, int R, int bpj) {
    int jobi = blockIdx.x / bpj;
    int lb = blockIdx.x % bpj;
    TJob jb = jobs.j[jobi];
    int lane = threadIdx.x & 63;
    int wid = lb * 4 + (threadIdx.x >> 6);
    int j0 = __builtin_amdgcn_readfirstlane(wid * RPW);
    if (j0 >= R) return;
    float accx[RPW], accy[RPW];
#pragma unroll
    for (int r = 0; r < RPW; ++r) { accx[r] = 0.f; accy[r] = 0.f; }
    const float* pa = jb.Wa + (size_t)lane * jb.ldw + jb.coloff;
    const float* pb = jb.Wb + (size_t)lane * jb.ldw + jb.coloff;
#pragma unroll 1
    for (int kc = 0; kc < 64; kc += KCH) {
        float wx[KCH], wy[KCH];
#pragma unroll
        for (int kk = 0; kk < KCH; ++kk) { wx[kk] = pa[kc + kk]; wy[kk] = pb[kc + kk]; }
#pragma unroll
        for (int r = 0; r < RPW; ++r) {
            const float* rp = in + (size_t)(j0 + r) * 64 + kc;
#pragma unroll
            for (int kk = 0; kk < KCH; ++kk) {
                float s = rp[kk];
                accx[r] = fmaf(s, wx[kk], accx[r]);
                accy[r] = fmaf(s, wy[kk], accy[r]);
            }
        }
    }
#pragma unroll
    for (int r = 0; r < RPW; ++r) {
        int j = j0 + r;
        ((float2*)jb.o)[(size_t)j * 64 + lane] = make_float2(accx[r], accy[r]);
    }
}

// ======== batched CSR build (unchanged) ========
__global__ void zero4_k(int* p1, int s1, int* p2, int s2, int* p3, int s3,
                        int* p4, int s4, int nb1, int nb2, int nb3) {
    int b = blockIdx.x; int* p; int n; int lb;
    if (b < nb1)                 { p = p1; n = s1; lb = b; }
    else if (b < nb1 + nb2)      { p = p2; n = s2; lb = b - nb1; }
    else if (b < nb1 + nb2 + nb3){ p = p3; n = s3; lb = b - nb1 - nb2; }
    else                         { p = p4; n = s4; lb = b - nb1 - nb2 - nb3; }
    int i = lb * 256 + threadIdx.x;
    if (i < n) p[i] = 0;
}

__global__ void hist3_k(const int* e1, int E1, int* c1,
                        const int* e2, int E2, int* c2,
                        const int* e3, int E3, int* c3, int nb1, int nb2) {
    int b = blockIdx.x; const int* dst; int* c; int E; int lb;
    if (b < nb1)            { dst = e1 + E1; c = c1; E = E1; lb = b; }
    else if (b < nb1 + nb2) { dst = e2 + E2; c = c2; E = E2; lb = b - nb1; }
    else                    { dst = e3 + E3; c = c3; E = E3; lb = b - nb1 - nb2; }
    int e = lb * 256 + threadIdx.x;
    if (e < E) atomicAdd(&c[dst[e]], 1);
}

__device__ __forceinline__ void scan1_body(const int* __restrict__ cnt, int* __restrict__ rs,
                                           int* __restrict__ bsum, int n1, int n, int lb) {
    __shared__ int wsum[4];
    int t = threadIdx.x;
    int base = lb * 1024 + t * 4;
    int v[4]; int s = 0;
#pragma unroll
    for (int i = 0; i < 4; ++i) { int idx = base + i; v[i] = s; s += (idx < n) ? cnt[idx] : 0; }
    int lane = t & 63, wv = t >> 6;
    int x = s;
#pragma unroll
    for (int off = 1; off < 64; off <<= 1) { int y = __shfl_up(x, off, 64); if (lane >= off) x += y; }
    if (lane == 63) wsum[wv] = x;
    __syncthreads();
    int woff = 0;
    for (int w = 0; w < wv; ++w) woff += wsum[w];
    int excl = woff + (x - s);
#pragma unroll
    for (int i = 0; i < 4; ++i) { int idx = base + i; if (idx < n1) rs[idx] = excl + v[i]; }
    if (t == 255) bsum[lb] = wsum[0] + wsum[1] + wsum[2] + wsum[3];
}

__global__ void scan1_3k(const int* c1, int* r1, int* b1, int n1a, int na,
                         const int* c2, int* r2, int* b2, int n1b, int nb,
                         const int* c3, int* r3, int* b3, int n1c, int nc,
                         int nbl1, int nbl2) {
    int b = blockIdx.x;
    if (b < nbl1)             scan1_body(c1, r1, b1, n1a, na, b);
    else if (b < nbl1 + nbl2) scan1_body(c2, r2, b2, n1b, nb, b - nbl1);
    else                      scan1_body(c3, r3, b3, n1c, nc, b - nbl1 - nbl2);
}

__device__ __forceinline__ void scan2_body(int* bsum, int nb, int* wsum) {
    int t = threadIdx.x;
    int s = (t < nb) ? bsum[t] : 0;
    int lane = t & 63, wv = t >> 6;
    int x = s;
#pragma unroll
    for (int off = 1; off < 64; off <<= 1) { int y = __shfl_up(x, off, 64); if (lane >= off) x += y; }
    if (lane == 63) wsum[wv] = x;
    __syncthreads();
    int woff = 0;
    for (int w = 0; w < wv; ++w) woff += wsum[w];
    if (t < nb) bsum[t] = woff + x - s;
    __syncthreads();
}

__global__ void scan2_3k(int* b1, int nb1, int* b2, int nb2, int* b3, int nb3) {
    __shared__ int wsum[4];
    scan2_body(b1, nb1, wsum);
    scan2_body(b2, nb2, wsum);
    scan2_body(b3, nb3, wsum);
}

__global__ void scan3_3k(int* r1, const int* b1, int n1a,
                         int* r2, const int* b2, int n1b,
                         int* r3, const int* b3, int n1c, int nc1, int nc2) {
    int b = blockIdx.x; int* rs; const int* bsum; int n1; int lb;
    if (b < nc1)            { rs = r1; bsum = b1; n1 = n1a; lb = b; }
    else if (b < nc1 + nc2) { rs = r2; bsum = b2; n1 = n1b; lb = b - nc1; }
    else                    { rs = r3; bsum = b3; n1 = n1c; lb = b - nc1 - nc2; }
    int i = lb * 256 + threadIdx.x;
    if (i < n1) rs[i] += bsum[lb >> 2];
}

__global__ void fill3_k(const int* e1, int E1, const int* r1, int* c1, int* s1,
                        const int* e2, int E2, const int* r2, int* c2, int* s2,
                        const int* e3, int E3, const int* r3, int* c3, int* s3,
                        int nb1, int nb2) {
    int b = blockIdx.x;
    const int* edges; int E; const int* rs; int* cur; int* csrc; int lb;
    if (b < nb1)            { edges = e1; E = E1; rs = r1; cur = c1; csrc = s1; lb = b; }
    else if (b < nb1 + nb2) { edges = e2; E = E2; rs = r2; cur = c2; csrc = s2; lb = b - nb1; }
    else                    { edges = e3; E = E3; rs = r3; cur = c3; csrc = s3; lb = b - nb1 - nb2; }
    int e = lb * 256 + threadIdx.x;
    if (e >= E) return;
    int d = edges[E + e];
    int p = rs[d] + atomicAdd(&cur[d], 1);
    csrc[p] = edges[e];
}

// -------- gather + relu (bf16 messages); TZI/TZO select fp32/bf16 in/out.
__device__ __forceinline__ void loadz(const float2* p, float& ax, float& ay) {
    float2 v = *p; ax = v.x; ay = v.y;
}
__device__ __forceinline__ void loadz(const bf162* p, float& ax, float& ay) {
    bf162 v = *p; ax = bl(v.x); ay = bl(v.y);
}
__device__ __forceinline__ void storez(float2* p, float ax, float ay) {
    *p = make_float2(ax, ay);
}
__device__ __forceinline__ void storez(bf162* p, float ax, float ay) {
    bf162 v; v.x = __float2bfloat16(ax); v.y = __float2bfloat16(ay); *p = v;
}

struct NJob { const int* rs; const int* csrc; const bf162* m; const void* zin;
              void* zout; int R; int nb8; int nblocks; };

template <typename TZI, typename TZO>
__device__ __forceinline__ void neigh_body(const NJob& jb, int blk, int t) {
    int b = (blk & 7) * jb.nb8 + (blk >> 3);
    int wv = t >> 6, lane = t & 63;
    int j = b * 8 + wv * 2 + (lane >> 5);
    int f2 = lane & 31;
    if (j >= jb.R) return;
    const bf162* m = jb.m;
    int s = jb.rs[j], e = jb.rs[j + 1];
    float ax, ay;
    loadz((const TZI*)jb.zin + (size_t)j * 32 + f2, ax, ay);
    int k = s;
    for (; k + 8 <= e; k += 8) {
        int i0 = jb.csrc[k],     i1 = jb.csrc[k + 1], i2 = jb.csrc[k + 2], i3 = jb.csrc[k + 3];
        int i4 = jb.csrc[k + 4], i5 = jb.csrc[k + 5], i6 = jb.csrc[k + 6], i7 = jb.csrc[k + 7];
        bf162 v0 = m[(size_t)i0 * 32 + f2], v1 = m[(size_t)i1 * 32 + f2];
        bf162 v2 = m[(size_t)i2 * 32 + f2], v3 = m[(size_t)i3 * 32 + f2];
        bf162 v4 = m[(size_t)i4 * 32 + f2], v5 = m[(size_t)i5 * 32 + f2];
        bf162 v6 = m[(size_t)i6 * 32 + f2], v7 = m[(size_t)i7 * 32 + f2];
        ax += ((bl(v0.x) + bl(v1.x)) + (bl(v2.x) + bl(v3.x)))
            + ((bl(v4.x) + bl(v5.x)) + (bl(v6.x) + bl(v7.x)));
        ay += ((bl(v0.y) + bl(v1.y)) + (bl(v2.y) + bl(v3.y)))
            + ((bl(v4.y) + bl(v5.y)) + (bl(v6.y) + bl(v7.y)));
    }
    for (; k + 4 <= e; k += 4) {
        int i0 = jb.csrc[k], i1 = jb.csrc[k + 1], i2 = jb.csrc[k + 2], i3 = jb.csrc[k + 3];
        bf162 v0 = m[(size_t)i0 * 32 + f2], v1 = m[(size_t)i1 * 32 + f2];
        bf162 v2 = m[(size_t)i2 * 32 + f2], v3 = m[(size_t)i3 * 32 + f2];
        ax += (bl(v0.x) + bl(v1.x)) + (bl(v2.x) + bl(v3.x));
        ay += (bl(v0.y) + bl(v1.y)) + (bl(v2.y) + bl(v3.y));
    }
    for (; k < e; ++k) {
        bf162 v = m[(size_t)jb.csrc[k] * 32 + f2];
        ax += bl(v.x); ay += bl(v.y);
    }
    storez((TZO*)jb.zout + (size_t)j * 32 + f2, fmaxf(ax, 0.f), fmaxf(ay, 0.f));
}

template <typename TZI, typename TZO>
__global__ void neighsum_relu_k(NJob j1) {
    neigh_body<TZI, TZO>(j1, blockIdx.x, threadIdx.x);
}
template <typename TZI, typename TZO>
__global__ void neighsum2_relu_k(NJob j3, NJob j2) {
    if ((int)blockIdx.x < j3.nblocks) neigh_body<TZI, TZO>(j3, blockIdx.x, threadIdx.x);
    else                              neigh_body<TZI, TZO>(j2, blockIdx.x - j3.nblocks, threadIdx.x);
}

// -------- merged layer-0 combined gather (L3 blocks first, then L2).
// Tables are INTERLEAVED (x=W1-part, y=W2-part) -> one float2 per table.
// Outputs z-init as bf16 (consumed only by the bf16-out neighsum, in-place).
__global__ void gatherZM23_k(
    const float2* __restrict__ hAi, const float2* __restrict__ hBi, const float2* __restrict__ hCi,
    const int* __restrict__ ga, const int* __restrict__ gb, const int* __restrict__ gc,
    const float* __restrict__ iso3, const float* __restrict__ W13, const float* __restrict__ W23,
    bf16* __restrict__ zb3, bf16* __restrict__ m3, int n3, int jstep3, int nblk3,
    const float2* __restrict__ hUi, const float2* __restrict__ hVi,
    const int* __restrict__ gu, const int* __restrict__ gv,
    const float* __restrict__ iso2, const float* __restrict__ W12, const float* __restrict__ W22,
    bf16* __restrict__ zb2, bf16* __restrict__ m2, int n2, int jstep2) {
    int t = threadIdx.x;
    if ((int)blockIdx.x < nblk3) {
        int idx = blockIdx.x * 256 + t;
        int j = idx >> 6, f = idx & 63;
        float w1c[4], w2c[4];
#pragma unroll
        for (int c = 0; c < 4; ++c) {
            w1c[c] = W13[f * 196 + 192 + c];
            w2c[c] = W23[f * 196 + 192 + c];
        }
        const float4* I4 = (const float4*)iso3;
#pragma unroll
        for (int r = 0; r < 4; ++r, j += jstep3) {
            if (j >= n3) return;
            int a = ga[j], b = gb[j], c = gc[j];
            float4 iv = I4[j];
            float2 va = hAi[(size_t)a * 64 + f];
            float2 vb = hBi[(size_t)b * 64 + f];
            float2 vc = hCi[(size_t)c * 64 + f];
            float zz = va.x + vb.x + vc.x
                     + iv.x * w1c[0] + iv.y * w1c[1] + iv.z * w1c[2] + iv.w * w1c[3];
            float mm = va.y + vb.y + vc.y
                     + iv.x * w2c[0] + iv.y * w2c[1] + iv.z * w2c[2] + iv.w * w2c[3];
            zb3[(size_t)j * HID + f] = __float2bfloat16(zz);
            m3[(size_t)j * HID + f] = __float2bfloat16(mm);
        }
    } else {
        int idx = (blockIdx.x - nblk3) * 256 + t;
        int j = idx >> 6, f = idx & 63;
        float w1c = W12[f * 129 + 128], w2c = W22[f * 129 + 128];
#pragma unroll
        for (int r = 0; r < 4; ++r, j += jstep2) {
            if (j >= n2) return;
            int u = gu[j], v = gv[j];
            float is = iso2[j];
            float2 vu = hUi[(size_t)u * 64 + f];
            float2 vv = hVi[(size_t)v * 64 + f];
            zb2[(size_t)j * HID + f] = __float2bfloat16(vu.x + vv.x + is * w1c);
            m2[(size_t)j * HID + f] = __float2bfloat16(vu.y + vv.y + is * w2c);
        }
    }
}

// -------- merged split segment sum (levels 1+2+3 in one dispatch)
struct SJob { const float* h; int per; int coloff; int S; int nblocks; };

__device__ __forceinline__ void segsum_body(const SJob& jb, float* comb, int blk, int f) {
    int g = blk / jb.S, s = blk % jb.S;
    int r0 = s * 64;
    int r1 = min(jb.per, r0 + 64);
    float acc = 0.f;
    const float* p = jb.h + ((size_t)g * jb.per + r0) * HID + f;
    for (int r = r0; r < r1; ++r) { acc += *p; p += HID; }
    atomicAdd(&comb[g * 192 + jb.coloff + f], acc);
}

__global__ void segsum3_k(SJob s1, SJob s2, SJob s3, float* comb) {
    int b = blockIdx.x, f = threadIdx.x;   // 64 threads
    if (b < s1.nblocks)                    segsum_body(s1, comb, b, f);
    else if (b < s1.nblocks + s2.nblocks)  segsum_body(s2, comb, b - s1.nblocks, f);
    else                                   segsum_body(s3, comb, b - s1.nblocks - s2.nblocks, f);
}

// -------- classifier
__global__ void classifier_k(const float* __restrict__ comb,
                             const float* __restrict__ cW1, const float* __restrict__ cb1,
                             const float* __restrict__ cW2, const float* __restrict__ cb2,
                             float* __restrict__ out) {
    __shared__ float row[192];
    __shared__ float hid[64];
    int g = blockIdx.x, t = threadIdx.x;
    for (int i = t; i < 192; i += 64) row[i] = comb[g * 192 + i];
    __syncthreads();
    float acc = cb1[t];
#pragma unroll 8
    for (int k = 0; k < 192; ++k) acc += row[k] * cW1[t * 192 + k];
    hid[t] = fmaxf(acc, 0.f);
    __syncthreads();
    if (t < 10) {
        float o = cb2[t];
#pragma unroll
        for (int k = 0; k < 64; ++k) o += hid[k] * cW2[t * 64 + k];
        out[g * 10 + t] = o;
    }
}

static inline int cdiv(long long a, long long b) { return (int)((a + b - 1) / b); }

extern "C" void kernel_launch(void* const* d_in, const int* in_sizes, int n_in,
                              void* d_out, int out_size, void* d_ws, size_t ws_size,
                              hipStream_t stream) {
    const float* x        = (const float*)d_in[0];
    const int*   eidx     = (const int*)d_in[1];
    const int*   gu2      = (const int*)d_in[3];
    const int*   gv2      = (const int*)d_in[4];
    const float* iso2     = (const float*)d_in[5];
    const int*   tedges   = (const int*)d_in[6];
    const int*   ga3      = (const int*)d_in[8];
    const int*   gb3      = (const int*)d_in[9];
    const int*   gc3      = (const int*)d_in[10];
    const float* iso3     = (const float*)d_in[11];
    const int*   hedges   = (const int*)d_in[12];
    const float* g1W1[3]  = {(const float*)d_in[14], (const float*)d_in[16], (const float*)d_in[18]};
    const float* g1W2[3]  = {(const float*)d_in[15], (const float*)d_in[17], (const float*)d_in[19]};
    const float* g2W1_0   = (const float*)d_in[20];
    const float* g2W2_0   = (const float*)d_in[21];
    const float* g2W1_1   = (const float*)d_in[22];
    const float* g2W2_1   = (const float*)d_in[23];
    const float* g3W1_0   = (const float*)d_in[24];
    const float* g3W2_0   = (const float*)d_in[25];
    const float* g3W1_1   = (const float*)d_in[26];
    const float* g3W2_1   = (const float*)d_in[27];
    const float* cW1      = (const float*)d_in[28];
    const float* cb1      = (const float*)d_in[29];
    const float* cW2      = (const float*)d_in[30];
    const float* cb2      = (const float*)d_in[31];
    float* out = (float*)d_out;

    const int N  = in_sizes[0] / 32;       // 2560
    const int E1 = in_sizes[1] / 2;
    const int n2 = in_sizes[3];            // 24320
    const int E2 = in_sizes[6] / 2;
    const int n3 = in_sizes[8];            // 145920
    const int E3 = in_sizes[12] / 2;
    const int G  = out_size / 10;          // 128
    const int per1 = N / G, per2 = n2 / G, per3 = n3 / G;

    // ---- workspace carve-up (float units, 16B-aligned blocks)
    float* ws = (float*)d_ws;
    size_t off = 0;
    auto alloc = [&](size_t n) { off = (off + 3) & ~(size_t)3; float* p = ws + off; off += n; return p; };
    const size_t NH = (size_t)N * HID;
    float* nb0 = alloc(NH); float* nb1 = alloc(NH);
    bf16* mb1 = (bf16*)alloc(NH / 2 + 64);
    float* hUi = alloc(NH * 2); float* hVi = alloc(NH * 2);     // interleaved tables
    float* hAi = alloc(NH * 2); float* hBi = alloc(NH * 2); float* hCi = alloc(NH * 2);
    float* z2 = alloc((size_t)n2 * HID);
    bf16* m2b = (bf16*)alloc((size_t)n2 * HID / 2 + 64);
    bf16* z2b = (bf16*)alloc((size_t)n2 * HID / 2 + 64);
    float* z3 = alloc((size_t)n3 * HID);
    bf16* m3b = (bf16*)alloc((size_t)n3 * HID / 2 + 64);
    bf16* z3b = (bf16*)alloc((size_t)n3 * HID / 2 + 64);
    float* comb = alloc((size_t)G * 192);
    int* iws = (int*)(ws + off);
    size_t ioff = 0;
    auto ialloc = [&](size_t n) { int* p = iws + ioff; ioff += n; return p; };
    int* rs1 = ialloc(N + 1);  int* cur1 = ialloc(N);  int* csrc1 = ialloc(E1);
    int* rs2 = ialloc(n2 + 1); int* cur2 = ialloc(n2); int* csrc2 = ialloc(E2);
    int* rs3 = ialloc(n3 + 1); int* cur3 = ialloc(n3); int* csrc3 = ialloc(E3);
    int* bsum1 = ialloc(256); int* bsum2 = ialloc(256); int* bsum3 = ialloc(256);
    (void)ws_size;

    dim3 B256(256);
    auto gemm2b = [&](const float* in, const float* Wa, const float* Wb,
                      float* oa, bf16* ob, int R, int K, int ldw, int coloff) {
        int blocks = cdiv(cdiv(R, RPW), 4);
        if (K == 64)
            gemm2_regb<64><<<blocks, B256, 0, stream>>>(in, Wa, Wb, oa, ob, R, ldw, coloff);
        else
            gemm2_regb<32><<<blocks, B256, 0, stream>>>(in, Wa, Wb, oa, ob, R, ldw, coloff);
    };
    auto mknjob = [&](const int* rs, const int* csrc, const bf16* m,
                      const void* zi, void* zo, int R) {
        NJob j; j.rs = rs; j.csrc = csrc; j.m = (const bf162*)m; j.zin = zi; j.zout = zo;
        j.R = R; int nb = cdiv(R, 8); j.nb8 = cdiv(nb, 8); j.nblocks = j.nb8 * 8; return j;
    };

    // ---- batched CSR build (7 dispatches; comb zero folded into first)
    int nz1 = cdiv(N, 256), nz2 = cdiv(n2, 256), nz3 = cdiv(n3, 256), nz4 = cdiv(G * 192, 256);
    zero4_k<<<nz1 + nz2 + nz3 + nz4, B256, 0, stream>>>(
        cur1, N, cur2, n2, cur3, n3, (int*)comb, G * 192, nz1, nz2, nz3);
    int ne1 = cdiv(E1, 256), ne2 = cdiv(E2, 256), ne3 = cdiv(E3, 256);
    hist3_k<<<ne1 + ne2 + ne3, B256, 0, stream>>>(
        eidx, E1, cur1, tedges, E2, cur2, hedges, E3, cur3, ne1, ne2);
    int ns1 = cdiv(N + 1, 1024), ns2 = cdiv(n2 + 1, 1024), ns3 = cdiv(n3 + 1, 1024);
    scan1_3k<<<ns1 + ns2 + ns3, B256, 0, stream>>>(
        cur1, rs1, bsum1, N + 1, N, cur2, rs2, bsum2, n2 + 1, n2,
        cur3, rs3, bsum3, n3 + 1, n3, ns1, ns2);
    scan2_3k<<<1, B256, 0, stream>>>(bsum1, ns1, bsum2, ns2, bsum3, ns3);
    int nc1 = cdiv(N + 1, 256), nc2 = cdiv(n2 + 1, 256), nc3 = cdiv(n3 + 1, 256);
    scan3_3k<<<nc1 + nc2 + nc3, B256, 0, stream>>>(
        rs1, bsum1, N + 1, rs2, bsum2, n2 + 1, rs3, bsum3, n3 + 1, nc1, nc2);
    zero4_k<<<nz1 + nz2 + nz3, B256, 0, stream>>>(
        cur1, N, cur2, n2, cur3, n3, nullptr, 0, nz1, nz2, nz3);
    fill3_k<<<ne1 + ne2 + ne3, B256, 0, stream>>>(
        eidx, E1, rs1, cur1, csrc1, tedges, E2, rs2, cur2, csrc2,
        hedges, E3, rs3, cur3, csrc3, ne1, ne2);

    // ================= level 1: node GNN (3 layers; scalar gemm) ==========
    const float* hcur = x;
    float* zb[2] = {nb0, nb1};
    for (int l = 0; l < 3; ++l) {
        int K = (l == 0) ? 32 : 64;
        float* z = zb[l & 1];
        gemm2b(hcur, g1W1[l], g1W2[l], z, mb1, N, K, K, 0);
        NJob j1 = mknjob(rs1, csrc1, mb1, z, z, N);
        neighsum_relu_k<float2, float2><<<j1.nblocks, B256, 0, stream>>>(j1);
        hcur = z;
    }
    const float* h = hcur;   // = nb0 after 3 layers

    // ---- all 5 table GEMMs (interleaved outputs) in ONE dispatch
    {
        TJobs5 jobs;
        jobs.j[0] = {g2W1_0, g2W2_0, hUi, 129, 0};
        jobs.j[1] = {g2W1_0, g2W2_0, hVi, 129, 64};
        jobs.j[2] = {g3W1_0, g3W2_0, hAi, 196, 0};
        jobs.j[3] = {g3W1_0, g3W2_0, hBi, 196, 64};
        jobs.j[4] = {g3W1_0, g3W2_0, hCi, 196, 128};
        int bpj = cdiv(cdiv(N, RPW), 4);
        gemm2_table<<<bpj * 5, B256, 0, stream>>>(h, jobs, N, bpj);
    }

    // ================= levels 2+3 merged (independent pipelines) ==========
    {
        int jstep3 = cdiv(n3, 4), jstep2 = cdiv(n2, 4);
        int nblk3 = cdiv((long long)jstep3 * 64, 256);
        int nblk2 = cdiv((long long)jstep2 * 64, 256);
        gatherZM23_k<<<nblk3 + nblk2, B256, 0, stream>>>(
            (const float2*)hAi, (const float2*)hBi, (const float2*)hCi,
            ga3, gb3, gc3, iso3, g3W1_0, g3W2_0, z3b, m3b, n3, jstep3, nblk3,
            (const float2*)hUi, (const float2*)hVi, gu2, gv2, iso2,
            g2W1_0, g2W2_0, z2b, m2b, n2, jstep2);
    }
    // layer-0 neighbor sums: bf16 in (z-init), bf16 out, IN-PLACE on zb
    {
        NJob j3 = mknjob(rs3, csrc3, m3b, z3b, z3b, n3);
        NJob j2 = mknjob(rs2, csrc2, m2b, z2b, z2b, n2);
        neighsum2_relu_k<bf162, bf162><<<j3.nblocks + j2.nblocks, B256, 0, stream>>>(j3, j2);
    }
    // layer-1 MFMA dual GEMMs, merged
    {
        MJob j3 = {z3b, g3W1_1, g3W2_1, z3, m3b, n3, cdiv(n3, 128)};
        MJob j2 = {z2b, g2W1_1, g2W2_1, z2, m2b, n2, cdiv(n2, 128)};
        gemm2_mfma2<<<j3.nblocks + j2.nblocks, B256, 0, stream>>>(j3, j2);
    }
    // layer-1 neighbor sums: fp32 in/out, merged
    {
        NJob j3 = mknjob(rs3, csrc3, m3b, z3, z3, n3);
        NJob j2 = mknjob(rs2, csrc2, m2b, z2, z2, n2);
        neighsum2_relu_k<float2, float2><<<j3.nblocks + j2.nblocks, B256, 0, stream>>>(j3, j2);
    }
    // all three segment sums, merged
    {
        SJob s1 = {h,  per1, 0,   cdiv(per1, 64), 0};
        SJob s2 = {z2, per2, 64,  cdiv(per2, 64), 0};
        SJob s3 = {z3, per3, 128, cdiv(per3, 64), 0};
        s1.nblocks = G * s1.S; s2.nblocks = G * s2.S; s3.nblocks = G * s3.S;
        segsum3_k<<<s1.nblocks + s2.nblocks + s3.nblocks, 64, 0, stream>>>(s1, s2, s3, comb);
    }

    // ================= classifier =================
    classifier_k<<<G, 64, 0, stream>>>(comb, cW1, cb1, cW2, cb2, out);
}

// Round 21
// 398.019 us; speedup vs baseline: 1.5399x; 1.0069x over previous
//
#include <hip/hip_runtime.h>
#include <hip/hip_bf16.h>

#define HID 64
#define RPW 16   // rows per wave in scalar gemm kernels
#define KCH 8    // k-chunk width (W regs live at a time = 2*KCH)

typedef __hip_bfloat16  bf16;
typedef __hip_bfloat162 bf162;
typedef __attribute__((ext_vector_type(8))) short bf8v;   // 8 bf16 (4 VGPRs)
typedef __attribute__((ext_vector_type(4))) float f4v;    // MFMA acc
__device__ __forceinline__ float bl(bf16 h) { return __bfloat162float(h); }

// -------- scalar dual GEMM (level-1 sites). R13-best config.
template <int KC>
__global__ __attribute__((amdgpu_flat_work_group_size(256, 256),
                          amdgpu_waves_per_eu(6, 6)))
void gemm2_regb(const float* in,
                const float* __restrict__ Wa, const float* __restrict__ Wb,
                float* outa, bf16* outb,
                int R, int ldw, int coloff) {
    int lane = threadIdx.x & 63;
    int wid = blockIdx.x * (blockDim.x >> 6) + (threadIdx.x >> 6);
    int j0 = __builtin_amdgcn_readfirstlane(wid * RPW);
    if (j0 >= R) return;
    float accx[RPW], accy[RPW];
#pragma unroll
    for (int r = 0; r < RPW; ++r) { accx[r] = 0.f; accy[r] = 0.f; }
    const float* pa = Wa + (size_t)lane * ldw + coloff;
    const float* pb = Wb + (size_t)lane * ldw + coloff;
#pragma unroll 1
    for (int kc = 0; kc < KC; kc += KCH) {
        float wx[KCH], wy[KCH];
#pragma unroll
        for (int kk = 0; kk < KCH; ++kk) { wx[kk] = pa[kc + kk]; wy[kk] = pb[kc + kk]; }
#pragma unroll
        for (int r = 0; r < RPW; ++r) {
            const float* rp = in + (size_t)(j0 + r) * KC + kc;
#pragma unroll
            for (int kk = 0; kk < KCH; ++kk) {
                float s = rp[kk];
                accx[r] = fmaf(s, wx[kk], accx[r]);
                accy[r] = fmaf(s, wy[kk], accy[r]);
            }
        }
    }
#pragma unroll
    for (int r = 0; r < RPW; ++r) {
        int j = j0 + r;
        outa[(size_t)j * HID + lane] = accx[r];
        outb[(size_t)j * HID + lane] = __float2bfloat16(accy[r]);
    }
}

// -------- MFMA dual GEMM body (verified layouts m89/m120). Both outputs bf16.
struct MJob { const bf16* in; const float* Wa; const float* Wb; bf16* oa; bf16* ob; int R; int nblocks; };

__device__ __forceinline__ void mfma_body(const MJob& jb, int blk, int t) {
    __shared__ bf16 wl1[64][72];
    __shared__ bf16 wl2[64][72];
    {
        int n = t >> 2, k0 = (t & 3) * 16;
#pragma unroll
        for (int k = 0; k < 16; ++k) {
            wl1[n][k0 + k] = __float2bfloat16(jb.Wa[n * 64 + k0 + k]);
            wl2[n][k0 + k] = __float2bfloat16(jb.Wb[n * 64 + k0 + k]);
        }
    }
    __syncthreads();
    int lane = t & 63, wv = t >> 6;
    int quad = lane >> 4, m16 = lane & 15;
    int j0 = (blk * 4 + wv) * 32;
    if (j0 >= jb.R) return;
    bf8v a[2][2];
#pragma unroll
    for (int rt = 0; rt < 2; ++rt)
#pragma unroll
        for (int kt = 0; kt < 2; ++kt)
            a[rt][kt] = *(const bf8v*)(jb.in + (size_t)(j0 + rt * 16 + m16) * 64
                                             + kt * 32 + quad * 8);
#pragma unroll
    for (int n = 0; n < 4; ++n) {
        bf8v b1k0 = *(const bf8v*)&wl1[n * 16 + m16][quad * 8];
        bf8v b1k1 = *(const bf8v*)&wl1[n * 16 + m16][32 + quad * 8];
        bf8v b2k0 = *(const bf8v*)&wl2[n * 16 + m16][quad * 8];
        bf8v b2k1 = *(const bf8v*)&wl2[n * 16 + m16][32 + quad * 8];
#pragma unroll
        for (int rt = 0; rt < 2; ++rt) {
            f4v acca = {0.f, 0.f, 0.f, 0.f};
            f4v accb = {0.f, 0.f, 0.f, 0.f};
            acca = __builtin_amdgcn_mfma_f32_16x16x32_bf16(a[rt][0], b1k0, acca, 0, 0, 0);
            acca = __builtin_amdgcn_mfma_f32_16x16x32_bf16(a[rt][1], b1k1, acca, 0, 0, 0);
            accb = __builtin_amdgcn_mfma_f32_16x16x32_bf16(a[rt][0], b2k0, accb, 0, 0, 0);
            accb = __builtin_amdgcn_mfma_f32_16x16x32_bf16(a[rt][1], b2k1, accb, 0, 0, 0);
            int col = n * 16 + m16;
#pragma unroll
            for (int r = 0; r < 4; ++r) {
                int row = j0 + rt * 16 + quad * 4 + r;
                jb.oa[(size_t)row * 64 + col] = __float2bfloat16(acca[r]);
                jb.ob[(size_t)row * 64 + col] = __float2bfloat16(accb[r]);
            }
        }
    }
}

__global__ __launch_bounds__(256)
void gemm2_mfma2(MJob j3, MJob j2) {
    if ((int)blockIdx.x < j3.nblocks) mfma_body(j3, blockIdx.x, threadIdx.x);
    else                              mfma_body(j2, blockIdx.x - j3.nblocks, threadIdx.x);
}

// -------- batched table GEMM: 5 jobs over h; INTERLEAVED float2 output.
struct TJob { const float* Wa; const float* Wb; float* o; int ldw; int coloff; };
struct TJobs5 { TJob j[5]; };

__global__ __attribute__((amdgpu_flat_work_group_size(256, 256),
                          amdgpu_waves_per_eu(6, 6)))
void gemm2_table(const float* in, TJobs5 jobs, int R, int bpj) {
    int jobi = blockIdx.x / bpj;
    int lb = blockIdx.x % bpj;
    TJob jb = jobs.j[jobi];
    int lane = threadIdx.x & 63;
    int wid = lb * 4 + (threadIdx.x >> 6);
    int j0 = __builtin_amdgcn_readfirstlane(wid * RPW);
    if (j0 >= R) return;
    float accx[RPW], accy[RPW];
#pragma unroll
    for (int r = 0; r < RPW; ++r) { accx[r] = 0.f; accy[r] = 0.f; }
    const float* pa = jb.Wa + (size_t)lane * jb.ldw + jb.coloff;
    const float* pb = jb.Wb + (size_t)lane * jb.ldw + jb.coloff;
#pragma unroll 1
    for (int kc = 0; kc < 64; kc += KCH) {
        float wx[KCH], wy[KCH];
#pragma unroll
        for (int kk = 0; kk < KCH; ++kk) { wx[kk] = pa[kc + kk]; wy[kk] = pb[kc + kk]; }
#pragma unroll
        for (int r = 0; r < RPW; ++r) {
            const float* rp = in + (size_t)(j0 + r) * 64 + kc;
#pragma unroll
            for (int kk = 0; kk < KCH; ++kk) {
                float s = rp[kk];
                accx[r] = fmaf(s, wx[kk], accx[r]);
                accy[r] = fmaf(s, wy[kk], accy[r]);
            }
        }
    }
#pragma unroll
    for (int r = 0; r < RPW; ++r) {
        int j = j0 + r;
        ((float2*)jb.o)[(size_t)j * 64 + lane] = make_float2(accx[r], accy[r]);
    }
}

// ======== batched CSR build (unchanged) ========
__global__ void zero4_k(int* p1, int s1, int* p2, int s2, int* p3, int s3,
                        int* p4, int s4, int nb1, int nb2, int nb3) {
    int b = blockIdx.x; int* p; int n; int lb;
    if (b < nb1)                 { p = p1; n = s1; lb = b; }
    else if (b < nb1 + nb2)      { p = p2; n = s2; lb = b - nb1; }
    else if (b < nb1 + nb2 + nb3){ p = p3; n = s3; lb = b - nb1 - nb2; }
    else                         { p = p4; n = s4; lb = b - nb1 - nb2 - nb3; }
    int i = lb * 256 + threadIdx.x;
    if (i < n) p[i] = 0;
}

__global__ void hist3_k(const int* e1, int E1, int* c1,
                        const int* e2, int E2, int* c2,
                        const int* e3, int E3, int* c3, int nb1, int nb2) {
    int b = blockIdx.x; const int* dst; int* c; int E; int lb;
    if (b < nb1)            { dst = e1 + E1; c = c1; E = E1; lb = b; }
    else if (b < nb1 + nb2) { dst = e2 + E2; c = c2; E = E2; lb = b - nb1; }
    else                    { dst = e3 + E3; c = c3; E = E3; lb = b - nb1 - nb2; }
    int e = lb * 256 + threadIdx.x;
    if (e < E) atomicAdd(&c[dst[e]], 1);
}

__device__ __forceinline__ void scan1_body(const int* __restrict__ cnt, int* __restrict__ rs,
                                           int* __restrict__ bsum, int n1, int n, int lb) {
    __shared__ int wsum[4];
    int t = threadIdx.x;
    int base = lb * 1024 + t * 4;
    int v[4]; int s = 0;
#pragma unroll
    for (int i = 0; i < 4; ++i) { int idx = base + i; v[i] = s; s += (idx < n) ? cnt[idx] : 0; }
    int lane = t & 63, wv = t >> 6;
    int x = s;
#pragma unroll
    for (int off = 1; off < 64; off <<= 1) { int y = __shfl_up(x, off, 64); if (lane >= off) x += y; }
    if (lane == 63) wsum[wv] = x;
    __syncthreads();
    int woff = 0;
    for (int w = 0; w < wv; ++w) woff += wsum[w];
    int excl = woff + (x - s);
#pragma unroll
    for (int i = 0; i < 4; ++i) { int idx = base + i; if (idx < n1) rs[idx] = excl + v[i]; }
    if (t == 255) bsum[lb] = wsum[0] + wsum[1] + wsum[2] + wsum[3];
}

__global__ void scan1_3k(const int* c1, int* r1, int* b1, int n1a, int na,
                         const int* c2, int* r2, int* b2, int n1b, int nb,
                         const int* c3, int* r3, int* b3, int n1c, int nc,
                         int nbl1, int nbl2) {
    int b = blockIdx.x;
    if (b < nbl1)             scan1_body(c1, r1, b1, n1a, na, b);
    else if (b < nbl1 + nbl2) scan1_body(c2, r2, b2, n1b, nb, b - nbl1);
    else                      scan1_body(c3, r3, b3, n1c, nc, b - nbl1 - nbl2);
}

__device__ __forceinline__ void scan2_body(int* bsum, int nb, int* wsum) {
    int t = threadIdx.x;
    int s = (t < nb) ? bsum[t] : 0;
    int lane = t & 63, wv = t >> 6;
    int x = s;
#pragma unroll
    for (int off = 1; off < 64; off <<= 1) { int y = __shfl_up(x, off, 64); if (lane >= off) x += y; }
    if (lane == 63) wsum[wv] = x;
    __syncthreads();
    int woff = 0;
    for (int w = 0; w < wv; ++w) woff += wsum[w];
    if (t < nb) bsum[t] = woff + x - s;
    __syncthreads();
}

__global__ void scan2_3k(int* b1, int nb1, int* b2, int nb2, int* b3, int nb3) {
    __shared__ int wsum[4];
    scan2_body(b1, nb1, wsum);
    scan2_body(b2, nb2, wsum);
    scan2_body(b3, nb3, wsum);
}

__global__ void scan3_3k(int* r1, const int* b1, int n1a,
                         int* r2, const int* b2, int n1b,
                         int* r3, const int* b3, int n1c, int nc1, int nc2) {
    int b = blockIdx.x; int* rs; const int* bsum; int n1; int lb;
    if (b < nc1)            { rs = r1; bsum = b1; n1 = n1a; lb = b; }
    else if (b < nc1 + nc2) { rs = r2; bsum = b2; n1 = n1b; lb = b - nc1; }
    else                    { rs = r3; bsum = b3; n1 = n1c; lb = b - nc1 - nc2; }
    int i = lb * 256 + threadIdx.x;
    if (i < n1) rs[i] += bsum[lb >> 2];
}

__global__ void fill3_k(const int* e1, int E1, const int* r1, int* c1, int* s1,
                        const int* e2, int E2, const int* r2, int* c2, int* s2,
                        const int* e3, int E3, const int* r3, int* c3, int* s3,
                        int nb1, int nb2) {
    int b = blockIdx.x;
    const int* edges; int E; const int* rs; int* cur; int* csrc; int lb;
    if (b < nb1)            { edges = e1; E = E1; rs = r1; cur = c1; csrc = s1; lb = b; }
    else if (b < nb1 + nb2) { edges = e2; E = E2; rs = r2; cur = c2; csrc = s2; lb = b - nb1; }
    else                    { edges = e3; E = E3; rs = r3; cur = c3; csrc = s3; lb = b - nb1 - nb2; }
    int e = lb * 256 + threadIdx.x;
    if (e >= E) return;
    int d = edges[E + e];
    int p = rs[d] + atomicAdd(&cur[d], 1);
    csrc[p] = edges[e];
}

// -------- gather + relu (bf16 messages); TZI/TZO select fp32/bf16 in/out.
__device__ __forceinline__ void loadz(const float2* p, float& ax, float& ay) {
    float2 v = *p; ax = v.x; ay = v.y;
}
__device__ __forceinline__ void loadz(const bf162* p, float& ax, float& ay) {
    bf162 v = *p; ax = bl(v.x); ay = bl(v.y);
}
__device__ __forceinline__ void storez(float2* p, float ax, float ay) {
    *p = make_float2(ax, ay);
}
__device__ __forceinline__ void storez(bf162* p, float ax, float ay) {
    bf162 v; v.x = __float2bfloat16(ax); v.y = __float2bfloat16(ay); *p = v;
}

struct NJob { const int* rs; const int* csrc; const bf162* m; const void* zin;
              void* zout; int R; int nb8; int nblocks; };

template <typename TZI, typename TZO>
__device__ __forceinline__ void neigh_body(const NJob& jb, int blk, int t) {
    int b = (blk & 7) * jb.nb8 + (blk >> 3);
    int wv = t >> 6, lane = t & 63;
    int j = b * 8 + wv * 2 + (lane >> 5);
    int f2 = lane & 31;
    if (j >= jb.R) return;
    const bf162* m = jb.m;
    int s = jb.rs[j], e = jb.rs[j + 1];
    float ax, ay;
    loadz((const TZI*)jb.zin + (size_t)j * 32 + f2, ax, ay);
    int k = s;
    for (; k + 8 <= e; k += 8) {
        int i0 = jb.csrc[k],     i1 = jb.csrc[k + 1], i2 = jb.csrc[k + 2], i3 = jb.csrc[k + 3];
        int i4 = jb.csrc[k + 4], i5 = jb.csrc[k + 5], i6 = jb.csrc[k + 6], i7 = jb.csrc[k + 7];
        bf162 v0 = m[(size_t)i0 * 32 + f2], v1 = m[(size_t)i1 * 32 + f2];
        bf162 v2 = m[(size_t)i2 * 32 + f2], v3 = m[(size_t)i3 * 32 + f2];
        bf162 v4 = m[(size_t)i4 * 32 + f2], v5 = m[(size_t)i5 * 32 + f2];
        bf162 v6 = m[(size_t)i6 * 32 + f2], v7 = m[(size_t)i7 * 32 + f2];
        ax += ((bl(v0.x) + bl(v1.x)) + (bl(v2.x) + bl(v3.x)))
            + ((bl(v4.x) + bl(v5.x)) + (bl(v6.x) + bl(v7.x)));
        ay += ((bl(v0.y) + bl(v1.y)) + (bl(v2.y) + bl(v3.y)))
            + ((bl(v4.y) + bl(v5.y)) + (bl(v6.y) + bl(v7.y)));
    }
    for (; k + 4 <= e; k += 4) {
        int i0 = jb.csrc[k], i1 = jb.csrc[k + 1], i2 = jb.csrc[k + 2], i3 = jb.csrc[k + 3];
        bf162 v0 = m[(size_t)i0 * 32 + f2], v1 = m[(size_t)i1 * 32 + f2];
        bf162 v2 = m[(size_t)i2 * 32 + f2], v3 = m[(size_t)i3 * 32 + f2];
        ax += (bl(v0.x) + bl(v1.x)) + (bl(v2.x) + bl(v3.x));
        ay += (bl(v0.y) + bl(v1.y)) + (bl(v2.y) + bl(v3.y));
    }
    for (; k < e; ++k) {
        bf162 v = m[(size_t)jb.csrc[k] * 32 + f2];
        ax += bl(v.x); ay += bl(v.y);
    }
    storez((TZO*)jb.zout + (size_t)j * 32 + f2, fmaxf(ax, 0.f), fmaxf(ay, 0.f));
}

template <typename TZI, typename TZO>
__global__ void neighsum_relu_k(NJob j1) {
    neigh_body<TZI, TZO>(j1, blockIdx.x, threadIdx.x);
}
template <typename TZI, typename TZO>
__global__ void neighsum2_relu_k(NJob j3, NJob j2) {
    if ((int)blockIdx.x < j3.nblocks) neigh_body<TZI, TZO>(j3, blockIdx.x, threadIdx.x);
    else                              neigh_body<TZI, TZO>(j2, blockIdx.x - j3.nblocks, threadIdx.x);
}

// -------- merged layer-0 combined gather (L3 blocks first, then L2).
__global__ void gatherZM23_k(
    const float2* __restrict__ hAi, const float2* __restrict__ hBi, const float2* __restrict__ hCi,
    const int* __restrict__ ga, const int* __restrict__ gb, const int* __restrict__ gc,
    const float* __restrict__ iso3, const float* __restrict__ W13, const float* __restrict__ W23,
    bf16* __restrict__ zb3, bf16* __restrict__ m3, int n3, int jstep3, int nblk3,
    const float2* __restrict__ hUi, const float2* __restrict__ hVi,
    const int* __restrict__ gu, const int* __restrict__ gv,
    const float* __restrict__ iso2, const float* __restrict__ W12, const float* __restrict__ W22,
    bf16* __restrict__ zb2, bf16* __restrict__ m2, int n2, int jstep2) {
    int t = threadIdx.x;
    if ((int)blockIdx.x < nblk3) {
        int idx = blockIdx.x * 256 + t;
        int j = idx >> 6, f = idx & 63;
        float w1c[4], w2c[4];
#pragma unroll
        for (int c = 0; c < 4; ++c) {
            w1c[c] = W13[f * 196 + 192 + c];
            w2c[c] = W23[f * 196 + 192 + c];
        }
        const float4* I4 = (const float4*)iso3;
#pragma unroll
        for (int r = 0; r < 4; ++r, j += jstep3) {
            if (j >= n3) return;
            int a = ga[j], b = gb[j], c = gc[j];
            float4 iv = I4[j];
            float2 va = hAi[(size_t)a * 64 + f];
            float2 vb = hBi[(size_t)b * 64 + f];
            float2 vc = hCi[(size_t)c * 64 + f];
            float zz = va.x + vb.x + vc.x
                     + iv.x * w1c[0] + iv.y * w1c[1] + iv.z * w1c[2] + iv.w * w1c[3];
            float mm = va.y + vb.y + vc.y
                     + iv.x * w2c[0] + iv.y * w2c[1] + iv.z * w2c[2] + iv.w * w2c[3];
            zb3[(size_t)j * HID + f] = __float2bfloat16(zz);
            m3[(size_t)j * HID + f] = __float2bfloat16(mm);
        }
    } else {
        int idx = (blockIdx.x - nblk3) * 256 + t;
        int j = idx >> 6, f = idx & 63;
        float w1c = W12[f * 129 + 128], w2c = W22[f * 129 + 128];
#pragma unroll
        for (int r = 0; r < 4; ++r, j += jstep2) {
            if (j >= n2) return;
            int u = gu[j], v = gv[j];
            float is = iso2[j];
            float2 vu = hUi[(size_t)u * 64 + f];
            float2 vv = hVi[(size_t)v * 64 + f];
            zb2[(size_t)j * HID + f] = __float2bfloat16(vu.x + vv.x + is * w1c);
            m2[(size_t)j * HID + f] = __float2bfloat16(vu.y + vv.y + is * w2c);
        }
    }
}

// -------- merged split segment sum (level 1 fp32, levels 2/3 bf16)
struct SJob { const void* h; int per; int coloff; int S; int nblocks; };

template <typename T>
__device__ __forceinline__ float ldconv(const T* p);
template <> __device__ __forceinline__ float ldconv<float>(const float* p) { return *p; }
template <> __device__ __forceinline__ float ldconv<bf16>(const bf16* p) { return bl(*p); }

template <typename T>
__device__ __forceinline__ void segsum_body(const SJob& jb, float* comb, int blk, int f) {
    int g = blk / jb.S, s = blk % jb.S;
    int r0 = s * 64;
    int r1 = min(jb.per, r0 + 64);
    float acc = 0.f;
    const T* p = (const T*)jb.h + ((size_t)g * jb.per + r0) * HID + f;
    for (int r = r0; r < r1; ++r) { acc += ldconv(p); p += HID; }
    atomicAdd(&comb[g * 192 + jb.coloff + f], acc);
}

__global__ void segsum3_k(SJob s1, SJob s2, SJob s3, float* comb) {
    int b = blockIdx.x, f = threadIdx.x;   // 64 threads
    if (b < s1.nblocks)                    segsum_body<float>(s1, comb, b, f);
    else if (b < s1.nblocks + s2.nblocks)  segsum_body<bf16>(s2, comb, b - s1.nblocks, f);
    else                                   segsum_body<bf16>(s3, comb, b - s1.nblocks - s2.nblocks, f);
}

// -------- classifier
__global__ void classifier_k(const float* __restrict__ comb,
                             const float* __restrict__ cW1, const float* __restrict__ cb1,
                             const float* __restrict__ cW2, const float* __restrict__ cb2,
                             float* __restrict__ out) {
    __shared__ float row[192];
    __shared__ float hid[64];
    int g = blockIdx.x, t = threadIdx.x;
    for (int i = t; i < 192; i += 64) row[i] = comb[g * 192 + i];
    __syncthreads();
    float acc = cb1[t];
#pragma unroll 8
    for (int k = 0; k < 192; ++k) acc += row[k] * cW1[t * 192 + k];
    hid[t] = fmaxf(acc, 0.f);
    __syncthreads();
    if (t < 10) {
        float o = cb2[t];
#pragma unroll
        for (int k = 0; k < 64; ++k) o += hid[k] * cW2[t * 64 + k];
        out[g * 10 + t] = o;
    }
}

static inline int cdiv(long long a, long long b) { return (int)((a + b - 1) / b); }

extern "C" void kernel_launch(void* const* d_in, const int* in_sizes, int n_in,
                              void* d_out, int out_size, void* d_ws, size_t ws_size,
                              hipStream_t stream) {
    const float* x        = (const float*)d_in[0];
    const int*   eidx     = (const int*)d_in[1];
    const int*   gu2      = (const int*)d_in[3];
    const int*   gv2      = (const int*)d_in[4];
    const float* iso2     = (const float*)d_in[5];
    const int*   tedges   = (const int*)d_in[6];
    const int*   ga3      = (const int*)d_in[8];
    const int*   gb3      = (const int*)d_in[9];
    const int*   gc3      = (const int*)d_in[10];
    const float* iso3     = (const float*)d_in[11];
    const int*   hedges   = (const int*)d_in[12];
    const float* g1W1[3]  = {(const float*)d_in[14], (const float*)d_in[16], (const float*)d_in[18]};
    const float* g1W2[3]  = {(const float*)d_in[15], (const float*)d_in[17], (const float*)d_in[19]};
    const float* g2W1_0   = (const float*)d_in[20];
    const float* g2W2_0   = (const float*)d_in[21];
    const float* g2W1_1   = (const float*)d_in[22];
    const float* g2W2_1   = (const float*)d_in[23];
    const float* g3W1_0   = (const float*)d_in[24];
    const float* g3W2_0   = (const float*)d_in[25];
    const float* g3W1_1   = (const float*)d_in[26];
    const float* g3W2_1   = (const float*)d_in[27];
    const float* cW1      = (const float*)d_in[28];
    const float* cb1      = (const float*)d_in[29];
    const float* cW2      = (const float*)d_in[30];
    const float* cb2      = (const float*)d_in[31];
    float* out = (float*)d_out;

    const int N  = in_sizes[0] / 32;       // 2560
    const int E1 = in_sizes[1] / 2;
    const int n2 = in_sizes[3];            // 24320
    const int E2 = in_sizes[6] / 2;
    const int n3 = in_sizes[8];            // 145920
    const int E3 = in_sizes[12] / 2;
    const int G  = out_size / 10;          // 128
    const int per1 = N / G, per2 = n2 / G, per3 = n3 / G;

    // ---- workspace carve-up (float units, 16B-aligned blocks)
    float* ws = (float*)d_ws;
    size_t off = 0;
    auto alloc = [&](size_t n) { off = (off + 3) & ~(size_t)3; float* p = ws + off; off += n; return p; };
    const size_t NH = (size_t)N * HID;
    float* nb0 = alloc(NH); float* nb1 = alloc(NH);
    bf16* mb1 = (bf16*)alloc(NH / 2 + 64);
    float* hUi = alloc(NH * 2); float* hVi = alloc(NH * 2);     // interleaved tables
    float* hAi = alloc(NH * 2); float* hBi = alloc(NH * 2); float* hCi = alloc(NH * 2);
    bf16* m2b = (bf16*)alloc((size_t)n2 * HID / 2 + 64);
    bf16* z2b = (bf16*)alloc((size_t)n2 * HID / 2 + 64);
    bf16* z2c = (bf16*)alloc((size_t)n2 * HID / 2 + 64);
    bf16* m3b = (bf16*)alloc((size_t)n3 * HID / 2 + 64);
    bf16* z3b = (bf16*)alloc((size_t)n3 * HID / 2 + 64);
    bf16* z3c = (bf16*)alloc((size_t)n3 * HID / 2 + 64);
    float* comb = alloc((size_t)G * 192);
    int* iws = (int*)(ws + off);
    size_t ioff = 0;
    auto ialloc = [&](size_t n) { int* p = iws + ioff; ioff += n; return p; };
    int* rs1 = ialloc(N + 1);  int* cur1 = ialloc(N);  int* csrc1 = ialloc(E1);
    int* rs2 = ialloc(n2 + 1); int* cur2 = ialloc(n2); int* csrc2 = ialloc(E2);
    int* rs3 = ialloc(n3 + 1); int* cur3 = ialloc(n3); int* csrc3 = ialloc(E3);
    int* bsum1 = ialloc(256); int* bsum2 = ialloc(256); int* bsum3 = ialloc(256);
    (void)ws_size;

    dim3 B256(256);
    auto gemm2b = [&](const float* in, const float* Wa, const float* Wb,
                      float* oa, bf16* ob, int R, int K, int ldw, int coloff) {
        int blocks = cdiv(cdiv(R, RPW), 4);
        if (K == 64)
            gemm2_regb<64><<<blocks, B256, 0, stream>>>(in, Wa, Wb, oa, ob, R, ldw, coloff);
        else
            gemm2_regb<32><<<blocks, B256, 0, stream>>>(in, Wa, Wb, oa, ob, R, ldw, coloff);
    };
    auto mknjob = [&](const int* rs, const int* csrc, const bf16* m,
                      const void* zi, void* zo, int R) {
        NJob j; j.rs = rs; j.csrc = csrc; j.m = (const bf162*)m; j.zin = zi; j.zout = zo;
        j.R = R; int nb = cdiv(R, 8); j.nb8 = cdiv(nb, 8); j.nblocks = j.nb8 * 8; return j;
    };

    // ---- batched CSR build (7 dispatches; comb zero folded into first)
    int nz1 = cdiv(N, 256), nz2 = cdiv(n2, 256), nz3 = cdiv(n3, 256), nz4 = cdiv(G * 192, 256);
    zero4_k<<<nz1 + nz2 + nz3 + nz4, B256, 0, stream>>>(
        cur1, N, cur2, n2, cur3, n3, (int*)comb, G * 192, nz1, nz2, nz3);
    int ne1 = cdiv(E1, 256), ne2 = cdiv(E2, 256), ne3 = cdiv(E3, 256);
    hist3_k<<<ne1 + ne2 + ne3, B256, 0, stream>>>(
        eidx, E1, cur1, tedges, E2, cur2, hedges, E3, cur3, ne1, ne2);
    int ns1 = cdiv(N + 1, 1024), ns2 = cdiv(n2 + 1, 1024), ns3 = cdiv(n3 + 1, 1024);
    scan1_3k<<<ns1 + ns2 + ns3, B256, 0, stream>>>(
        cur1, rs1, bsum1, N + 1, N, cur2, rs2, bsum2, n2 + 1, n2,
        cur3, rs3, bsum3, n3 + 1, n3, ns1, ns2);
    scan2_3k<<<1, B256, 0, stream>>>(bsum1, ns1, bsum2, ns2, bsum3, ns3);
    int nc1 = cdiv(N + 1, 256), nc2 = cdiv(n2 + 1, 256), nc3 = cdiv(n3 + 1, 256);
    scan3_3k<<<nc1 + nc2 + nc3, B256, 0, stream>>>(
        rs1, bsum1, N + 1, rs2, bsum2, n2 + 1, rs3, bsum3, n3 + 1, nc1, nc2);
    zero4_k<<<nz1 + nz2 + nz3, B256, 0, stream>>>(
        cur1, N, cur2, n2, cur3, n3, nullptr, 0, nz1, nz2, nz3);
    fill3_k<<<ne1 + ne2 + ne3, B256, 0, stream>>>(
        eidx, E1, rs1, cur1, csrc1, tedges, E2, rs2, cur2, csrc2,
        hedges, E3, rs3, cur3, csrc3, ne1, ne2);

    // ================= level 1: node GNN (3 layers; scalar gemm) ==========
    const float* hcur = x;
    float* zb[2] = {nb0, nb1};
    for (int l = 0; l < 3; ++l) {
        int K = (l == 0) ? 32 : 64;
        float* z = zb[l & 1];
        gemm2b(hcur, g1W1[l], g1W2[l], z, mb1, N, K, K, 0);
        NJob j1 = mknjob(rs1, csrc1, mb1, z, z, N);
        neighsum_relu_k<float2, float2><<<j1.nblocks, B256, 0, stream>>>(j1);
        hcur = z;
    }
    const float* h = hcur;   // = nb0 after 3 layers

    // ---- all 5 table GEMMs (interleaved outputs) in ONE dispatch
    {
        TJobs5 jobs;
        jobs.j[0] = {g2W1_0, g2W2_0, hUi, 129, 0};
        jobs.j[1] = {g2W1_0, g2W2_0, hVi, 129, 64};
        jobs.j[2] = {g3W1_0, g3W2_0, hAi, 196, 0};
        jobs.j[3] = {g3W1_0, g3W2_0, hBi, 196, 64};
        jobs.j[4] = {g3W1_0, g3W2_0, hCi, 196, 128};
        int bpj = cdiv(cdiv(N, RPW), 4);
        gemm2_table<<<bpj * 5, B256, 0, stream>>>(h, jobs, N, bpj);
    }

    // ================= levels 2+3 merged (independent pipelines) ==========
    {
        int jstep3 = cdiv(n3, 4), jstep2 = cdiv(n2, 4);
        int nblk3 = cdiv((long long)jstep3 * 64, 256);
        int nblk2 = cdiv((long long)jstep2 * 64, 256);
        gatherZM23_k<<<nblk3 + nblk2, B256, 0, stream>>>(
            (const float2*)hAi, (const float2*)hBi, (const float2*)hCi,
            ga3, gb3, gc3, iso3, g3W1_0, g3W2_0, z3b, m3b, n3, jstep3, nblk3,
            (const float2*)hUi, (const float2*)hVi, gu2, gv2, iso2,
            g2W1_0, g2W2_0, z2b, m2b, n2, jstep2);
    }
    // layer-0 neighbor sums: bf16 in/out, IN-PLACE on zb
    {
        NJob j3 = mknjob(rs3, csrc3, m3b, z3b, z3b, n3);
        NJob j2 = mknjob(rs2, csrc2, m2b, z2b, z2b, n2);
        neighsum2_relu_k<bf162, bf162><<<j3.nblocks + j2.nblocks, B256, 0, stream>>>(j3, j2);
    }
    // layer-1 MFMA dual GEMMs (both outputs bf16), merged
    {
        MJob j3 = {z3b, g3W1_1, g3W2_1, z3c, m3b, n3, cdiv(n3, 128)};
        MJob j2 = {z2b, g2W1_1, g2W2_1, z2c, m2b, n2, cdiv(n2, 128)};
        gemm2_mfma2<<<j3.nblocks + j2.nblocks, B256, 0, stream>>>(j3, j2);
    }
    // layer-1 neighbor sums: bf16 in/out, IN-PLACE on zc, merged
    {
        NJob j3 = mknjob(rs3, csrc3, m3b, z3c, z3c, n3);
        NJob j2 = mknjob(rs2, csrc2, m2b, z2c, z2c, n2);
        neighsum2_relu_k<bf162, bf162><<<j3.nblocks + j2.nblocks, B256, 0, stream>>>(j3, j2);
    }
    // all three segment sums (L1 fp32, L2/L3 bf16), merged
    {
        SJob s1 = {h,   per1, 0,   cdiv(per1, 64), 0};
        SJob s2 = {z2c, per2, 64,  cdiv(per2, 64), 0};
        SJob s3 = {z3c, per3, 128, cdiv(per3, 64), 0};
        s1.nblocks = G * s1.S; s2.nblocks = G * s2.S; s3.nblocks = G * s3.S;
        segsum3_k<<<s1.nblocks + s2.nblocks + s3.nblocks, 64, 0, stream>>>(s1, s2, s3, comb);
    }

    // ================= classifier =================
    classifier_k<<<G, 64, 0, stream>>>(comb, cW1, cb1, cW2, cb2, out);
}

// Round 22
// 368.960 us; speedup vs baseline: 1.6612x; 1.0788x over previous
//
#include <hip/hip_runtime.h>
#include <hip/hip_bf16.h>

#define HID 64
#define RPW 16   // rows per wave in scalar gemm kernels
#define KCH 8    // k-chunk width

typedef __hip_bfloat16  bf16;
typedef __hip_bfloat162 bf162;
typedef __attribute__((ext_vector_type(8))) short bf8v;
typedef __attribute__((ext_vector_type(4))) float f4v;
__device__ __forceinline__ float bl(bf16 h) { return __bfloat162float(h); }

// -------- FUSED level-1 GNN: one block per graph (20 nodes), 3 layers
// entirely in LDS. Edges are graph-local so no inter-block dependency.
// wl: W^T (k-major) so lane=col reads are conflict-free; h-row reads are
// wave-uniform broadcasts. 42KB LDS -> 3 blocks/CU (only 128 blocks anyway).
__global__ __launch_bounds__(256)
void level1_k(const float* __restrict__ x,
              const int* __restrict__ rs1, const int* __restrict__ csrc1,
              const float* __restrict__ W10, const float* __restrict__ W20,
              const float* __restrict__ W11, const float* __restrict__ W21,
              const float* __restrict__ W12, const float* __restrict__ W22,
              float* __restrict__ hout, int nper) {
    __shared__ float hbuf[20][64];
    __shared__ float mbuf[20][64];
    __shared__ float wl1[64 * 64];
    __shared__ float wl2[64 * 64];
    int g = blockIdx.x, t = threadIdx.x;
    int wv = t >> 6, lane = t & 63;
    int base = g * nper;
    for (int i = t; i < 20 * 32; i += 256)
        hbuf[i >> 5][i & 31] = x[(size_t)(base + (i >> 5)) * 32 + (i & 31)];
    const float* W1s[3] = {W10, W11, W12};
    const float* W2s[3] = {W20, W21, W22};
#pragma unroll 1
    for (int l = 0; l < 3; ++l) {
        int K = (l == 0) ? 32 : 64;
        const float* W1 = W1s[l];
        const float* W2 = W2s[l];
        __syncthreads();
        for (int i = t; i < K * 64; i += 256) {   // i = k*64+col
            int k = i >> 6, col = i & 63;
            wl1[i] = W1[col * K + k];
            wl2[i] = W2[col * K + k];
        }
        __syncthreads();
        float accz[5], accm[5];
#pragma unroll
        for (int ri = 0; ri < 5; ++ri) {
            int r = wv + ri * 4;
            float az = 0.f, am = 0.f;
            for (int k = 0; k < K; ++k) {
                float hv = hbuf[r][k];
                az = fmaf(hv, wl1[k * 64 + lane], az);
                am = fmaf(hv, wl2[k * 64 + lane], am);
            }
            accz[ri] = az; accm[ri] = am;
        }
        __syncthreads();          // all hbuf reads done
#pragma unroll
        for (int ri = 0; ri < 5; ++ri)
            mbuf[wv + ri * 4][lane] = accm[ri];
        __syncthreads();          // mbuf ready
#pragma unroll
        for (int ri = 0; ri < 5; ++ri) {
            int r = wv + ri * 4;
            float acc = accz[ri];
            int s = rs1[base + r], e = rs1[base + r + 1];
            for (int k = s; k < e; ++k)
                acc += mbuf[csrc1[k] - base][lane];
            hbuf[r][lane] = fmaxf(acc, 0.f);
        }
    }
    __syncthreads();
    for (int i = t; i < 20 * 64; i += 256)
        hout[(size_t)(base + (i >> 6)) * 64 + (i & 63)] = hbuf[i >> 6][i & 63];
}

// -------- MFMA dual GEMM body (verified layouts m89/m120). Both outputs bf16.
struct MJob { const bf16* in; const float* Wa; const float* Wb; bf16* oa; bf16* ob; int R; int nblocks; };

__device__ __forceinline__ void mfma_body(const MJob& jb, int blk, int t) {
    __shared__ bf16 wl1[64][72];
    __shared__ bf16 wl2[64][72];
    {
        int n = t >> 2, k0 = (t & 3) * 16;
#pragma unroll
        for (int k = 0; k < 16; ++k) {
            wl1[n][k0 + k] = __float2bfloat16(jb.Wa[n * 64 + k0 + k]);
            wl2[n][k0 + k] = __float2bfloat16(jb.Wb[n * 64 + k0 + k]);
        }
    }
    __syncthreads();
    int lane = t & 63, wv = t >> 6;
    int quad = lane >> 4, m16 = lane & 15;
    int j0 = (blk * 4 + wv) * 32;
    if (j0 >= jb.R) return;
    bf8v a[2][2];
#pragma unroll
    for (int rt = 0; rt < 2; ++rt)
#pragma unroll
        for (int kt = 0; kt < 2; ++kt)
            a[rt][kt] = *(const bf8v*)(jb.in + (size_t)(j0 + rt * 16 + m16) * 64
                                             + kt * 32 + quad * 8);
#pragma unroll
    for (int n = 0; n < 4; ++n) {
        bf8v b1k0 = *(const bf8v*)&wl1[n * 16 + m16][quad * 8];
        bf8v b1k1 = *(const bf8v*)&wl1[n * 16 + m16][32 + quad * 8];
        bf8v b2k0 = *(const bf8v*)&wl2[n * 16 + m16][quad * 8];
        bf8v b2k1 = *(const bf8v*)&wl2[n * 16 + m16][32 + quad * 8];
#pragma unroll
        for (int rt = 0; rt < 2; ++rt) {
            f4v acca = {0.f, 0.f, 0.f, 0.f};
            f4v accb = {0.f, 0.f, 0.f, 0.f};
            acca = __builtin_amdgcn_mfma_f32_16x16x32_bf16(a[rt][0], b1k0, acca, 0, 0, 0);
            acca = __builtin_amdgcn_mfma_f32_16x16x32_bf16(a[rt][1], b1k1, acca, 0, 0, 0);
            accb = __builtin_amdgcn_mfma_f32_16x16x32_bf16(a[rt][0], b2k0, accb, 0, 0, 0);
            accb = __builtin_amdgcn_mfma_f32_16x16x32_bf16(a[rt][1], b2k1, accb, 0, 0, 0);
            int col = n * 16 + m16;
#pragma unroll
            for (int r = 0; r < 4; ++r) {
                int row = j0 + rt * 16 + quad * 4 + r;
                jb.oa[(size_t)row * 64 + col] = __float2bfloat16(acca[r]);
                jb.ob[(size_t)row * 64 + col] = __float2bfloat16(accb[r]);
            }
        }
    }
}

__global__ __launch_bounds__(256)
void gemm2_mfma2(MJob j3, MJob j2) {
    if ((int)blockIdx.x < j3.nblocks) mfma_body(j3, blockIdx.x, threadIdx.x);
    else                              mfma_body(j2, blockIdx.x - j3.nblocks, threadIdx.x);
}

// -------- batched table GEMM: 5 jobs over h; INTERLEAVED bf162 output
// (x=W1-part, y=W2-part). Total tables 3.3MB -> fit per-XCD L2.
struct TJob { const float* Wa; const float* Wb; bf162* o; int ldw; int coloff; };
struct TJobs5 { TJob j[5]; };

__global__ __attribute__((amdgpu_flat_work_group_size(256, 256),
                          amdgpu_waves_per_eu(6, 6)))
void gemm2_table(const float* in, TJobs5 jobs, int R, int bpj) {
    int jobi = blockIdx.x / bpj;
    int lb = blockIdx.x % bpj;
    TJob jb = jobs.j[jobi];
    int lane = threadIdx.x & 63;
    int wid = lb * 4 + (threadIdx.x >> 6);
    int j0 = __builtin_amdgcn_readfirstlane(wid * RPW);
    if (j0 >= R) return;
    float accx[RPW], accy[RPW];
#pragma unroll
    for (int r = 0; r < RPW; ++r) { accx[r] = 0.f; accy[r] = 0.f; }
    const float* pa = jb.Wa + (size_t)lane * jb.ldw + jb.coloff;
    const float* pb = jb.Wb + (size_t)lane * jb.ldw + jb.coloff;
#pragma unroll 1
    for (int kc = 0; kc < 64; kc += KCH) {
        float wx[KCH], wy[KCH];
#pragma unroll
        for (int kk = 0; kk < KCH; ++kk) { wx[kk] = pa[kc + kk]; wy[kk] = pb[kc + kk]; }
#pragma unroll
        for (int r = 0; r < RPW; ++r) {
            const float* rp = in + (size_t)(j0 + r) * 64 + kc;
#pragma unroll
            for (int kk = 0; kk < KCH; ++kk) {
                float s = rp[kk];
                accx[r] = fmaf(s, wx[kk], accx[r]);
                accy[r] = fmaf(s, wy[kk], accy[r]);
            }
        }
    }
#pragma unroll
    for (int r = 0; r < RPW; ++r) {
        int j = j0 + r;
        bf162 v; v.x = __float2bfloat16(accx[r]); v.y = __float2bfloat16(accy[r]);
        jb.o[(size_t)j * 64 + lane] = v;
    }
}

// ======== batched CSR build (unchanged) ========
__global__ void zero4_k(int* p1, int s1, int* p2, int s2, int* p3, int s3,
                        int* p4, int s4, int nb1, int nb2, int nb3) {
    int b = blockIdx.x; int* p; int n; int lb;
    if (b < nb1)                 { p = p1; n = s1; lb = b; }
    else if (b < nb1 + nb2)      { p = p2; n = s2; lb = b - nb1; }
    else if (b < nb1 + nb2 + nb3){ p = p3; n = s3; lb = b - nb1 - nb2; }
    else                         { p = p4; n = s4; lb = b - nb1 - nb2 - nb3; }
    int i = lb * 256 + threadIdx.x;
    if (i < n) p[i] = 0;
}

__global__ void hist3_k(const int* e1, int E1, int* c1,
                        const int* e2, int E2, int* c2,
                        const int* e3, int E3, int* c3, int nb1, int nb2) {
    int b = blockIdx.x; const int* dst; int* c; int E; int lb;
    if (b < nb1)            { dst = e1 + E1; c = c1; E = E1; lb = b; }
    else if (b < nb1 + nb2) { dst = e2 + E2; c = c2; E = E2; lb = b - nb1; }
    else                    { dst = e3 + E3; c = c3; E = E3; lb = b - nb1 - nb2; }
    int e = lb * 256 + threadIdx.x;
    if (e < E) atomicAdd(&c[dst[e]], 1);
}

__device__ __forceinline__ void scan1_body(const int* __restrict__ cnt, int* __restrict__ rs,
                                           int* __restrict__ bsum, int n1, int n, int lb) {
    __shared__ int wsum[4];
    int t = threadIdx.x;
    int base = lb * 1024 + t * 4;
    int v[4]; int s = 0;
#pragma unroll
    for (int i = 0; i < 4; ++i) { int idx = base + i; v[i] = s; s += (idx < n) ? cnt[idx] : 0; }
    int lane = t & 63, wv = t >> 6;
    int x = s;
#pragma unroll
    for (int off = 1; off < 64; off <<= 1) { int y = __shfl_up(x, off, 64); if (lane >= off) x += y; }
    if (lane == 63) wsum[wv] = x;
    __syncthreads();
    int woff = 0;
    for (int w = 0; w < wv; ++w) woff += wsum[w];
    int excl = woff + (x - s);
#pragma unroll
    for (int i = 0; i < 4; ++i) { int idx = base + i; if (idx < n1) rs[idx] = excl + v[i]; }
    if (t == 255) bsum[lb] = wsum[0] + wsum[1] + wsum[2] + wsum[3];
}

__global__ void scan1_3k(const int* c1, int* r1, int* b1, int n1a, int na,
                         const int* c2, int* r2, int* b2, int n1b, int nb,
                         const int* c3, int* r3, int* b3, int n1c, int nc,
                         int nbl1, int nbl2) {
    int b = blockIdx.x;
    if (b < nbl1)             scan1_body(c1, r1, b1, n1a, na, b);
    else if (b < nbl1 + nbl2) scan1_body(c2, r2, b2, n1b, nb, b - nbl1);
    else                      scan1_body(c3, r3, b3, n1c, nc, b - nbl1 - nbl2);
}

__device__ __forceinline__ void scan2_body(int* bsum, int nb, int* wsum) {
    int t = threadIdx.x;
    int s = (t < nb) ? bsum[t] : 0;
    int lane = t & 63, wv = t >> 6;
    int x = s;
#pragma unroll
    for (int off = 1; off < 64; off <<= 1) { int y = __shfl_up(x, off, 64); if (lane >= off) x += y; }
    if (lane == 63) wsum[wv] = x;
    __syncthreads();
    int woff = 0;
    for (int w = 0; w < wv; ++w) woff += wsum[w];
    if (t < nb) bsum[t] = woff + x - s;
    __syncthreads();
}

__global__ void scan2_3k(int* b1, int nb1, int* b2, int nb2, int* b3, int nb3) {
    __shared__ int wsum[4];
    scan2_body(b1, nb1, wsum);
    scan2_body(b2, nb2, wsum);
    scan2_body(b3, nb3, wsum);
}

__global__ void scan3_3k(int* r1, const int* b1, int n1a,
                         int* r2, const int* b2, int n1b,
                         int* r3, const int* b3, int n1c, int nc1, int nc2) {
    int b = blockIdx.x; int* rs; const int* bsum; int n1; int lb;
    if (b < nc1)            { rs = r1; bsum = b1; n1 = n1a; lb = b; }
    else if (b < nc1 + nc2) { rs = r2; bsum = b2; n1 = n1b; lb = b - nc1; }
    else                    { rs = r3; bsum = b3; n1 = n1c; lb = b - nc1 - nc2; }
    int i = lb * 256 + threadIdx.x;
    if (i < n1) rs[i] += bsum[lb >> 2];
}

__global__ void fill3_k(const int* e1, int E1, const int* r1, int* c1, int* s1,
                        const int* e2, int E2, const int* r2, int* c2, int* s2,
                        const int* e3, int E3, const int* r3, int* c3, int* s3,
                        int nb1, int nb2) {
    int b = blockIdx.x;
    const int* edges; int E; const int* rs; int* cur; int* csrc; int lb;
    if (b < nb1)            { edges = e1; E = E1; rs = r1; cur = c1; csrc = s1; lb = b; }
    else if (b < nb1 + nb2) { edges = e2; E = E2; rs = r2; cur = c2; csrc = s2; lb = b - nb1; }
    else                    { edges = e3; E = E3; rs = r3; cur = c3; csrc = s3; lb = b - nb1 - nb2; }
    int e = lb * 256 + threadIdx.x;
    if (e >= E) return;
    int d = edges[E + e];
    int p = rs[d] + atomicAdd(&cur[d], 1);
    csrc[p] = edges[e];
}

// -------- gather + relu (bf16 messages), bf16 in/out.
struct NJob { const int* rs; const int* csrc; const bf162* m; const void* zin;
              void* zout; int R; int nb8; int nblocks; };

__device__ __forceinline__ void neigh_body(const NJob& jb, int blk, int t) {
    int b = (blk & 7) * jb.nb8 + (blk >> 3);
    int wv = t >> 6, lane = t & 63;
    int j = b * 8 + wv * 2 + (lane >> 5);
    int f2 = lane & 31;
    if (j >= jb.R) return;
    const bf162* m = jb.m;
    int s = jb.rs[j], e = jb.rs[j + 1];
    bf162 z0 = ((const bf162*)jb.zin)[(size_t)j * 32 + f2];
    float ax = bl(z0.x), ay = bl(z0.y);
    int k = s;
    for (; k + 8 <= e; k += 8) {
        int i0 = jb.csrc[k],     i1 = jb.csrc[k + 1], i2 = jb.csrc[k + 2], i3 = jb.csrc[k + 3];
        int i4 = jb.csrc[k + 4], i5 = jb.csrc[k + 5], i6 = jb.csrc[k + 6], i7 = jb.csrc[k + 7];
        bf162 v0 = m[(size_t)i0 * 32 + f2], v1 = m[(size_t)i1 * 32 + f2];
        bf162 v2 = m[(size_t)i2 * 32 + f2], v3 = m[(size_t)i3 * 32 + f2];
        bf162 v4 = m[(size_t)i4 * 32 + f2], v5 = m[(size_t)i5 * 32 + f2];
        bf162 v6 = m[(size_t)i6 * 32 + f2], v7 = m[(size_t)i7 * 32 + f2];
        ax += ((bl(v0.x) + bl(v1.x)) + (bl(v2.x) + bl(v3.x)))
            + ((bl(v4.x) + bl(v5.x)) + (bl(v6.x) + bl(v7.x)));
        ay += ((bl(v0.y) + bl(v1.y)) + (bl(v2.y) + bl(v3.y)))
            + ((bl(v4.y) + bl(v5.y)) + (bl(v6.y) + bl(v7.y)));
    }
    for (; k + 4 <= e; k += 4) {
        int i0 = jb.csrc[k], i1 = jb.csrc[k + 1], i2 = jb.csrc[k + 2], i3 = jb.csrc[k + 3];
        bf162 v0 = m[(size_t)i0 * 32 + f2], v1 = m[(size_t)i1 * 32 + f2];
        bf162 v2 = m[(size_t)i2 * 32 + f2], v3 = m[(size_t)i3 * 32 + f2];
        ax += (bl(v0.x) + bl(v1.x)) + (bl(v2.x) + bl(v3.x));
        ay += (bl(v0.y) + bl(v1.y)) + (bl(v2.y) + bl(v3.y));
    }
    for (; k < e; ++k) {
        bf162 v = m[(size_t)jb.csrc[k] * 32 + f2];
        ax += bl(v.x); ay += bl(v.y);
    }
    bf162 o; o.x = __float2bfloat16(fmaxf(ax, 0.f)); o.y = __float2bfloat16(fmaxf(ay, 0.f));
    ((bf162*)jb.zout)[(size_t)j * 32 + f2] = o;
}

__global__ void neighsum2_relu_k(NJob j3, NJob j2) {
    if ((int)blockIdx.x < j3.nblocks) neigh_body(j3, blockIdx.x, threadIdx.x);
    else                              neigh_body(j2, blockIdx.x - j3.nblocks, threadIdx.x);
}

// -------- merged layer-0 combined gather (bf162 interleaved tables)
__global__ void gatherZM23_k(
    const bf162* __restrict__ hAi, const bf162* __restrict__ hBi, const bf162* __restrict__ hCi,
    const int* __restrict__ ga, const int* __restrict__ gb, const int* __restrict__ gc,
    const float* __restrict__ iso3, const float* __restrict__ W13, const float* __restrict__ W23,
    bf16* __restrict__ zb3, bf16* __restrict__ m3, int n3, int jstep3, int nblk3,
    const bf162* __restrict__ hUi, const bf162* __restrict__ hVi,
    const int* __restrict__ gu, const int* __restrict__ gv,
    const float* __restrict__ iso2, const float* __restrict__ W12, const float* __restrict__ W22,
    bf16* __restrict__ zb2, bf16* __restrict__ m2, int n2, int jstep2) {
    int t = threadIdx.x;
    if ((int)blockIdx.x < nblk3) {
        int idx = blockIdx.x * 256 + t;
        int j = idx >> 6, f = idx & 63;
        float w1c[4], w2c[4];
#pragma unroll
        for (int c = 0; c < 4; ++c) {
            w1c[c] = W13[f * 196 + 192 + c];
            w2c[c] = W23[f * 196 + 192 + c];
        }
        const float4* I4 = (const float4*)iso3;
#pragma unroll
        for (int r = 0; r < 4; ++r, j += jstep3) {
            if (j >= n3) return;
            int a = ga[j], b = gb[j], c = gc[j];
            float4 iv = I4[j];
            bf162 va = hAi[(size_t)a * 64 + f];
            bf162 vb = hBi[(size_t)b * 64 + f];
            bf162 vc = hCi[(size_t)c * 64 + f];
            float zz = bl(va.x) + bl(vb.x) + bl(vc.x)
                     + iv.x * w1c[0] + iv.y * w1c[1] + iv.z * w1c[2] + iv.w * w1c[3];
            float mm = bl(va.y) + bl(vb.y) + bl(vc.y)
                     + iv.x * w2c[0] + iv.y * w2c[1] + iv.z * w2c[2] + iv.w * w2c[3];
            zb3[(size_t)j * HID + f] = __float2bfloat16(zz);
            m3[(size_t)j * HID + f] = __float2bfloat16(mm);
        }
    } else {
        int idx = (blockIdx.x - nblk3) * 256 + t;
        int j = idx >> 6, f = idx & 63;
        float w1c = W12[f * 129 + 128], w2c = W22[f * 129 + 128];
#pragma unroll
        for (int r = 0; r < 4; ++r, j += jstep2) {
            if (j >= n2) return;
            int u = gu[j], v = gv[j];
            float is = iso2[j];
            bf162 vu = hUi[(size_t)u * 64 + f];
            bf162 vv = hVi[(size_t)v * 64 + f];
            zb2[(size_t)j * HID + f] = __float2bfloat16(bl(vu.x) + bl(vv.x) + is * w1c);
            m2[(size_t)j * HID + f] = __float2bfloat16(bl(vu.y) + bl(vv.y) + is * w2c);
        }
    }
}

// -------- merged split segment sum (level 1 fp32, levels 2/3 bf16)
struct SJob { const void* h; int per; int coloff; int S; int nblocks; };

template <typename T>
__device__ __forceinline__ float ldconv(const T* p);
template <> __device__ __forceinline__ float ldconv<float>(const float* p) { return *p; }
template <> __device__ __forceinline__ float ldconv<bf16>(const bf16* p) { return bl(*p); }

template <typename T>
__device__ __forceinline__ void segsum_body(const SJob& jb, float* comb, int blk, int f) {
    int g = blk / jb.S, s = blk % jb.S;
    int r0 = s * 64;
    int r1 = min(jb.per, r0 + 64);
    float acc = 0.f;
    const T* p = (const T*)jb.h + ((size_t)g * jb.per + r0) * HID + f;
    for (int r = r0; r < r1; ++r) { acc += ldconv(p); p += HID; }
    atomicAdd(&comb[g * 192 + jb.coloff + f], acc);
}

__global__ void segsum3_k(SJob s1, SJob s2, SJob s3, float* comb) {
    int b = blockIdx.x, f = threadIdx.x;   // 64 threads
    if (b < s1.nblocks)                    segsum_body<float>(s1, comb, b, f);
    else if (b < s1.nblocks + s2.nblocks)  segsum_body<bf16>(s2, comb, b - s1.nblocks, f);
    else                                   segsum_body<bf16>(s3, comb, b - s1.nblocks - s2.nblocks, f);
}

// -------- classifier
__global__ void classifier_k(const float* __restrict__ comb,
                             const float* __restrict__ cW1, const float* __restrict__ cb1,
                             const float* __restrict__ cW2, const float* __restrict__ cb2,
                             float* __restrict__ out) {
    __shared__ float row[192];
    __shared__ float hid[64];
    int g = blockIdx.x, t = threadIdx.x;
    for (int i = t; i < 192; i += 64) row[i] = comb[g * 192 + i];
    __syncthreads();
    float acc = cb1[t];
#pragma unroll 8
    for (int k = 0; k < 192; ++k) acc += row[k] * cW1[t * 192 + k];
    hid[t] = fmaxf(acc, 0.f);
    __syncthreads();
    if (t < 10) {
        float o = cb2[t];
#pragma unroll
        for (int k = 0; k < 64; ++k) o += hid[k] * cW2[t * 64 + k];
        out[g * 10 + t] = o;
    }
}

static inline int cdiv(long long a, long long b) { return (int)((a + b - 1) / b); }

extern "C" void kernel_launch(void* const* d_in, const int* in_sizes, int n_in,
                              void* d_out, int out_size, void* d_ws, size_t ws_size,
                              hipStream_t stream) {
    const float* x        = (const float*)d_in[0];
    const int*   eidx     = (const int*)d_in[1];
    const int*   gu2      = (const int*)d_in[3];
    const int*   gv2      = (const int*)d_in[4];
    const float* iso2     = (const float*)d_in[5];
    const int*   tedges   = (const int*)d_in[6];
    const int*   ga3      = (const int*)d_in[8];
    const int*   gb3      = (const int*)d_in[9];
    const int*   gc3      = (const int*)d_in[10];
    const float* iso3     = (const float*)d_in[11];
    const int*   hedges   = (const int*)d_in[12];
    const float* g1W1[3]  = {(const float*)d_in[14], (const float*)d_in[16], (const float*)d_in[18]};
    const float* g1W2[3]  = {(const float*)d_in[15], (const float*)d_in[17], (const float*)d_in[19]};
    const float* g2W1_0   = (const float*)d_in[20];
    const float* g2W2_0   = (const float*)d_in[21];
    const float* g2W1_1   = (const float*)d_in[22];
    const float* g2W2_1   = (const float*)d_in[23];
    const float* g3W1_0   = (const float*)d_in[24];
    const float* g3W2_0   = (const float*)d_in[25];
    const float* g3W1_1   = (const float*)d_in[26];
    const float* g3W2_1   = (const float*)d_in[27];
    const float* cW1      = (const float*)d_in[28];
    const float* cb1      = (const float*)d_in[29];
    const float* cW2      = (const float*)d_in[30];
    const float* cb2      = (const float*)d_in[31];
    float* out = (float*)d_out;

    const int N  = in_sizes[0] / 32;       // 2560
    const int E1 = in_sizes[1] / 2;
    const int n2 = in_sizes[3];            // 24320
    const int E2 = in_sizes[6] / 2;
    const int n3 = in_sizes[8];            // 145920
    const int E3 = in_sizes[12] / 2;
    const int G  = out_size / 10;          // 128
    const int per1 = N / G, per2 = n2 / G, per3 = n3 / G;

    // ---- workspace carve-up (float units, 16B-aligned blocks)
    float* ws = (float*)d_ws;
    size_t off = 0;
    auto alloc = [&](size_t n) { off = (off + 3) & ~(size_t)3; float* p = ws + off; off += n; return p; };
    const size_t NH = (size_t)N * HID;
    float* h0 = alloc(NH);                                      // level-1 output
    bf162* hUi = (bf162*)alloc(NH); bf162* hVi = (bf162*)alloc(NH);  // bf162 interleaved tables
    bf162* hAi = (bf162*)alloc(NH); bf162* hBi = (bf162*)alloc(NH); bf162* hCi = (bf162*)alloc(NH);
    bf16* m2b = (bf16*)alloc((size_t)n2 * HID / 2 + 64);
    bf16* z2b = (bf16*)alloc((size_t)n2 * HID / 2 + 64);
    bf16* z2c = (bf16*)alloc((size_t)n2 * HID / 2 + 64);
    bf16* m3b = (bf16*)alloc((size_t)n3 * HID / 2 + 64);
    bf16* z3b = (bf16*)alloc((size_t)n3 * HID / 2 + 64);
    bf16* z3c = (bf16*)alloc((size_t)n3 * HID / 2 + 64);
    float* comb = alloc((size_t)G * 192);
    int* iws = (int*)(ws + off);
    size_t ioff = 0;
    auto ialloc = [&](size_t n) { int* p = iws + ioff; ioff += n; return p; };
    int* rs1 = ialloc(N + 1);  int* cur1 = ialloc(N);  int* csrc1 = ialloc(E1);
    int* rs2 = ialloc(n2 + 1); int* cur2 = ialloc(n2); int* csrc2 = ialloc(E2);
    int* rs3 = ialloc(n3 + 1); int* cur3 = ialloc(n3); int* csrc3 = ialloc(E3);
    int* bsum1 = ialloc(256); int* bsum2 = ialloc(256); int* bsum3 = ialloc(256);
    (void)ws_size;

    dim3 B256(256);
    auto mknjob = [&](const int* rs, const int* csrc, const bf16* m,
                      const void* zi, void* zo, int R) {
        NJob j; j.rs = rs; j.csrc = csrc; j.m = (const bf162*)m; j.zin = zi; j.zout = zo;
        j.R = R; int nb = cdiv(R, 8); j.nb8 = cdiv(nb, 8); j.nblocks = j.nb8 * 8; return j;
    };

    // ---- batched CSR build (7 dispatches; comb zero folded into first)
    int nz1 = cdiv(N, 256), nz2 = cdiv(n2, 256), nz3 = cdiv(n3, 256), nz4 = cdiv(G * 192, 256);
    zero4_k<<<nz1 + nz2 + nz3 + nz4, B256, 0, stream>>>(
        cur1, N, cur2, n2, cur3, n3, (int*)comb, G * 192, nz1, nz2, nz3);
    int ne1 = cdiv(E1, 256), ne2 = cdiv(E2, 256), ne3 = cdiv(E3, 256);
    hist3_k<<<ne1 + ne2 + ne3, B256, 0, stream>>>(
        eidx, E1, cur1, tedges, E2, cur2, hedges, E3, cur3, ne1, ne2);
    int ns1 = cdiv(N + 1, 1024), ns2 = cdiv(n2 + 1, 1024), ns3 = cdiv(n3 + 1, 1024);
    scan1_3k<<<ns1 + ns2 + ns3, B256, 0, stream>>>(
        cur1, rs1, bsum1, N + 1, N, cur2, rs2, bsum2, n2 + 1, n2,
        cur3, rs3, bsum3, n3 + 1, n3, ns1, ns2);
    scan2_3k<<<1, B256, 0, stream>>>(bsum1, ns1, bsum2, ns2, bsum3, ns3);
    int nc1 = cdiv(N + 1, 256), nc2 = cdiv(n2 + 1, 256), nc3 = cdiv(n3 + 1, 256);
    scan3_3k<<<nc1 + nc2 + nc3, B256, 0, stream>>>(
        rs1, bsum1, N + 1, rs2, bsum2, n2 + 1, rs3, bsum3, n3 + 1, nc1, nc2);
    zero4_k<<<nz1 + nz2 + nz3, B256, 0, stream>>>(
        cur1, N, cur2, n2, cur3, n3, nullptr, 0, nz1, nz2, nz3);
    fill3_k<<<ne1 + ne2 + ne3, B256, 0, stream>>>(
        eidx, E1, rs1, cur1, csrc1, tedges, E2, rs2, cur2, csrc2,
        hedges, E3, rs3, cur3, csrc3, ne1, ne2);

    // ================= level 1: FUSED single kernel (block = graph) ========
    level1_k<<<G, B256, 0, stream>>>(x, rs1, csrc1,
        g1W1[0], g1W2[0], g1W1[1], g1W2[1], g1W1[2], g1W2[2], h0, per1);
    const float* h = h0;

    // ---- all 5 table GEMMs (bf162 interleaved outputs) in ONE dispatch
    {
        TJobs5 jobs;
        jobs.j[0] = {g2W1_0, g2W2_0, hUi, 129, 0};
        jobs.j[1] = {g2W1_0, g2W2_0, hVi, 129, 64};
        jobs.j[2] = {g3W1_0, g3W2_0, hAi, 196, 0};
        jobs.j[3] = {g3W1_0, g3W2_0, hBi, 196, 64};
        jobs.j[4] = {g3W1_0, g3W2_0, hCi, 196, 128};
        int bpj = cdiv(cdiv(N, RPW), 4);
        gemm2_table<<<bpj * 5, B256, 0, stream>>>(h, jobs, N, bpj);
    }

    // ================= levels 2+3 merged (independent pipelines) ==========
    {
        int jstep3 = cdiv(n3, 4), jstep2 = cdiv(n2, 4);
        int nblk3 = cdiv((long long)jstep3 * 64, 256);
        int nblk2 = cdiv((long long)jstep2 * 64, 256);
        gatherZM23_k<<<nblk3 + nblk2, B256, 0, stream>>>(
            hAi, hBi, hCi, ga3, gb3, gc3, iso3, g3W1_0, g3W2_0,
            z3b, m3b, n3, jstep3, nblk3,
            hUi, hVi, gu2, gv2, iso2, g2W1_0, g2W2_0, z2b, m2b, n2, jstep2);
    }
    {
        NJob j3 = mknjob(rs3, csrc3, m3b, z3b, z3b, n3);
        NJob j2 = mknjob(rs2, csrc2, m2b, z2b, z2b, n2);
        neighsum2_relu_k<<<j3.nblocks + j2.nblocks, B256, 0, stream>>>(j3, j2);
    }
    {
        MJob j3 = {z3b, g3W1_1, g3W2_1, z3c, m3b, n3, cdiv(n3, 128)};
        MJob j2 = {z2b, g2W1_1, g2W2_1, z2c, m2b, n2, cdiv(n2, 128)};
        gemm2_mfma2<<<j3.nblocks + j2.nblocks, B256, 0, stream>>>(j3, j2);
    }
    {
        NJob j3 = mknjob(rs3, csrc3, m3b, z3c, z3c, n3);
        NJob j2 = mknjob(rs2, csrc2, m2b, z2c, z2c, n2);
        neighsum2_relu_k<<<j3.nblocks + j2.nblocks, B256, 0, stream>>>(j3, j2);
    }
    {
        SJob s1 = {h,   per1, 0,   cdiv(per1, 64), 0};
        SJob s2 = {z2c, per2, 64,  cdiv(per2, 64), 0};
        SJob s3 = {z3c, per3, 128, cdiv(per3, 64), 0};
        s1.nblocks = G * s1.S; s2.nblocks = G * s2.S; s3.nblocks = G * s3.S;
        segsum3_k<<<s1.nblocks + s2.nblocks + s3.nblocks, 64, 0, stream>>>(s1, s2, s3, comb);
    }

    // ================= classifier =================
    classifier_k<<<G, 64, 0, stream>>>(comb, cW1, cb1, cW2, cb2, out);
}